// Round 1
// baseline (394.075 us; speedup 1.0000x reference)
//
#include <hip/hip_runtime.h>
#include <stdint.h>

// ---------------------------------------------------------------------------
// AlbertDecoderAttention on MI355X (gfx950)
// Decomposition: f32->bf16 converts, weight transposes, bf16 MFMA GEMMs
// (128x128 tile, BK=64, global_load_lds width-16 staging), flash-style
// attention (64 q-rows/block, online softmax), row layernorm.
// Residuals (q1,q2) and pre-LN sums kept in f32 for accuracy.
// Workspace budget: ~94 MB.
// ---------------------------------------------------------------------------

typedef unsigned short u16;
typedef __bf16 bf16x8 __attribute__((ext_vector_type(8)));
typedef float f32x4 __attribute__((ext_vector_type(4)));

#define AS1 __attribute__((address_space(1)))
#define AS3 __attribute__((address_space(3)))

__device__ __forceinline__ u16 f2bf(float f) {
  union { float f; uint32_t u; } v; v.f = f;
  uint32_t u = v.u;
  return (u16)((u + 0x7fffu + ((u >> 16) & 1u)) >> 16);  // RNE
}

__device__ __forceinline__ void gl_lds16(const void* g, void* l) {
  // 16B per lane; LDS dest is wave-uniform base + lane*16 (HW behavior)
  __builtin_amdgcn_global_load_lds((AS1 void*)(g), (AS3 void*)(l), 16, 0, 0);
}

// ---------------------------------------------------------------------------
// f32 -> bf16 convert (exact grid: n = blocks*256*4)
// ---------------------------------------------------------------------------
__global__ void __launch_bounds__(256)
convert_kernel(const float* __restrict__ in, u16* __restrict__ out) {
  const int i = blockIdx.x * 256 + threadIdx.x;
  float4 v = ((const float4*)in)[i];
  ushort4 o;
  o.x = f2bf(v.x); o.y = f2bf(v.y); o.z = f2bf(v.z); o.w = f2bf(v.w);
  ((ushort4*)out)[i] = o;
}

// ---------------------------------------------------------------------------
// Weight transpose + convert: W[k][n] f32 -> Wt[n][k] bf16 (7 matrices, 1024^2)
// ---------------------------------------------------------------------------
struct WP { const float* w[7]; };

__global__ void __launch_bounds__(256)
transpose_kernel(WP wp, u16* __restrict__ out) {
  __shared__ float tile[64][65];
  const float* W = wp.w[blockIdx.z];
  u16* Wt = out + (size_t)blockIdx.z * 1024 * 1024;
  const int k0 = blockIdx.y * 64, n0 = blockIdx.x * 64;
  const int t = threadIdx.x;
  const int r = t >> 4, c4 = (t & 15) * 4;
#pragma unroll
  for (int rr = 0; rr < 64; rr += 16) {
    float4 v = *(const float4*)&W[(size_t)(k0 + r + rr) * 1024 + n0 + c4];
    tile[r + rr][c4 + 0] = v.x; tile[r + rr][c4 + 1] = v.y;
    tile[r + rr][c4 + 2] = v.z; tile[r + rr][c4 + 3] = v.w;
  }
  __syncthreads();
  const int n = t >> 2, seg = (t & 3) * 16;
  union { u16 s[16]; uint4 q[2]; } u;
#pragma unroll
  for (int i = 0; i < 16; ++i) u.s[i] = f2bf(tile[seg + i][n]);
  uint4* dst = (uint4*)&Wt[(size_t)(n0 + n) * 1024 + k0 + seg];
  dst[0] = u.q[0]; dst[1] = u.q[1];
}

// ---------------------------------------------------------------------------
// GEMM: C[4096][1024] = A[4096][1024](bf16) x Bt[1024][1024](bf16,[n][k]) + bias
// MODE 0: bf16 out   MODE 1: bf16 + f32 out
// MODE 2: bf16 out transposed into Vt[B=4][H=16][DH=64][S=1024]
// MODE 3: f32 out = acc + bias + resid (pre-layernorm sum)
// 128x128 tile, BK=64, 4 waves (2x2), 4x4 16x16x32 fragments per wave.
// ---------------------------------------------------------------------------
template <int MODE>
__global__ void __launch_bounds__(256)
gemm_kernel(const u16* __restrict__ A, const u16* __restrict__ Bt,
            const float* __restrict__ bias, const float* __restrict__ resid,
            u16* __restrict__ outb, float* __restrict__ outf) {
  __shared__ u16 Alds[128 * 64];
  __shared__ u16 Blds[128 * 64];
  const int bm = blockIdx.y * 128, bn = blockIdx.x * 128;
  const int t = threadIdx.x, wv = t >> 6, ln = t & 63;
  const int wm = (wv >> 1) * 64, wn = (wv & 1) * 64;
  const int lcol = ln & 15, lk8 = (ln >> 4) * 8, lr4 = (ln >> 4) * 4;

  f32x4 acc[4][4] = {};

  for (int k0 = 0; k0 < 1024; k0 += 64) {
#pragma unroll
    for (int c = 0; c < 4; ++c) {
      const int o = c * 4096 + wv * 1024 + ln * 16;
      const int row = o >> 7, colb = o & 127;
      gl_lds16((const char*)A + ((size_t)(bm + row) * 1024 + k0) * 2 + colb,
               (char*)Alds + c * 4096 + wv * 1024);
      gl_lds16((const char*)Bt + ((size_t)(bn + row) * 1024 + k0) * 2 + colb,
               (char*)Blds + c * 4096 + wv * 1024);
    }
    __syncthreads();
#pragma unroll
    for (int ks = 0; ks < 2; ++ks) {
      bf16x8 a[4], b[4];
#pragma unroll
      for (int i = 0; i < 4; ++i)
        a[i] = *(const bf16x8*)&Alds[(wm + i * 16 + lcol) * 64 + ks * 32 + lk8];
#pragma unroll
      for (int j = 0; j < 4; ++j)
        b[j] = *(const bf16x8*)&Blds[(wn + j * 16 + lcol) * 64 + ks * 32 + lk8];
#pragma unroll
      for (int i = 0; i < 4; ++i)
#pragma unroll
        for (int j = 0; j < 4; ++j)
          acc[i][j] = __builtin_amdgcn_mfma_f32_16x16x32_bf16(a[i], b[j], acc[i][j], 0, 0, 0);
    }
    __syncthreads();
  }

  // epilogue: D layout col = lane&15, row = (lane>>4)*4 + reg
#pragma unroll
  for (int j = 0; j < 4; ++j) {
    const int col = bn + wn + j * 16 + lcol;
    const float bc = bias[col];
#pragma unroll
    for (int i = 0; i < 4; ++i) {
      const int row0 = bm + wm + i * 16 + lr4;
      if constexpr (MODE == 2) {
        // Vt[b][h][d][s]; consecutive regs -> consecutive s
        ushort4 o;
        o.x = f2bf(acc[i][j][0] + bc); o.y = f2bf(acc[i][j][1] + bc);
        o.z = f2bf(acc[i][j][2] + bc); o.w = f2bf(acc[i][j][3] + bc);
        const int b = row0 >> 10, s = row0 & 1023;
        const int h = col >> 6, d = col & 63;
        *(ushort4*)&outb[(((size_t)(b * 16 + h) * 64 + d) << 10) + s] = o;
      } else {
#pragma unroll
        for (int r = 0; r < 4; ++r) {
          const size_t idx = (size_t)(row0 + r) * 1024 + col;
          const float v = acc[i][j][r] + bc;
          if constexpr (MODE == 3) {
            outf[idx] = v + resid[idx];
          } else if constexpr (MODE == 1) {
            outb[idx] = f2bf(v); outf[idx] = v;
          } else {
            outb[idx] = f2bf(v);
          }
        }
      }
    }
  }
}

// ---------------------------------------------------------------------------
// Flash attention: grid (T/64, B*H); 4 waves x 16 q-rows.
// Q,K bf16 [B,T,HID]; Vt bf16 [B,H,DH,S]; mask f32 [B,S]; ctx bf16 [B,T,HID].
// scores = QK^T/8 + mask; online softmax; O^T = Vt * P^T via MFMA.
// ---------------------------------------------------------------------------
__global__ void __launch_bounds__(256)
attn_kernel(const u16* __restrict__ Q, const u16* __restrict__ Kb,
            const u16* __restrict__ Vt, const float* __restrict__ mask,
            u16* __restrict__ ctx) {
  __shared__ u16 Klds[64 * 64];      // [s][d]
  __shared__ u16 Vlds[64 * 64];      // [d][s]
  __shared__ u16 Plds[4][16 * 64];   // per-wave [q][s]
  __shared__ float sAlpha[4][16];
  __shared__ float sLsum[4][16];

  const int bh = blockIdx.y, b = bh >> 4, h = bh & 15;
  const int q0 = blockIdx.x * 64;
  const int t = threadIdx.x, wv = t >> 6, ln = t & 63;
  const int lcol = ln & 15, lk8 = (ln >> 4) * 8, lr4 = (ln >> 4) * 4;

  const int qrow = q0 + wv * 16 + lcol;
  const u16* qptr = Q + ((size_t)(b * 1024 + qrow) * 1024 + h * 64);
  bf16x8 qa[2];
  qa[0] = *(const bf16x8*)(qptr + lk8);
  qa[1] = *(const bf16x8*)(qptr + 32 + lk8);

  f32x4 accO[4] = {};
  float m_r[4] = {-1e30f, -1e30f, -1e30f, -1e30f};
  float l_r[4] = {};

  for (int s0 = 0; s0 < 1024; s0 += 64) {
    __syncthreads();  // previous tile's LDS reads done before restage
#pragma unroll
    for (int c = 0; c < 2; ++c) {
      const int o = c * 4096 + wv * 1024 + ln * 16;
      const int row = o >> 7, colb = o & 127;
      gl_lds16((const char*)Kb + ((size_t)((b * 1024 + s0 + row) * 1024 + h * 64)) * 2 + colb,
               (char*)Klds + c * 4096 + wv * 1024);
      gl_lds16((const char*)Vt + ((size_t)(((b * 16 + h) * 64 + row) * 1024 + s0)) * 2 + colb,
               (char*)Vlds + c * 4096 + wv * 1024);
    }
    __syncthreads();

    // QK^T -> S[16q][64s] per wave
    f32x4 accS[4] = {};
#pragma unroll
    for (int ks = 0; ks < 2; ++ks)
#pragma unroll
      for (int sc = 0; sc < 4; ++sc) {
        bf16x8 kb = *(const bf16x8*)&Klds[(sc * 16 + lcol) * 64 + ks * 32 + lk8];
        accS[sc] = __builtin_amdgcn_mfma_f32_16x16x32_bf16(qa[ks], kb, accS[sc], 0, 0, 0);
      }

    float sv[4][4];
#pragma unroll
    for (int sc = 0; sc < 4; ++sc) {
      const float mk = mask[b * 1024 + s0 + sc * 16 + lcol];
#pragma unroll
      for (int r = 0; r < 4; ++r) sv[sc][r] = accS[sc][r] * 0.125f + mk;
    }
    float mt[4];
#pragma unroll
    for (int r = 0; r < 4; ++r)
      mt[r] = fmaxf(fmaxf(sv[0][r], sv[1][r]), fmaxf(sv[2][r], sv[3][r]));
#pragma unroll
    for (int off = 1; off < 16; off <<= 1)
#pragma unroll
      for (int r = 0; r < 4; ++r) mt[r] = fmaxf(mt[r], __shfl_xor(mt[r], off));

    float al[4], rs[4];
#pragma unroll
    for (int r = 0; r < 4; ++r) {
      const float mn = fmaxf(m_r[r], mt[r]);
      al[r] = __expf(m_r[r] - mn);
      m_r[r] = mn;
      rs[r] = 0.f;
    }
#pragma unroll
    for (int sc = 0; sc < 4; ++sc)
#pragma unroll
      for (int r = 0; r < 4; ++r) {
        const float pp = __expf(sv[sc][r] - m_r[r]);
        sv[sc][r] = pp;
        rs[r] += pp;
      }
#pragma unroll
    for (int off = 1; off < 16; off <<= 1)
#pragma unroll
      for (int r = 0; r < 4; ++r) rs[r] += __shfl_xor(rs[r], off);
#pragma unroll
    for (int r = 0; r < 4; ++r) l_r[r] = l_r[r] * al[r] + rs[r];

#pragma unroll
    for (int sc = 0; sc < 4; ++sc)
#pragma unroll
      for (int r = 0; r < 4; ++r)
        Plds[wv][(lr4 + r) * 64 + sc * 16 + lcol] = f2bf(sv[sc][r]);
    if (lcol == 0) {
#pragma unroll
      for (int r = 0; r < 4; ++r) sAlpha[wv][lr4 + r] = al[r];
    }
    __syncthreads();

    // rescale O (lane owns q = lcol) then PV
    const float av = sAlpha[wv][lcol];
#pragma unroll
    for (int df = 0; df < 4; ++df)
#pragma unroll
      for (int r = 0; r < 4; ++r) accO[df][r] *= av;
#pragma unroll
    for (int ks = 0; ks < 2; ++ks) {
      bf16x8 pb = *(const bf16x8*)&Plds[wv][lcol * 64 + ks * 32 + lk8];
#pragma unroll
      for (int df = 0; df < 4; ++df) {
        bf16x8 va = *(const bf16x8*)&Vlds[(df * 16 + lcol) * 64 + ks * 32 + lk8];
        accO[df] = __builtin_amdgcn_mfma_f32_16x16x32_bf16(va, pb, accO[df], 0, 0, 0);
      }
    }
  }

  if (lcol == 0) {
#pragma unroll
    for (int r = 0; r < 4; ++r) sLsum[wv][lr4 + r] = l_r[r];
  }
  __syncthreads();
  const float inv = 1.0f / sLsum[wv][lcol];
  u16* cp = ctx + ((size_t)(b * 1024 + qrow) * 1024 + h * 64);
#pragma unroll
  for (int df = 0; df < 4; ++df) {
    ushort4 o;
    o.x = f2bf(accO[df][0] * inv); o.y = f2bf(accO[df][1] * inv);
    o.z = f2bf(accO[df][2] * inv); o.w = f2bf(accO[df][3] * inv);
    *(ushort4*)(cp + df * 16 + lr4) = o;
  }
}

// ---------------------------------------------------------------------------
// LayerNorm over rows of x[4096][1024]; OUTF=1 -> f32 out, else bf16 out
// ---------------------------------------------------------------------------
template <int OUTF>
__global__ void __launch_bounds__(256)
ln_kernel(const float* __restrict__ x, const float* __restrict__ gamma,
          const float* __restrict__ beta, float* __restrict__ outf,
          u16* __restrict__ outb) {
  const int row = blockIdx.x, t = threadIdx.x;
  const float* xr = x + (size_t)row * 1024;
  float4 v = *(const float4*)&xr[t * 4];
  float s = v.x + v.y + v.z + v.w;
  float q = v.x * v.x + v.y * v.y + v.z * v.z + v.w * v.w;
#pragma unroll
  for (int off = 1; off < 64; off <<= 1) {
    s += __shfl_xor(s, off);
    q += __shfl_xor(q, off);
  }
  __shared__ float ws[4], wq[4];
  if ((t & 63) == 0) { ws[t >> 6] = s; wq[t >> 6] = q; }
  __syncthreads();
  s = ws[0] + ws[1] + ws[2] + ws[3];
  q = wq[0] + wq[1] + wq[2] + wq[3];
  const float mu = s * (1.0f / 1024.0f);
  float var = q * (1.0f / 1024.0f) - mu * mu;
  var = fmaxf(var, 0.0f);
  const float rstd = rsqrtf(var + 1e-12f);
  float4 g = *(const float4*)&gamma[t * 4];
  float4 be = *(const float4*)&beta[t * 4];
  float y0 = (v.x - mu) * rstd * g.x + be.x;
  float y1 = (v.y - mu) * rstd * g.y + be.y;
  float y2 = (v.z - mu) * rstd * g.z + be.z;
  float y3 = (v.w - mu) * rstd * g.w + be.w;
  if constexpr (OUTF) {
    float4 o; o.x = y0; o.y = y1; o.z = y2; o.w = y3;
    *(float4*)&outf[(size_t)row * 1024 + t * 4] = o;
  } else {
    ushort4 o; o.x = f2bf(y0); o.y = f2bf(y1); o.z = f2bf(y2); o.w = f2bf(y3);
    *(ushort4*)&outb[(size_t)row * 1024 + t * 4] = o;
  }
}

// ---------------------------------------------------------------------------
extern "C" void kernel_launch(void* const* d_in, const int* in_sizes, int n_in,
                              void* d_out, int out_size, void* d_ws, size_t ws_size,
                              hipStream_t stream) {
  const float* enc = (const float*)d_in[0];
  const float* dec = (const float*)d_in[1];
  const float* src_mask = (const float*)d_in[2];
  const float* tgt_mask = (const float*)d_in[3];
  const float* Wq  = (const float*)d_in[4];  const float* bq  = (const float*)d_in[5];
  const float* Wk  = (const float*)d_in[6];  const float* bk  = (const float*)d_in[7];
  const float* Wv  = (const float*)d_in[8];  const float* bv  = (const float*)d_in[9];
  const float* Wq2 = (const float*)d_in[10]; const float* bq2 = (const float*)d_in[11];
  const float* Wk2 = (const float*)d_in[12]; const float* bk2 = (const float*)d_in[13];
  const float* Wv2 = (const float*)d_in[14]; const float* bv2 = (const float*)d_in[15];
  const float* Wo  = (const float*)d_in[16]; const float* bo  = (const float*)d_in[17];
  const float* gamma = (const float*)d_in[18]; const float* beta = (const float*)d_in[19];
  float* out = (float*)d_out;

  char* p = (char*)d_ws;
  const size_t ABF = (size_t)4096 * 1024 * 2;  // bf16 activation
  const size_t AF  = (size_t)4096 * 1024 * 4;  // f32 activation
  const size_t WBF = (size_t)1024 * 1024 * 2;  // bf16 weight
  u16* decbf = (u16*)p; p += ABF;
  u16* encbf = (u16*)p; p += ABF;
  u16* wt    = (u16*)p; p += 7 * WBF;
  u16* qbf   = (u16*)p; p += ABF;
  float* qf  = (float*)p; p += AF;
  u16* kbf   = (u16*)p; p += ABF;
  u16* vtb   = (u16*)p; p += ABF;
  u16* ctxb  = (u16*)p; p += ABF;
  float* tmpf = (float*)p; p += AF;
  u16* sobf  = decbf;  // reuse: decoder bf16 dead after layer-1 projections

  u16* WqT  = wt + 0 * 1048576;
  u16* WkT  = wt + 1 * 1048576;
  u16* WvT  = wt + 2 * 1048576;
  u16* Wq2T = wt + 3 * 1048576;
  u16* Wk2T = wt + 4 * 1048576;
  u16* Wv2T = wt + 5 * 1048576;
  u16* WoT  = wt + 6 * 1048576;

  dim3 b256(256);
  convert_kernel<<<4096, b256, 0, stream>>>(dec, decbf);
  convert_kernel<<<4096, b256, 0, stream>>>(enc, encbf);
  WP wp;
  wp.w[0] = Wq; wp.w[1] = Wk; wp.w[2] = Wv; wp.w[3] = Wq2;
  wp.w[4] = Wk2; wp.w[5] = Wv2; wp.w[6] = Wo;
  transpose_kernel<<<dim3(16, 16, 7), b256, 0, stream>>>(wp, wt);

  dim3 gg(8, 32);
  // ---- layer 1 (self-attention on decoder inputs) ----
  gemm_kernel<1><<<gg, b256, 0, stream>>>(decbf, WqT, bq, nullptr, qbf, qf);
  gemm_kernel<0><<<gg, b256, 0, stream>>>(decbf, WkT, bk, nullptr, kbf, nullptr);
  gemm_kernel<2><<<gg, b256, 0, stream>>>(decbf, WvT, bv, nullptr, vtb, nullptr);
  attn_kernel<<<dim3(16, 64), b256, 0, stream>>>(qbf, kbf, vtb, tgt_mask, ctxb);
  gemm_kernel<3><<<gg, b256, 0, stream>>>(ctxb, WoT, bo, qf, nullptr, tmpf);
  ln_kernel<0><<<4096, b256, 0, stream>>>(tmpf, gamma, beta, nullptr, sobf);
  // ---- layer 2 (cross-attention vs encoder states) ----
  gemm_kernel<1><<<gg, b256, 0, stream>>>(sobf, Wq2T, bq2, nullptr, qbf, qf);
  gemm_kernel<0><<<gg, b256, 0, stream>>>(encbf, Wk2T, bk2, nullptr, kbf, nullptr);
  gemm_kernel<2><<<gg, b256, 0, stream>>>(encbf, Wv2T, bv2, nullptr, vtb, nullptr);
  attn_kernel<<<dim3(16, 64), b256, 0, stream>>>(qbf, kbf, vtb, src_mask, ctxb);
  gemm_kernel<3><<<gg, b256, 0, stream>>>(ctxb, WoT, bo, qf, nullptr, tmpf);
  ln_kernel<1><<<4096, b256, 0, stream>>>(tmpf, gamma, beta, out, nullptr);
}

// Round 2
// 317.968 us; speedup vs baseline: 1.2394x; 1.2394x over previous
//
#include <hip/hip_runtime.h>
#include <stdint.h>

// ---------------------------------------------------------------------------
// AlbertDecoderAttention on MI355X (gfx950) — round 2
// Changes vs round 1:
//  * attn: XOR-swizzled K/V/P LDS (kills 16-way bank conflicts), barrier count
//    4->2 per tile, alpha/lsum broadcast via cndmask+shfl instead of LDS.
//  * GEMM fusion: layer1 QKV as one N=3072 GEMM; layer2 K2V2 as one N=2048
//    GEMM (occupancy 1 -> 3 and 2 blocks/CU).
// ---------------------------------------------------------------------------

typedef unsigned short u16;
typedef __bf16 bf16x8 __attribute__((ext_vector_type(8)));
typedef float f32x4 __attribute__((ext_vector_type(4)));

#define AS1 __attribute__((address_space(1)))
#define AS3 __attribute__((address_space(3)))

__device__ __forceinline__ u16 f2bf(float f) {
  union { float f; uint32_t u; } v; v.f = f;
  uint32_t u = v.u;
  return (u16)((u + 0x7fffu + ((u >> 16) & 1u)) >> 16);  // RNE
}

__device__ __forceinline__ void gl_lds16(const void* g, void* l) {
  __builtin_amdgcn_global_load_lds((AS1 void*)(g), (AS3 void*)(l), 16, 0, 0);
}

// swizzled byte address within a [rows][128B] LDS tile (involution on bits 4-6)
__device__ __forceinline__ int swz(int row, int byte) {
  return row * 128 + (byte ^ ((row & 7) << 4));
}

// ---------------------------------------------------------------------------
// f32 -> bf16 convert (exact grid: n = blocks*256*4)
// ---------------------------------------------------------------------------
__global__ void __launch_bounds__(256)
convert_kernel(const float* __restrict__ in, u16* __restrict__ out) {
  const int i = blockIdx.x * 256 + threadIdx.x;
  float4 v = ((const float4*)in)[i];
  ushort4 o;
  o.x = f2bf(v.x); o.y = f2bf(v.y); o.z = f2bf(v.z); o.w = f2bf(v.w);
  ((ushort4*)out)[i] = o;
}

// ---------------------------------------------------------------------------
// Weight transpose + convert: W[k][n] f32 -> Wt[n][k] bf16 (7 matrices)
// ---------------------------------------------------------------------------
struct WP { const float* w[7]; };

__global__ void __launch_bounds__(256)
transpose_kernel(WP wp, u16* __restrict__ out) {
  __shared__ float tile[64][65];
  const float* W = wp.w[blockIdx.z];
  u16* Wt = out + (size_t)blockIdx.z * 1024 * 1024;
  const int k0 = blockIdx.y * 64, n0 = blockIdx.x * 64;
  const int t = threadIdx.x;
  const int r = t >> 4, c4 = (t & 15) * 4;
#pragma unroll
  for (int rr = 0; rr < 64; rr += 16) {
    float4 v = *(const float4*)&W[(size_t)(k0 + r + rr) * 1024 + n0 + c4];
    tile[r + rr][c4 + 0] = v.x; tile[r + rr][c4 + 1] = v.y;
    tile[r + rr][c4 + 2] = v.z; tile[r + rr][c4 + 3] = v.w;
  }
  __syncthreads();
  const int n = t >> 2, seg = (t & 3) * 16;
  union { u16 s[16]; uint4 q[2]; } u;
#pragma unroll
  for (int i = 0; i < 16; ++i) u.s[i] = f2bf(tile[seg + i][n]);
  uint4* dst = (uint4*)&Wt[(size_t)(n0 + n) * 1024 + k0 + seg];
  dst[0] = u.q[0]; dst[1] = u.q[1];
}

// ---------------------------------------------------------------------------
// Shared GEMM core: 128x128 tile, BK=64, 4 waves (2x2), 4x4 16x16x32 frags.
// Epilogue variants via policy ints. A[4096][1024] bf16 x Bt[n][k] bf16.
// ---------------------------------------------------------------------------
__device__ __forceinline__ void gemm_core(
    const u16* __restrict__ A, const u16* __restrict__ Bt,
    int bm, int bn, int wv, int ln, u16* Alds, u16* Blds, f32x4 acc[4][4]) {
  const int wm = (wv >> 1) * 64, wn = (wv & 1) * 64;
  const int lcol = ln & 15, lk8 = (ln >> 4) * 8;
  for (int k0 = 0; k0 < 1024; k0 += 64) {
#pragma unroll
    for (int c = 0; c < 4; ++c) {
      const int o = c * 4096 + wv * 1024 + ln * 16;
      const int row = o >> 7, colb = o & 127;
      gl_lds16((const char*)A + ((size_t)(bm + row) * 1024 + k0) * 2 + colb,
               (char*)Alds + c * 4096 + wv * 1024);
      gl_lds16((const char*)Bt + ((size_t)(bn + row) * 1024 + k0) * 2 + colb,
               (char*)Blds + c * 4096 + wv * 1024);
    }
    __syncthreads();
#pragma unroll
    for (int ks = 0; ks < 2; ++ks) {
      bf16x8 a[4], b[4];
#pragma unroll
      for (int i = 0; i < 4; ++i)
        a[i] = *(const bf16x8*)&Alds[(wm + i * 16 + lcol) * 64 + ks * 32 + lk8];
#pragma unroll
      for (int j = 0; j < 4; ++j)
        b[j] = *(const bf16x8*)&Blds[(wn + j * 16 + lcol) * 64 + ks * 32 + lk8];
#pragma unroll
      for (int i = 0; i < 4; ++i)
#pragma unroll
        for (int j = 0; j < 4; ++j)
          acc[i][j] = __builtin_amdgcn_mfma_f32_16x16x32_bf16(a[i], b[j], acc[i][j], 0, 0, 0);
    }
    __syncthreads();
  }
}

// single-output GEMM.  MODE 1: bf16+f32 out   MODE 3: f32 out = acc+bias+resid
template <int MODE>
__global__ void __launch_bounds__(256)
gemm_kernel(const u16* __restrict__ A, const u16* __restrict__ Bt,
            const float* __restrict__ bias, const float* __restrict__ resid,
            u16* __restrict__ outb, float* __restrict__ outf) {
  __shared__ u16 Alds[128 * 64];
  __shared__ u16 Blds[128 * 64];
  const int bm = blockIdx.y * 128, bn = blockIdx.x * 128;
  const int t = threadIdx.x, wv = t >> 6, ln = t & 63;
  const int wm = (wv >> 1) * 64, wn = (wv & 1) * 64;
  const int lcol = ln & 15, lr4 = (ln >> 4) * 4;
  f32x4 acc[4][4] = {};
  gemm_core(A, Bt, bm, bn, wv, ln, Alds, Blds, acc);
#pragma unroll
  for (int j = 0; j < 4; ++j) {
    const int col = bn + wn + j * 16 + lcol;
    const float bc = bias[col];
#pragma unroll
    for (int i = 0; i < 4; ++i) {
      const int row0 = bm + wm + i * 16 + lr4;
#pragma unroll
      for (int r = 0; r < 4; ++r) {
        const size_t idx = (size_t)(row0 + r) * 1024 + col;
        const float v = acc[i][j][r] + bc;
        if constexpr (MODE == 3) {
          outf[idx] = v + resid[idx];
        } else {
          outb[idx] = f2bf(v); outf[idx] = v;
        }
      }
    }
  }
}

// fused multi-segment GEMM.
// KIND 0 (QKV, N=3072): seg0 -> q (bf16+f32), seg1 -> k (bf16), seg2 -> Vt
// KIND 1 (KV,  N=2048): seg0 -> k (bf16),     seg1 -> Vt
template <int KIND>
__global__ void __launch_bounds__(256)
gemm_fused(const u16* __restrict__ A, const u16* __restrict__ Bt,
           const float* __restrict__ b0, const float* __restrict__ b1,
           const float* __restrict__ b2,
           u16* __restrict__ qb, float* __restrict__ qf,
           u16* __restrict__ kb, u16* __restrict__ vt) {
  __shared__ u16 Alds[128 * 64];
  __shared__ u16 Blds[128 * 64];
  const int bm = blockIdx.y * 128, bn = blockIdx.x * 128;
  const int t = threadIdx.x, wv = t >> 6, ln = t & 63;
  const int wm = (wv >> 1) * 64, wn = (wv & 1) * 64;
  const int lcol = ln & 15, lr4 = (ln >> 4) * 4;
  f32x4 acc[4][4] = {};
  gemm_core(A, Bt, bm, bn, wv, ln, Alds, Blds, acc);

  const int seg = bn >> 10;            // which weight segment
  const int cs = bn & 1023;            // col base within segment
  const float* bias = (seg == 0) ? b0 : (seg == 1) ? b1 : b2;
  const bool isQ = (KIND == 0) && (seg == 0);
  const bool isV = (KIND == 0) ? (seg == 2) : (seg == 1);

#pragma unroll
  for (int j = 0; j < 4; ++j) {
    const int col = cs + wn + j * 16 + lcol;    // within-segment column
    const float bc = bias[col];
#pragma unroll
    for (int i = 0; i < 4; ++i) {
      const int row0 = bm + wm + i * 16 + lr4;
      if (isV) {
        ushort4 o;
        o.x = f2bf(acc[i][j][0] + bc); o.y = f2bf(acc[i][j][1] + bc);
        o.z = f2bf(acc[i][j][2] + bc); o.w = f2bf(acc[i][j][3] + bc);
        const int b = row0 >> 10, s = row0 & 1023;
        const int h = col >> 6, d = col & 63;
        *(ushort4*)&vt[(((size_t)(b * 16 + h) * 64 + d) << 10) + s] = o;
      } else if (isQ) {
#pragma unroll
        for (int r = 0; r < 4; ++r) {
          const size_t idx = (size_t)(row0 + r) * 1024 + col;
          const float v = acc[i][j][r] + bc;
          qb[idx] = f2bf(v); qf[idx] = v;
        }
      } else {
#pragma unroll
        for (int r = 0; r < 4; ++r) {
          const size_t idx = (size_t)(row0 + r) * 1024 + col;
          kb[idx] = f2bf(acc[i][j][r] + bc);
        }
      }
    }
  }
}

// ---------------------------------------------------------------------------
// Flash attention: grid (T/64, B*H); 4 waves x 16 q-rows. Swizzled LDS.
// Q,K bf16 [B,T,HID]; Vt bf16 [B,H,DH,S]; mask f32 [B,S]; ctx bf16 [B,T,HID].
// ---------------------------------------------------------------------------
__global__ void __launch_bounds__(256)
attn_kernel(const u16* __restrict__ Q, const u16* __restrict__ Kb,
            const u16* __restrict__ Vt, const float* __restrict__ mask,
            u16* __restrict__ ctx) {
  __shared__ u16 Klds[64 * 64];      // [s][d], swizzled
  __shared__ u16 Vlds[64 * 64];      // [d][s], swizzled
  __shared__ u16 Plds[4][16 * 64];   // per-wave [q][s], swizzled

  const int bh = blockIdx.y, b = bh >> 4, h = bh & 15;
  const int q0 = blockIdx.x * 64;
  const int t = threadIdx.x, wv = t >> 6, ln = t & 63;
  const int lcol = ln & 15, lk8 = (ln >> 4) * 8, lr4 = (ln >> 4) * 4;
  const int c0 = (ln >> 4) * 16;     // 16B-chunk byte base for frag reads

  const int qrow = q0 + wv * 16 + lcol;
  const u16* qptr = Q + ((size_t)(b * 1024 + qrow) * 1024 + h * 64);
  bf16x8 qa[2];
  qa[0] = *(const bf16x8*)(qptr + lk8);
  qa[1] = *(const bf16x8*)(qptr + 32 + lk8);

  char* pbase = (char*)&Plds[wv][0];

  f32x4 accO[4] = {};
  float m_r[4] = {-1e30f, -1e30f, -1e30f, -1e30f};
  float l_r[4] = {};

  for (int s0 = 0; s0 < 1024; s0 += 64) {
    __syncthreads();  // all waves done reading K/V of previous tile
#pragma unroll
    for (int c = 0; c < 2; ++c) {
      const int o = c * 4096 + wv * 1024 + ln * 16;
      const int row = o >> 7;
      const int src_cb = (o & 127) ^ ((row & 7) << 4);  // inverse-swizzle src
      gl_lds16((const char*)Kb + ((size_t)((b * 1024 + s0 + row) * 1024 + h * 64)) * 2 + src_cb,
               (char*)Klds + c * 4096 + wv * 1024);
      gl_lds16((const char*)Vt + ((size_t)(((b * 16 + h) * 64 + row) * 1024 + s0)) * 2 + src_cb,
               (char*)Vlds + c * 4096 + wv * 1024);
    }
    __syncthreads();

    // QK^T -> S[16q][64s] per wave
    f32x4 accS[4] = {};
#pragma unroll
    for (int ks = 0; ks < 2; ++ks)
#pragma unroll
      for (int sc = 0; sc < 4; ++sc) {
        bf16x8 kb = *(const bf16x8*)((const char*)Klds + swz(sc * 16 + lcol, ks * 64 + c0));
        accS[sc] = __builtin_amdgcn_mfma_f32_16x16x32_bf16(qa[ks], kb, accS[sc], 0, 0, 0);
      }

    float sv[4][4];
#pragma unroll
    for (int sc = 0; sc < 4; ++sc) {
      const float mk = mask[b * 1024 + s0 + sc * 16 + lcol];
#pragma unroll
      for (int r = 0; r < 4; ++r) sv[sc][r] = accS[sc][r] * 0.125f + mk;
    }
    float mt[4];
#pragma unroll
    for (int r = 0; r < 4; ++r)
      mt[r] = fmaxf(fmaxf(sv[0][r], sv[1][r]), fmaxf(sv[2][r], sv[3][r]));
#pragma unroll
    for (int off = 1; off < 16; off <<= 1)
#pragma unroll
      for (int r = 0; r < 4; ++r) mt[r] = fmaxf(mt[r], __shfl_xor(mt[r], off));

    float al[4], rs[4];
#pragma unroll
    for (int r = 0; r < 4; ++r) {
      const float mn = fmaxf(m_r[r], mt[r]);
      al[r] = __expf(m_r[r] - mn);
      m_r[r] = mn;
      rs[r] = 0.f;
    }
#pragma unroll
    for (int sc = 0; sc < 4; ++sc)
#pragma unroll
      for (int r = 0; r < 4; ++r) {
        const float pp = __expf(sv[sc][r] - m_r[r]);
        sv[sc][r] = pp;
        rs[r] += pp;
      }
#pragma unroll
    for (int off = 1; off < 16; off <<= 1)
#pragma unroll
      for (int r = 0; r < 4; ++r) rs[r] += __shfl_xor(rs[r], off);
#pragma unroll
    for (int r = 0; r < 4; ++r) l_r[r] = l_r[r] * al[r] + rs[r];

    // P -> LDS (swizzled); per-wave buffer, no barrier needed
#pragma unroll
    for (int sc = 0; sc < 4; ++sc)
#pragma unroll
      for (int r = 0; r < 4; ++r)
        *(u16*)(pbase + swz(lr4 + r, (sc * 16 + lcol) * 2)) = f2bf(sv[sc][r]);

    // broadcast alpha for q=lcol: group lcol>>2 holds it at reg lcol&3
    const int k2 = lcol & 3;
    float a_sel = (k2 & 2) ? ((k2 & 1) ? al[3] : al[2])
                           : ((k2 & 1) ? al[1] : al[0]);
    const float av = __shfl(a_sel, ((lcol >> 2) << 4) | k2);
#pragma unroll
    for (int df = 0; df < 4; ++df)
#pragma unroll
      for (int r = 0; r < 4; ++r) accO[df][r] *= av;

#pragma unroll
    for (int ks = 0; ks < 2; ++ks) {
      bf16x8 pb = *(const bf16x8*)(pbase + swz(lcol, ks * 64 + c0));
#pragma unroll
      for (int df = 0; df < 4; ++df) {
        bf16x8 va = *(const bf16x8*)((const char*)Vlds + swz(df * 16 + lcol, ks * 64 + c0));
        accO[df] = __builtin_amdgcn_mfma_f32_16x16x32_bf16(va, pb, accO[df], 0, 0, 0);
      }
    }
  }

  // broadcast l for q=lcol (same pattern as alpha)
  const int k2 = lcol & 3;
  float l_sel = (k2 & 2) ? ((k2 & 1) ? l_r[3] : l_r[2])
                         : ((k2 & 1) ? l_r[1] : l_r[0]);
  const float inv = 1.0f / __shfl(l_sel, ((lcol >> 2) << 4) | k2);
  u16* cp = ctx + ((size_t)(b * 1024 + qrow) * 1024 + h * 64);
#pragma unroll
  for (int df = 0; df < 4; ++df) {
    ushort4 o;
    o.x = f2bf(accO[df][0] * inv); o.y = f2bf(accO[df][1] * inv);
    o.z = f2bf(accO[df][2] * inv); o.w = f2bf(accO[df][3] * inv);
    *(ushort4*)(cp + df * 16 + lr4) = o;
  }
}

// ---------------------------------------------------------------------------
// LayerNorm over rows of x[4096][1024]; OUTF=1 -> f32 out, else bf16 out
// ---------------------------------------------------------------------------
template <int OUTF>
__global__ void __launch_bounds__(256)
ln_kernel(const float* __restrict__ x, const float* __restrict__ gamma,
          const float* __restrict__ beta, float* __restrict__ outf,
          u16* __restrict__ outb) {
  const int row = blockIdx.x, t = threadIdx.x;
  const float* xr = x + (size_t)row * 1024;
  float4 v = *(const float4*)&xr[t * 4];
  float s = v.x + v.y + v.z + v.w;
  float q = v.x * v.x + v.y * v.y + v.z * v.z + v.w * v.w;
#pragma unroll
  for (int off = 1; off < 64; off <<= 1) {
    s += __shfl_xor(s, off);
    q += __shfl_xor(q, off);
  }
  __shared__ float ws[4], wq[4];
  if ((t & 63) == 0) { ws[t >> 6] = s; wq[t >> 6] = q; }
  __syncthreads();
  s = ws[0] + ws[1] + ws[2] + ws[3];
  q = wq[0] + wq[1] + wq[2] + wq[3];
  const float mu = s * (1.0f / 1024.0f);
  float var = q * (1.0f / 1024.0f) - mu * mu;
  var = fmaxf(var, 0.0f);
  const float rstd = rsqrtf(var + 1e-12f);
  float4 g = *(const float4*)&gamma[t * 4];
  float4 be = *(const float4*)&beta[t * 4];
  float y0 = (v.x - mu) * rstd * g.x + be.x;
  float y1 = (v.y - mu) * rstd * g.y + be.y;
  float y2 = (v.z - mu) * rstd * g.z + be.z;
  float y3 = (v.w - mu) * rstd * g.w + be.w;
  if constexpr (OUTF) {
    float4 o; o.x = y0; o.y = y1; o.z = y2; o.w = y3;
    *(float4*)&outf[(size_t)row * 1024 + t * 4] = o;
  } else {
    ushort4 o; o.x = f2bf(y0); o.y = f2bf(y1); o.z = f2bf(y2); o.w = f2bf(y3);
    *(ushort4*)&outb[(size_t)row * 1024 + t * 4] = o;
  }
}

// ---------------------------------------------------------------------------
extern "C" void kernel_launch(void* const* d_in, const int* in_sizes, int n_in,
                              void* d_out, int out_size, void* d_ws, size_t ws_size,
                              hipStream_t stream) {
  const float* enc = (const float*)d_in[0];
  const float* dec = (const float*)d_in[1];
  const float* src_mask = (const float*)d_in[2];
  const float* tgt_mask = (const float*)d_in[3];
  const float* Wq  = (const float*)d_in[4];  const float* bq  = (const float*)d_in[5];
  const float* Wk  = (const float*)d_in[6];  const float* bk  = (const float*)d_in[7];
  const float* Wv  = (const float*)d_in[8];  const float* bv  = (const float*)d_in[9];
  const float* Wq2 = (const float*)d_in[10]; const float* bq2 = (const float*)d_in[11];
  const float* Wk2 = (const float*)d_in[12]; const float* bk2 = (const float*)d_in[13];
  const float* Wv2 = (const float*)d_in[14]; const float* bv2 = (const float*)d_in[15];
  const float* Wo  = (const float*)d_in[16]; const float* bo  = (const float*)d_in[17];
  const float* gamma = (const float*)d_in[18]; const float* beta = (const float*)d_in[19];
  float* out = (float*)d_out;

  char* p = (char*)d_ws;
  const size_t ABF = (size_t)4096 * 1024 * 2;  // bf16 activation
  const size_t AF  = (size_t)4096 * 1024 * 4;  // f32 activation
  const size_t WBF = (size_t)1024 * 1024 * 2;  // bf16 weight
  u16* decbf = (u16*)p; p += ABF;
  u16* encbf = (u16*)p; p += ABF;
  u16* wt    = (u16*)p; p += 7 * WBF;
  u16* qbf   = (u16*)p; p += ABF;
  float* qf  = (float*)p; p += AF;
  u16* kbf   = (u16*)p; p += ABF;
  u16* vtb   = (u16*)p; p += ABF;
  u16* ctxb  = (u16*)p; p += ABF;
  float* tmpf = (float*)p; p += AF;
  u16* sobf  = decbf;  // reuse: decoder bf16 dead after layer-1 projections

  u16* WqT  = wt + 0 * 1048576;
  u16* Wq2T = wt + 3 * 1048576;
  u16* Wk2T = wt + 4 * 1048576;
  u16* WoT  = wt + 6 * 1048576;

  dim3 b256(256);
  convert_kernel<<<4096, b256, 0, stream>>>(dec, decbf);
  convert_kernel<<<4096, b256, 0, stream>>>(enc, encbf);
  WP wp;
  wp.w[0] = Wq; wp.w[1] = Wk; wp.w[2] = Wv; wp.w[3] = Wq2;
  wp.w[4] = Wk2; wp.w[5] = Wv2; wp.w[6] = Wo;
  transpose_kernel<<<dim3(16, 16, 7), b256, 0, stream>>>(wp, wt);

  // ---- layer 1 (self-attention on decoder inputs) ----
  gemm_fused<0><<<dim3(24, 32), b256, 0, stream>>>(decbf, WqT, bq, bk, bv,
                                                   qbf, qf, kbf, vtb);
  attn_kernel<<<dim3(16, 64), b256, 0, stream>>>(qbf, kbf, vtb, tgt_mask, ctxb);
  gemm_kernel<3><<<dim3(8, 32), b256, 0, stream>>>(ctxb, WoT, bo, qf, nullptr, tmpf);
  ln_kernel<0><<<4096, b256, 0, stream>>>(tmpf, gamma, beta, nullptr, sobf);
  // ---- layer 2 (cross-attention vs encoder states) ----
  gemm_kernel<1><<<dim3(8, 32), b256, 0, stream>>>(sobf, Wq2T, bq2, nullptr, qbf, qf);
  gemm_fused<1><<<dim3(16, 32), b256, 0, stream>>>(encbf, Wk2T, bk2, bv2, nullptr,
                                                   nullptr, nullptr, kbf, vtb);
  attn_kernel<<<dim3(16, 64), b256, 0, stream>>>(qbf, kbf, vtb, src_mask, ctxb);
  gemm_kernel<3><<<dim3(8, 32), b256, 0, stream>>>(ctxb, WoT, bo, qf, nullptr, tmpf);
  ln_kernel<1><<<4096, b256, 0, stream>>>(tmpf, gamma, beta, out, nullptr);
}

// Round 3
// 304.670 us; speedup vs baseline: 1.2935x; 1.0436x over previous
//
#include <hip/hip_runtime.h>
#include <stdint.h>

// ---------------------------------------------------------------------------
// AlbertDecoderAttention on MI355X (gfx950) — round 3
// Changes vs round 2:
//  * attn: swapped QK^T (mfma(K,Q)) -> softmax fully lane-local (2 shfl/tile,
//    1 exp for alpha, no broadcasts); P packed via v_cvt_pk_bf16_f32 into
//    ds_write_b64; K/V double-buffered with early STAGE issue (T3-minimum);
//    XCD-grouped 1D grid (16 q-blocks of a (b,h) on one XCD).
//  * GEMM core: T3-minimum double-buffer (stage next tile during compute).
// ---------------------------------------------------------------------------

typedef unsigned short u16;
typedef __bf16 bf16x8 __attribute__((ext_vector_type(8)));
typedef float f32x4 __attribute__((ext_vector_type(4)));

#define AS1 __attribute__((address_space(1)))
#define AS3 __attribute__((address_space(3)))

__device__ __forceinline__ u16 f2bf(float f) {
  union { float f; uint32_t u; } v; v.f = f;
  uint32_t u = v.u;
  return (u16)((u + 0x7fffu + ((u >> 16) & 1u)) >> 16);  // RNE
}

__device__ __forceinline__ uint32_t cvt_pk_bf16(float lo, float hi) {
  uint32_t r;
  asm("v_cvt_pk_bf16_f32 %0, %1, %2" : "=v"(r) : "v"(lo), "v"(hi));
  return r;  // lo -> bits[15:0], hi -> bits[31:16]
}

__device__ __forceinline__ void gl_lds16(const void* g, void* l) {
  __builtin_amdgcn_global_load_lds((AS1 void*)(g), (AS3 void*)(l), 16, 0, 0);
}

// swizzled byte address within a [rows][128B] LDS tile (involution on bits 4-6)
__device__ __forceinline__ int swz(int row, int byte) {
  return row * 128 + (byte ^ ((row & 7) << 4));
}

// ---------------------------------------------------------------------------
// f32 -> bf16 convert (exact grid: n = blocks*256*4)
// ---------------------------------------------------------------------------
__global__ void __launch_bounds__(256)
convert_kernel(const float* __restrict__ in, u16* __restrict__ out) {
  const int i = blockIdx.x * 256 + threadIdx.x;
  float4 v = ((const float4*)in)[i];
  ushort4 o;
  o.x = f2bf(v.x); o.y = f2bf(v.y); o.z = f2bf(v.z); o.w = f2bf(v.w);
  ((ushort4*)out)[i] = o;
}

// ---------------------------------------------------------------------------
// Weight transpose + convert: W[k][n] f32 -> Wt[n][k] bf16 (7 matrices)
// ---------------------------------------------------------------------------
struct WP { const float* w[7]; };

__global__ void __launch_bounds__(256)
transpose_kernel(WP wp, u16* __restrict__ out) {
  __shared__ float tile[64][65];
  const float* W = wp.w[blockIdx.z];
  u16* Wt = out + (size_t)blockIdx.z * 1024 * 1024;
  const int k0 = blockIdx.y * 64, n0 = blockIdx.x * 64;
  const int t = threadIdx.x;
  const int r = t >> 4, c4 = (t & 15) * 4;
#pragma unroll
  for (int rr = 0; rr < 64; rr += 16) {
    float4 v = *(const float4*)&W[(size_t)(k0 + r + rr) * 1024 + n0 + c4];
    tile[r + rr][c4 + 0] = v.x; tile[r + rr][c4 + 1] = v.y;
    tile[r + rr][c4 + 2] = v.z; tile[r + rr][c4 + 3] = v.w;
  }
  __syncthreads();
  const int n = t >> 2, seg = (t & 3) * 16;
  union { u16 s[16]; uint4 q[2]; } u;
#pragma unroll
  for (int i = 0; i < 16; ++i) u.s[i] = f2bf(tile[seg + i][n]);
  uint4* dst = (uint4*)&Wt[(size_t)(n0 + n) * 1024 + k0 + seg];
  dst[0] = u.q[0]; dst[1] = u.q[1];
}

// ---------------------------------------------------------------------------
// Shared GEMM core: 128x128 tile, BK=64, 4 waves (2x2), 4x4 16x16x32 frags.
// Double-buffered LDS: STAGE(next) issued before compute(cur); single
// barrier per K-step (drains vmcnt).  A[4096][1024] bf16 x Bt[n][k] bf16.
// ---------------------------------------------------------------------------
__device__ __forceinline__ void gemm_core(
    const u16* __restrict__ A, const u16* __restrict__ Bt,
    int bm, int bn, int wv, int ln, u16* Alds, u16* Blds, f32x4 acc[4][4]) {
  const int wm = (wv >> 1) * 64, wn = (wv & 1) * 64;
  const int lcol = ln & 15, lk8 = (ln >> 4) * 8;

  auto STAGE = [&](int buf, int k0) {
#pragma unroll
    for (int c = 0; c < 4; ++c) {
      const int o = c * 4096 + wv * 1024 + ln * 16;
      const int row = o >> 7, colb = o & 127;
      gl_lds16((const char*)A + ((size_t)(bm + row) * 1024 + k0) * 2 + colb,
               (char*)Alds + buf * 16384 + c * 4096 + wv * 1024);
      gl_lds16((const char*)Bt + ((size_t)(bn + row) * 1024 + k0) * 2 + colb,
               (char*)Blds + buf * 16384 + c * 4096 + wv * 1024);
    }
  };

  STAGE(0, 0);
  __syncthreads();  // drains vmcnt(0) then barrier
  int cur = 0;
  for (int it = 0; it < 16; ++it) {
    if (it < 15) STAGE(cur ^ 1, (it + 1) * 64);
    const u16* Ab = Alds + cur * 8192;
    const u16* Bb = Blds + cur * 8192;
#pragma unroll
    for (int ks = 0; ks < 2; ++ks) {
      bf16x8 a[4], b[4];
#pragma unroll
      for (int i = 0; i < 4; ++i)
        a[i] = *(const bf16x8*)&Ab[(wm + i * 16 + lcol) * 64 + ks * 32 + lk8];
#pragma unroll
      for (int j = 0; j < 4; ++j)
        b[j] = *(const bf16x8*)&Bb[(wn + j * 16 + lcol) * 64 + ks * 32 + lk8];
#pragma unroll
      for (int i = 0; i < 4; ++i)
#pragma unroll
        for (int j = 0; j < 4; ++j)
          acc[i][j] = __builtin_amdgcn_mfma_f32_16x16x32_bf16(a[i], b[j], acc[i][j], 0, 0, 0);
    }
    __syncthreads();  // staged buf ready; all waves done reading cur
    cur ^= 1;
  }
}

// single-output GEMM.  MODE 1: bf16+f32 out   MODE 3: f32 out = acc+bias+resid
template <int MODE>
__global__ void __launch_bounds__(256)
gemm_kernel(const u16* __restrict__ A, const u16* __restrict__ Bt,
            const float* __restrict__ bias, const float* __restrict__ resid,
            u16* __restrict__ outb, float* __restrict__ outf) {
  __shared__ u16 Alds[2 * 8192];
  __shared__ u16 Blds[2 * 8192];
  const int bm = blockIdx.y * 128, bn = blockIdx.x * 128;
  const int t = threadIdx.x, wv = t >> 6, ln = t & 63;
  const int wm = (wv >> 1) * 64, wn = (wv & 1) * 64;
  const int lcol = ln & 15, lr4 = (ln >> 4) * 4;
  f32x4 acc[4][4] = {};
  gemm_core(A, Bt, bm, bn, wv, ln, Alds, Blds, acc);
#pragma unroll
  for (int j = 0; j < 4; ++j) {
    const int col = bn + wn + j * 16 + lcol;
    const float bc = bias[col];
#pragma unroll
    for (int i = 0; i < 4; ++i) {
      const int row0 = bm + wm + i * 16 + lr4;
#pragma unroll
      for (int r = 0; r < 4; ++r) {
        const size_t idx = (size_t)(row0 + r) * 1024 + col;
        const float v = acc[i][j][r] + bc;
        if constexpr (MODE == 3) {
          outf[idx] = v + resid[idx];
        } else {
          outb[idx] = f2bf(v); outf[idx] = v;
        }
      }
    }
  }
}

// fused multi-segment GEMM.
// KIND 0 (QKV, N=3072): seg0 -> q (bf16+f32), seg1 -> k (bf16), seg2 -> Vt
// KIND 1 (KV,  N=2048): seg0 -> k (bf16),     seg1 -> Vt
template <int KIND>
__global__ void __launch_bounds__(256)
gemm_fused(const u16* __restrict__ A, const u16* __restrict__ Bt,
           const float* __restrict__ b0, const float* __restrict__ b1,
           const float* __restrict__ b2,
           u16* __restrict__ qb, float* __restrict__ qf,
           u16* __restrict__ kb, u16* __restrict__ vt) {
  __shared__ u16 Alds[2 * 8192];
  __shared__ u16 Blds[2 * 8192];
  const int bm = blockIdx.y * 128, bn = blockIdx.x * 128;
  const int t = threadIdx.x, wv = t >> 6, ln = t & 63;
  const int wm = (wv >> 1) * 64, wn = (wv & 1) * 64;
  const int lcol = ln & 15, lr4 = (ln >> 4) * 4;
  f32x4 acc[4][4] = {};
  gemm_core(A, Bt, bm, bn, wv, ln, Alds, Blds, acc);

  const int seg = bn >> 10;            // which weight segment
  const int cs = bn & 1023;            // col base within segment
  const float* bias = (seg == 0) ? b0 : (seg == 1) ? b1 : b2;
  const bool isQ = (KIND == 0) && (seg == 0);
  const bool isV = (KIND == 0) ? (seg == 2) : (seg == 1);

#pragma unroll
  for (int j = 0; j < 4; ++j) {
    const int col = cs + wn + j * 16 + lcol;    // within-segment column
    const float bc = bias[col];
#pragma unroll
    for (int i = 0; i < 4; ++i) {
      const int row0 = bm + wm + i * 16 + lr4;
      if (isV) {
        ushort4 o;
        o.x = f2bf(acc[i][j][0] + bc); o.y = f2bf(acc[i][j][1] + bc);
        o.z = f2bf(acc[i][j][2] + bc); o.w = f2bf(acc[i][j][3] + bc);
        const int b = row0 >> 10, s = row0 & 1023;
        const int h = col >> 6, d = col & 63;
        *(ushort4*)&vt[(((size_t)(b * 16 + h) * 64 + d) << 10) + s] = o;
      } else if (isQ) {
#pragma unroll
        for (int r = 0; r < 4; ++r) {
          const size_t idx = (size_t)(row0 + r) * 1024 + col;
          const float v = acc[i][j][r] + bc;
          qb[idx] = f2bf(v); qf[idx] = v;
        }
      } else {
#pragma unroll
        for (int r = 0; r < 4; ++r) {
          const size_t idx = (size_t)(row0 + r) * 1024 + col;
          kb[idx] = f2bf(acc[i][j][r] + bc);
        }
      }
    }
  }
}

// ---------------------------------------------------------------------------
// Flash attention, swapped-QK^T: grid 1024 blocks 1D (XCD-grouped),
// 4 waves x 16 q-rows, KV tile 64, double-buffered K/V LDS.
// Q,K bf16 [B,T,HID]; Vt bf16 [B,H,DH,S]; mask f32 [B,S]; ctx bf16 [B,T,HID].
// S^T layout: accST[sb] row = s_local = sb*16 + g*4 + r, col = q = lane&15.
// ---------------------------------------------------------------------------
__global__ void __launch_bounds__(256)
attn_kernel(const u16* __restrict__ Q, const u16* __restrict__ Kb,
            const u16* __restrict__ Vt, const float* __restrict__ mask,
            u16* __restrict__ ctx) {
  __shared__ u16 Klds[2][64 * 64];   // [s][d], swizzled
  __shared__ u16 Vlds[2][64 * 64];   // [d][s], swizzled
  __shared__ u16 Plds[4][16 * 64];   // per-wave [q][s], swizzled

  // XCD-grouped mapping: 16 q-blocks of one (b,h) on one XCD
  const int fid = blockIdx.x;
  const int xcd = fid & 7, idx = fid >> 3;
  const int bh = xcd * 8 + (idx >> 4);
  const int b = bh >> 4, h = bh & 15;
  const int q0 = (idx & 15) * 64;

  const int t = threadIdx.x, wv = t >> 6, ln = t & 63;
  const int lcol = ln & 15, g = ln >> 4;
  const int lk8 = g * 8, c0 = g * 16;

  const int qrow = q0 + wv * 16 + lcol;
  const u16* qptr = Q + ((size_t)(b * 1024 + qrow) * 1024 + h * 64);
  bf16x8 qa[2];
  qa[0] = *(const bf16x8*)(qptr + lk8);
  qa[1] = *(const bf16x8*)(qptr + 32 + lk8);

  char* pbase = (char*)&Plds[wv][0];

  f32x4 accO[4] = {};
  float m_r = -1e30f, l_r = 0.f;

  auto STAGE = [&](int buf, int s0) {
#pragma unroll
    for (int c = 0; c < 2; ++c) {
      const int o = c * 4096 + wv * 1024 + ln * 16;
      const int row = o >> 7;
      const int src_cb = (o & 127) ^ ((row & 7) << 4);  // inverse-swizzle src
      gl_lds16((const char*)Kb + ((size_t)((b * 1024 + s0 + row) * 1024 + h * 64)) * 2 + src_cb,
               (char*)Klds[buf] + c * 4096 + wv * 1024);
      gl_lds16((const char*)Vt + ((size_t)(((b * 16 + h) * 64 + row) * 1024 + s0)) * 2 + src_cb,
               (char*)Vlds[buf] + c * 4096 + wv * 1024);
    }
  };

  STAGE(0, 0);
  __syncthreads();
  int cur = 0;
  for (int ti = 0; ti < 16; ++ti) {
    const int s0 = ti * 64;
    if (ti < 15) STAGE(cur ^ 1, s0 + 64);

    // S^T = (K Q^T): accST[sb] = mfma(K-rows, Q-rows)
    f32x4 accST[4] = {};
#pragma unroll
    for (int ks = 0; ks < 2; ++ks)
#pragma unroll
      for (int sb = 0; sb < 4; ++sb) {
        bf16x8 kb = *(const bf16x8*)((const char*)Klds[cur] + swz(sb * 16 + lcol, ks * 64 + c0));
        accST[sb] = __builtin_amdgcn_mfma_f32_16x16x32_bf16(kb, qa[ks], accST[sb], 0, 0, 0);
      }

    // lane-local softmax over 16 s-values (q = lcol fixed per lane)
    float sv[4][4];
#pragma unroll
    for (int sb = 0; sb < 4; ++sb) {
      float4 mk = *(const float4*)&mask[b * 1024 + s0 + sb * 16 + g * 4];
      sv[sb][0] = accST[sb][0] * 0.125f + mk.x;
      sv[sb][1] = accST[sb][1] * 0.125f + mk.y;
      sv[sb][2] = accST[sb][2] * 0.125f + mk.z;
      sv[sb][3] = accST[sb][3] * 0.125f + mk.w;
    }
    float mt = sv[0][0];
#pragma unroll
    for (int sb = 0; sb < 4; ++sb)
#pragma unroll
      for (int r = 0; r < 4; ++r) mt = fmaxf(mt, sv[sb][r]);
    mt = fmaxf(mt, __shfl_xor(mt, 16));
    mt = fmaxf(mt, __shfl_xor(mt, 32));

    const float mn = fmaxf(m_r, mt);
    const float alpha = __expf(m_r - mn);
    m_r = mn;
    float rs = 0.f;
#pragma unroll
    for (int sb = 0; sb < 4; ++sb)
#pragma unroll
      for (int r = 0; r < 4; ++r) {
        const float pp = __expf(sv[sb][r] - mn);
        sv[sb][r] = pp;
        rs += pp;
      }
    rs += __shfl_xor(rs, 16);
    rs += __shfl_xor(rs, 32);
    l_r = l_r * alpha + rs;

    // P^T pack -> Plds[q=lcol][s_local], 4x ds_write_b64
#pragma unroll
    for (int sb = 0; sb < 4; ++sb) {
      uint2 dd;
      dd.x = cvt_pk_bf16(sv[sb][0], sv[sb][1]);
      dd.y = cvt_pk_bf16(sv[sb][2], sv[sb][3]);
      *(uint2*)(pbase + swz(lcol, sb * 32 + g * 8)) = dd;
    }

    // rescale O (col q = lcol is lane-local) then PV
#pragma unroll
    for (int df = 0; df < 4; ++df)
#pragma unroll
      for (int r = 0; r < 4; ++r) accO[df][r] *= alpha;
#pragma unroll
    for (int ks = 0; ks < 2; ++ks) {
      bf16x8 pb = *(const bf16x8*)(pbase + swz(lcol, ks * 64 + c0));
#pragma unroll
      for (int df = 0; df < 4; ++df) {
        bf16x8 va = *(const bf16x8*)((const char*)Vlds[cur] + swz(df * 16 + lcol, ks * 64 + c0));
        accO[df] = __builtin_amdgcn_mfma_f32_16x16x32_bf16(va, pb, accO[df], 0, 0, 0);
      }
    }
    __syncthreads();  // staged next buf ready; all waves done reading cur
    cur ^= 1;
  }

  const float inv = 1.0f / l_r;   // lane-local (q = lcol)
  u16* cp = ctx + ((size_t)(b * 1024 + qrow) * 1024 + h * 64);
#pragma unroll
  for (int df = 0; df < 4; ++df) {
    ushort4 o;
    o.x = f2bf(accO[df][0] * inv); o.y = f2bf(accO[df][1] * inv);
    o.z = f2bf(accO[df][2] * inv); o.w = f2bf(accO[df][3] * inv);
    *(ushort4*)(cp + df * 16 + g * 4) = o;
  }
}

// ---------------------------------------------------------------------------
// LayerNorm over rows of x[4096][1024]; OUTF=1 -> f32 out, else bf16 out
// ---------------------------------------------------------------------------
template <int OUTF>
__global__ void __launch_bounds__(256)
ln_kernel(const float* __restrict__ x, const float* __restrict__ gamma,
          const float* __restrict__ beta, float* __restrict__ outf,
          u16* __restrict__ outb) {
  const int row = blockIdx.x, t = threadIdx.x;
  const float* xr = x + (size_t)row * 1024;
  float4 v = *(const float4*)&xr[t * 4];
  float s = v.x + v.y + v.z + v.w;
  float q = v.x * v.x + v.y * v.y + v.z * v.z + v.w * v.w;
#pragma unroll
  for (int off = 1; off < 64; off <<= 1) {
    s += __shfl_xor(s, off);
    q += __shfl_xor(q, off);
  }
  __shared__ float ws[4], wq[4];
  if ((t & 63) == 0) { ws[t >> 6] = s; wq[t >> 6] = q; }
  __syncthreads();
  s = ws[0] + ws[1] + ws[2] + ws[3];
  q = wq[0] + wq[1] + wq[2] + wq[3];
  const float mu = s * (1.0f / 1024.0f);
  float var = q * (1.0f / 1024.0f) - mu * mu;
  var = fmaxf(var, 0.0f);
  const float rstd = rsqrtf(var + 1e-12f);
  float4 g = *(const float4*)&gamma[t * 4];
  float4 be = *(const float4*)&beta[t * 4];
  float y0 = (v.x - mu) * rstd * g.x + be.x;
  float y1 = (v.y - mu) * rstd * g.y + be.y;
  float y2 = (v.z - mu) * rstd * g.z + be.z;
  float y3 = (v.w - mu) * rstd * g.w + be.w;
  if constexpr (OUTF) {
    float4 o; o.x = y0; o.y = y1; o.z = y2; o.w = y3;
    *(float4*)&outf[(size_t)row * 1024 + t * 4] = o;
  } else {
    ushort4 o; o.x = f2bf(y0); o.y = f2bf(y1); o.z = f2bf(y2); o.w = f2bf(y3);
    *(ushort4*)&outb[(size_t)row * 1024 + t * 4] = o;
  }
}

// ---------------------------------------------------------------------------
extern "C" void kernel_launch(void* const* d_in, const int* in_sizes, int n_in,
                              void* d_out, int out_size, void* d_ws, size_t ws_size,
                              hipStream_t stream) {
  const float* enc = (const float*)d_in[0];
  const float* dec = (const float*)d_in[1];
  const float* src_mask = (const float*)d_in[2];
  const float* tgt_mask = (const float*)d_in[3];
  const float* Wq  = (const float*)d_in[4];  const float* bq  = (const float*)d_in[5];
  const float* Wk  = (const float*)d_in[6];  const float* bk  = (const float*)d_in[7];
  const float* Wv  = (const float*)d_in[8];  const float* bv  = (const float*)d_in[9];
  const float* Wq2 = (const float*)d_in[10]; const float* bq2 = (const float*)d_in[11];
  const float* Wk2 = (const float*)d_in[12]; const float* bk2 = (const float*)d_in[13];
  const float* Wv2 = (const float*)d_in[14]; const float* bv2 = (const float*)d_in[15];
  const float* Wo  = (const float*)d_in[16]; const float* bo  = (const float*)d_in[17];
  const float* gamma = (const float*)d_in[18]; const float* beta = (const float*)d_in[19];
  float* out = (float*)d_out;

  char* p = (char*)d_ws;
  const size_t ABF = (size_t)4096 * 1024 * 2;  // bf16 activation
  const size_t AF  = (size_t)4096 * 1024 * 4;  // f32 activation
  const size_t WBF = (size_t)1024 * 1024 * 2;  // bf16 weight
  u16* decbf = (u16*)p; p += ABF;
  u16* encbf = (u16*)p; p += ABF;
  u16* wt    = (u16*)p; p += 7 * WBF;
  u16* qbf   = (u16*)p; p += ABF;
  float* qf  = (float*)p; p += AF;
  u16* kbf   = (u16*)p; p += ABF;
  u16* vtb   = (u16*)p; p += ABF;
  u16* ctxb  = (u16*)p; p += ABF;
  float* tmpf = (float*)p; p += AF;
  u16* sobf  = decbf;  // reuse: decoder bf16 dead after layer-1 projections

  u16* WqT  = wt + 0 * 1048576;
  u16* Wq2T = wt + 3 * 1048576;
  u16* Wk2T = wt + 4 * 1048576;
  u16* WoT  = wt + 6 * 1048576;

  dim3 b256(256);
  convert_kernel<<<4096, b256, 0, stream>>>(dec, decbf);
  convert_kernel<<<4096, b256, 0, stream>>>(enc, encbf);
  WP wp;
  wp.w[0] = Wq; wp.w[1] = Wk; wp.w[2] = Wv; wp.w[3] = Wq2;
  wp.w[4] = Wk2; wp.w[5] = Wv2; wp.w[6] = Wo;
  transpose_kernel<<<dim3(16, 16, 7), b256, 0, stream>>>(wp, wt);

  // ---- layer 1 (self-attention on decoder inputs) ----
  gemm_fused<0><<<dim3(24, 32), b256, 0, stream>>>(decbf, WqT, bq, bk, bv,
                                                   qbf, qf, kbf, vtb);
  attn_kernel<<<1024, b256, 0, stream>>>(qbf, kbf, vtb, tgt_mask, ctxb);
  gemm_kernel<3><<<dim3(8, 32), b256, 0, stream>>>(ctxb, WoT, bo, qf, nullptr, tmpf);
  ln_kernel<0><<<4096, b256, 0, stream>>>(tmpf, gamma, beta, nullptr, sobf);
  // ---- layer 2 (cross-attention vs encoder states) ----
  gemm_kernel<1><<<dim3(8, 32), b256, 0, stream>>>(sobf, Wq2T, bq2, nullptr, qbf, qf);
  gemm_fused<1><<<dim3(16, 32), b256, 0, stream>>>(encbf, Wk2T, bk2, bv2, nullptr,
                                                   nullptr, nullptr, kbf, vtb);
  attn_kernel<<<1024, b256, 0, stream>>>(qbf, kbf, vtb, src_mask, ctxb);
  gemm_kernel<3><<<dim3(8, 32), b256, 0, stream>>>(ctxb, WoT, bo, qf, nullptr, tmpf);
  ln_kernel<1><<<4096, b256, 0, stream>>>(tmpf, gamma, beta, out, nullptr);
}

// Round 4
// 280.504 us; speedup vs baseline: 1.4049x; 1.0862x over previous
//
#include <hip/hip_runtime.h>
#include <stdint.h>

// ---------------------------------------------------------------------------
// AlbertDecoderAttention on MI355X (gfx950) — round 4
// Changes vs round 3:
//  * Projections: new qkv256 kernel — 256x256 tile, 8 waves (2x4), BK=32,
//    double-buffered 64KB LDS, per-segment A pointer. Handles BOTH layers
//    (layer1: dec x {Wq,Wk,Wv}; layer2: so x Wq2, enc x {Wk2,Wv2}).
//    2x arithmetic intensity per staged byte vs the 128^2 core; grid 192.
//  * Removed gemm_kernel<1>/gemm_fused (replaced by qkv256).
//  * Wo-proj stays 128^2 dbuf (grid 256 = 1 block/CU; LDS size harmless).
//  * attn unchanged from round 3.
// ---------------------------------------------------------------------------

typedef unsigned short u16;
typedef __bf16 bf16x8 __attribute__((ext_vector_type(8)));
typedef float f32x4 __attribute__((ext_vector_type(4)));

#define AS1 __attribute__((address_space(1)))
#define AS3 __attribute__((address_space(3)))

__device__ __forceinline__ u16 f2bf(float f) {
  union { float f; uint32_t u; } v; v.f = f;
  uint32_t u = v.u;
  return (u16)((u + 0x7fffu + ((u >> 16) & 1u)) >> 16);  // RNE
}

__device__ __forceinline__ uint32_t cvt_pk_bf16(float lo, float hi) {
  uint32_t r;
  asm("v_cvt_pk_bf16_f32 %0, %1, %2" : "=v"(r) : "v"(lo), "v"(hi));
  return r;  // lo -> bits[15:0], hi -> bits[31:16]
}

__device__ __forceinline__ void gl_lds16(const void* g, void* l) {
  __builtin_amdgcn_global_load_lds((AS1 void*)(g), (AS3 void*)(l), 16, 0, 0);
}

// swizzled byte address within a [rows][128B] LDS tile (involution on bits 4-6)
__device__ __forceinline__ int swz(int row, int byte) {
  return row * 128 + (byte ^ ((row & 7) << 4));
}

// ---------------------------------------------------------------------------
// f32 -> bf16 convert (exact grid: n = blocks*256*4)
// ---------------------------------------------------------------------------
__global__ void __launch_bounds__(256)
convert_kernel(const float* __restrict__ in, u16* __restrict__ out) {
  const int i = blockIdx.x * 256 + threadIdx.x;
  float4 v = ((const float4*)in)[i];
  ushort4 o;
  o.x = f2bf(v.x); o.y = f2bf(v.y); o.z = f2bf(v.z); o.w = f2bf(v.w);
  ((ushort4*)out)[i] = o;
}

// ---------------------------------------------------------------------------
// Weight transpose + convert: W[k][n] f32 -> Wt[n][k] bf16 (7 matrices)
// ---------------------------------------------------------------------------
struct WP { const float* w[7]; };

__global__ void __launch_bounds__(256)
transpose_kernel(WP wp, u16* __restrict__ out) {
  __shared__ float tile[64][65];
  const float* W = wp.w[blockIdx.z];
  u16* Wt = out + (size_t)blockIdx.z * 1024 * 1024;
  const int k0 = blockIdx.y * 64, n0 = blockIdx.x * 64;
  const int t = threadIdx.x;
  const int r = t >> 4, c4 = (t & 15) * 4;
#pragma unroll
  for (int rr = 0; rr < 64; rr += 16) {
    float4 v = *(const float4*)&W[(size_t)(k0 + r + rr) * 1024 + n0 + c4];
    tile[r + rr][c4 + 0] = v.x; tile[r + rr][c4 + 1] = v.y;
    tile[r + rr][c4 + 2] = v.z; tile[r + rr][c4 + 3] = v.w;
  }
  __syncthreads();
  const int n = t >> 2, seg = (t & 3) * 16;
  union { u16 s[16]; uint4 q[2]; } u;
#pragma unroll
  for (int i = 0; i < 16; ++i) u.s[i] = f2bf(tile[seg + i][n]);
  uint4* dst = (uint4*)&Wt[(size_t)(n0 + n) * 1024 + k0 + seg];
  dst[0] = u.q[0]; dst[1] = u.q[1];
}

// ---------------------------------------------------------------------------
// qkv256: 3-segment projection GEMM, 256x256 tile, BK=32, 8 waves (2Mx4N),
// double-buffered 64KB LDS, per-segment A pointer.
// Bt = [Wseg0|Wseg1|Wseg2] as [3072][1024] bf16 (row = out-col, col = k).
// seg0 -> q (bf16 + f32), seg1 -> k (bf16), seg2 -> Vt[B,H,DH,S] (bf16).
// ---------------------------------------------------------------------------
__global__ void __launch_bounds__(512, 2)
qkv256_kernel(const u16* __restrict__ A0, const u16* __restrict__ A1,
              const u16* __restrict__ A2, const u16* __restrict__ Bt,
              const float* __restrict__ b0, const float* __restrict__ b1,
              const float* __restrict__ b2,
              u16* __restrict__ qb, float* __restrict__ qf,
              u16* __restrict__ kb, u16* __restrict__ vt) {
  __shared__ u16 Alds[2][256 * 32];
  __shared__ u16 Blds[2][256 * 32];
  const int bm = blockIdx.y * 256, bn = blockIdx.x * 256;
  const int seg = bn >> 10;
  const u16* A = (seg == 0) ? A0 : (seg == 1) ? A1 : A2;
  const int t = threadIdx.x, wv = t >> 6, ln = t & 63;
  const int wm = (wv >> 2) * 128, wn = (wv & 3) * 64;
  const int lcol = ln & 15, lk8 = (ln >> 4) * 8, lr4 = (ln >> 4) * 4;

  f32x4 acc[8][4] = {};

  auto STAGE = [&](int buf, int k0) {
#pragma unroll
    for (int c = 0; c < 2; ++c) {
      const int o = c * 8192 + wv * 1024 + ln * 16;
      const int row = o >> 6, colb = o & 63;
      gl_lds16((const char*)A + ((size_t)(bm + row) * 1024 + k0) * 2 + colb,
               (char*)Alds[buf] + c * 8192 + wv * 1024);
      gl_lds16((const char*)Bt + ((size_t)(bn + row) * 1024 + k0) * 2 + colb,
               (char*)Blds[buf] + c * 8192 + wv * 1024);
    }
  };

  STAGE(0, 0);
  __syncthreads();
  int cur = 0;
  for (int it = 0; it < 32; ++it) {
    if (it < 31) STAGE(cur ^ 1, (it + 1) * 32);
    const u16* Ab = Alds[cur];
    const u16* Bb = Blds[cur];
    bf16x8 a[8], b[4];
#pragma unroll
    for (int j = 0; j < 4; ++j)
      b[j] = *(const bf16x8*)&Bb[(wn + j * 16 + lcol) * 32 + lk8];
#pragma unroll
    for (int i = 0; i < 8; ++i)
      a[i] = *(const bf16x8*)&Ab[(wm + i * 16 + lcol) * 32 + lk8];
#pragma unroll
    for (int i = 0; i < 8; ++i)
#pragma unroll
      for (int j = 0; j < 4; ++j)
        acc[i][j] = __builtin_amdgcn_mfma_f32_16x16x32_bf16(a[i], b[j], acc[i][j], 0, 0, 0);
    __syncthreads();
    cur ^= 1;
  }

  const int cs = bn & 1023;
  const float* bias = (seg == 0) ? b0 : (seg == 1) ? b1 : b2;
#pragma unroll
  for (int j = 0; j < 4; ++j) {
    const int col = cs + wn + j * 16 + lcol;
    const float bc = bias[col];
#pragma unroll
    for (int i = 0; i < 8; ++i) {
      const int row0 = bm + wm + i * 16 + lr4;
      if (seg == 2) {
        ushort4 o;
        o.x = f2bf(acc[i][j][0] + bc); o.y = f2bf(acc[i][j][1] + bc);
        o.z = f2bf(acc[i][j][2] + bc); o.w = f2bf(acc[i][j][3] + bc);
        const int b_ = row0 >> 10, s = row0 & 1023;
        const int h = col >> 6, d = col & 63;
        *(ushort4*)&vt[(((size_t)(b_ * 16 + h) * 64 + d) << 10) + s] = o;
      } else if (seg == 0) {
#pragma unroll
        for (int r = 0; r < 4; ++r) {
          const size_t idx = (size_t)(row0 + r) * 1024 + col;
          const float v = acc[i][j][r] + bc;
          qb[idx] = f2bf(v); qf[idx] = v;
        }
      } else {
#pragma unroll
        for (int r = 0; r < 4; ++r) {
          const size_t idx = (size_t)(row0 + r) * 1024 + col;
          kb[idx] = f2bf(acc[i][j][r] + bc);
        }
      }
    }
  }
}

// ---------------------------------------------------------------------------
// Wo-projection GEMM: 128x128 tile, BK=64, 4 waves, double-buffered.
// out f32 = acc + bias + resid (pre-layernorm sum).
// ---------------------------------------------------------------------------
__global__ void __launch_bounds__(256)
gemm_proj(const u16* __restrict__ A, const u16* __restrict__ Bt,
          const float* __restrict__ bias, const float* __restrict__ resid,
          float* __restrict__ outf) {
  __shared__ u16 Alds[2][8192];
  __shared__ u16 Blds[2][8192];
  const int bm = blockIdx.y * 128, bn = blockIdx.x * 128;
  const int t = threadIdx.x, wv = t >> 6, ln = t & 63;
  const int wm = (wv >> 1) * 64, wn = (wv & 1) * 64;
  const int lcol = ln & 15, lk8 = (ln >> 4) * 8, lr4 = (ln >> 4) * 4;

  f32x4 acc[4][4] = {};

  auto STAGE = [&](int buf, int k0) {
#pragma unroll
    for (int c = 0; c < 4; ++c) {
      const int o = c * 4096 + wv * 1024 + ln * 16;
      const int row = o >> 7, colb = o & 127;
      gl_lds16((const char*)A + ((size_t)(bm + row) * 1024 + k0) * 2 + colb,
               (char*)Alds[buf] + c * 4096 + wv * 1024);
      gl_lds16((const char*)Bt + ((size_t)(bn + row) * 1024 + k0) * 2 + colb,
               (char*)Blds[buf] + c * 4096 + wv * 1024);
    }
  };

  STAGE(0, 0);
  __syncthreads();
  int cur = 0;
  for (int it = 0; it < 16; ++it) {
    if (it < 15) STAGE(cur ^ 1, (it + 1) * 64);
    const u16* Ab = Alds[cur];
    const u16* Bb = Blds[cur];
#pragma unroll
    for (int ks = 0; ks < 2; ++ks) {
      bf16x8 a[4], b[4];
#pragma unroll
      for (int i = 0; i < 4; ++i)
        a[i] = *(const bf16x8*)&Ab[(wm + i * 16 + lcol) * 64 + ks * 32 + lk8];
#pragma unroll
      for (int j = 0; j < 4; ++j)
        b[j] = *(const bf16x8*)&Bb[(wn + j * 16 + lcol) * 64 + ks * 32 + lk8];
#pragma unroll
      for (int i = 0; i < 4; ++i)
#pragma unroll
        for (int j = 0; j < 4; ++j)
          acc[i][j] = __builtin_amdgcn_mfma_f32_16x16x32_bf16(a[i], b[j], acc[i][j], 0, 0, 0);
    }
    __syncthreads();
    cur ^= 1;
  }

#pragma unroll
  for (int j = 0; j < 4; ++j) {
    const int col = bn + wn + j * 16 + lcol;
    const float bc = bias[col];
#pragma unroll
    for (int i = 0; i < 4; ++i) {
      const int row0 = bm + wm + i * 16 + lr4;
#pragma unroll
      for (int r = 0; r < 4; ++r) {
        const size_t idx = (size_t)(row0 + r) * 1024 + col;
        outf[idx] = acc[i][j][r] + bc + resid[idx];
      }
    }
  }
}

// ---------------------------------------------------------------------------
// Flash attention, swapped-QK^T: grid 1024 blocks 1D (XCD-grouped),
// 4 waves x 16 q-rows, KV tile 64, double-buffered K/V LDS.
// Q,K bf16 [B,T,HID]; Vt bf16 [B,H,DH,S]; mask f32 [B,S]; ctx bf16 [B,T,HID].
// ---------------------------------------------------------------------------
__global__ void __launch_bounds__(256)
attn_kernel(const u16* __restrict__ Q, const u16* __restrict__ Kb,
            const u16* __restrict__ Vt, const float* __restrict__ mask,
            u16* __restrict__ ctx) {
  __shared__ u16 Klds[2][64 * 64];   // [s][d], swizzled
  __shared__ u16 Vlds[2][64 * 64];   // [d][s], swizzled
  __shared__ u16 Plds[4][16 * 64];   // per-wave [q][s], swizzled

  const int fid = blockIdx.x;
  const int xcd = fid & 7, idx = fid >> 3;
  const int bh = xcd * 8 + (idx >> 4);
  const int b = bh >> 4, h = bh & 15;
  const int q0 = (idx & 15) * 64;

  const int t = threadIdx.x, wv = t >> 6, ln = t & 63;
  const int lcol = ln & 15, g = ln >> 4;
  const int lk8 = g * 8, c0 = g * 16;

  const int qrow = q0 + wv * 16 + lcol;
  const u16* qptr = Q + ((size_t)(b * 1024 + qrow) * 1024 + h * 64);
  bf16x8 qa[2];
  qa[0] = *(const bf16x8*)(qptr + lk8);
  qa[1] = *(const bf16x8*)(qptr + 32 + lk8);

  char* pbase = (char*)&Plds[wv][0];

  f32x4 accO[4] = {};
  float m_r = -1e30f, l_r = 0.f;

  auto STAGE = [&](int buf, int s0) {
#pragma unroll
    for (int c = 0; c < 2; ++c) {
      const int o = c * 4096 + wv * 1024 + ln * 16;
      const int row = o >> 7;
      const int src_cb = (o & 127) ^ ((row & 7) << 4);  // inverse-swizzle src
      gl_lds16((const char*)Kb + ((size_t)((b * 1024 + s0 + row) * 1024 + h * 64)) * 2 + src_cb,
               (char*)Klds[buf] + c * 4096 + wv * 1024);
      gl_lds16((const char*)Vt + ((size_t)(((b * 16 + h) * 64 + row) * 1024 + s0)) * 2 + src_cb,
               (char*)Vlds[buf] + c * 4096 + wv * 1024);
    }
  };

  STAGE(0, 0);
  __syncthreads();
  int cur = 0;
  for (int ti = 0; ti < 16; ++ti) {
    const int s0 = ti * 64;
    if (ti < 15) STAGE(cur ^ 1, s0 + 64);

    f32x4 accST[4] = {};
#pragma unroll
    for (int ks = 0; ks < 2; ++ks)
#pragma unroll
      for (int sb = 0; sb < 4; ++sb) {
        bf16x8 kb = *(const bf16x8*)((const char*)Klds[cur] + swz(sb * 16 + lcol, ks * 64 + c0));
        accST[sb] = __builtin_amdgcn_mfma_f32_16x16x32_bf16(kb, qa[ks], accST[sb], 0, 0, 0);
      }

    float sv[4][4];
#pragma unroll
    for (int sb = 0; sb < 4; ++sb) {
      float4 mk = *(const float4*)&mask[b * 1024 + s0 + sb * 16 + g * 4];
      sv[sb][0] = accST[sb][0] * 0.125f + mk.x;
      sv[sb][1] = accST[sb][1] * 0.125f + mk.y;
      sv[sb][2] = accST[sb][2] * 0.125f + mk.z;
      sv[sb][3] = accST[sb][3] * 0.125f + mk.w;
    }
    float mt = sv[0][0];
#pragma unroll
    for (int sb = 0; sb < 4; ++sb)
#pragma unroll
      for (int r = 0; r < 4; ++r) mt = fmaxf(mt, sv[sb][r]);
    mt = fmaxf(mt, __shfl_xor(mt, 16));
    mt = fmaxf(mt, __shfl_xor(mt, 32));

    const float mn = fmaxf(m_r, mt);
    const float alpha = __expf(m_r - mn);
    m_r = mn;
    float rs = 0.f;
#pragma unroll
    for (int sb = 0; sb < 4; ++sb)
#pragma unroll
      for (int r = 0; r < 4; ++r) {
        const float pp = __expf(sv[sb][r] - mn);
        sv[sb][r] = pp;
        rs += pp;
      }
    rs += __shfl_xor(rs, 16);
    rs += __shfl_xor(rs, 32);
    l_r = l_r * alpha + rs;

#pragma unroll
    for (int sb = 0; sb < 4; ++sb) {
      uint2 dd;
      dd.x = cvt_pk_bf16(sv[sb][0], sv[sb][1]);
      dd.y = cvt_pk_bf16(sv[sb][2], sv[sb][3]);
      *(uint2*)(pbase + swz(lcol, sb * 32 + g * 8)) = dd;
    }

#pragma unroll
    for (int df = 0; df < 4; ++df)
#pragma unroll
      for (int r = 0; r < 4; ++r) accO[df][r] *= alpha;
#pragma unroll
    for (int ks = 0; ks < 2; ++ks) {
      bf16x8 pb = *(const bf16x8*)(pbase + swz(lcol, ks * 64 + c0));
#pragma unroll
      for (int df = 0; df < 4; ++df) {
        bf16x8 va = *(const bf16x8*)((const char*)Vlds[cur] + swz(df * 16 + lcol, ks * 64 + c0));
        accO[df] = __builtin_amdgcn_mfma_f32_16x16x32_bf16(va, pb, accO[df], 0, 0, 0);
      }
    }
    __syncthreads();
    cur ^= 1;
  }

  const float inv = 1.0f / l_r;
  u16* cp = ctx + ((size_t)(b * 1024 + qrow) * 1024 + h * 64);
#pragma unroll
  for (int df = 0; df < 4; ++df) {
    ushort4 o;
    o.x = f2bf(accO[df][0] * inv); o.y = f2bf(accO[df][1] * inv);
    o.z = f2bf(accO[df][2] * inv); o.w = f2bf(accO[df][3] * inv);
    *(ushort4*)(cp + df * 16 + g * 4) = o;
  }
}

// ---------------------------------------------------------------------------
// LayerNorm over rows of x[4096][1024]; OUTF=1 -> f32 out, else bf16 out
// ---------------------------------------------------------------------------
template <int OUTF>
__global__ void __launch_bounds__(256)
ln_kernel(const float* __restrict__ x, const float* __restrict__ gamma,
          const float* __restrict__ beta, float* __restrict__ outf,
          u16* __restrict__ outb) {
  const int row = blockIdx.x, t = threadIdx.x;
  const float* xr = x + (size_t)row * 1024;
  float4 v = *(const float4*)&xr[t * 4];
  float s = v.x + v.y + v.z + v.w;
  float q = v.x * v.x + v.y * v.y + v.z * v.z + v.w * v.w;
#pragma unroll
  for (int off = 1; off < 64; off <<= 1) {
    s += __shfl_xor(s, off);
    q += __shfl_xor(q, off);
  }
  __shared__ float ws[4], wq[4];
  if ((t & 63) == 0) { ws[t >> 6] = s; wq[t >> 6] = q; }
  __syncthreads();
  s = ws[0] + ws[1] + ws[2] + ws[3];
  q = wq[0] + wq[1] + wq[2] + wq[3];
  const float mu = s * (1.0f / 1024.0f);
  float var = q * (1.0f / 1024.0f) - mu * mu;
  var = fmaxf(var, 0.0f);
  const float rstd = rsqrtf(var + 1e-12f);
  float4 g = *(const float4*)&gamma[t * 4];
  float4 be = *(const float4*)&beta[t * 4];
  float y0 = (v.x - mu) * rstd * g.x + be.x;
  float y1 = (v.y - mu) * rstd * g.y + be.y;
  float y2 = (v.z - mu) * rstd * g.z + be.z;
  float y3 = (v.w - mu) * rstd * g.w + be.w;
  if constexpr (OUTF) {
    float4 o; o.x = y0; o.y = y1; o.z = y2; o.w = y3;
    *(float4*)&outf[(size_t)row * 1024 + t * 4] = o;
  } else {
    ushort4 o; o.x = f2bf(y0); o.y = f2bf(y1); o.z = f2bf(y2); o.w = f2bf(y3);
    *(ushort4*)&outb[(size_t)row * 1024 + t * 4] = o;
  }
}

// ---------------------------------------------------------------------------
extern "C" void kernel_launch(void* const* d_in, const int* in_sizes, int n_in,
                              void* d_out, int out_size, void* d_ws, size_t ws_size,
                              hipStream_t stream) {
  const float* enc = (const float*)d_in[0];
  const float* dec = (const float*)d_in[1];
  const float* src_mask = (const float*)d_in[2];
  const float* tgt_mask = (const float*)d_in[3];
  const float* Wq  = (const float*)d_in[4];  const float* bq  = (const float*)d_in[5];
  const float* Wk  = (const float*)d_in[6];  const float* bk  = (const float*)d_in[7];
  const float* Wv  = (const float*)d_in[8];  const float* bv  = (const float*)d_in[9];
  const float* Wq2 = (const float*)d_in[10]; const float* bq2 = (const float*)d_in[11];
  const float* Wk2 = (const float*)d_in[12]; const float* bk2 = (const float*)d_in[13];
  const float* Wv2 = (const float*)d_in[14]; const float* bv2 = (const float*)d_in[15];
  const float* Wo  = (const float*)d_in[16]; const float* bo  = (const float*)d_in[17];
  const float* gamma = (const float*)d_in[18]; const float* beta = (const float*)d_in[19];
  float* out = (float*)d_out;

  char* p = (char*)d_ws;
  const size_t ABF = (size_t)4096 * 1024 * 2;  // bf16 activation
  const size_t AF  = (size_t)4096 * 1024 * 4;  // f32 activation
  const size_t WBF = (size_t)1024 * 1024 * 2;  // bf16 weight
  u16* decbf = (u16*)p; p += ABF;
  u16* encbf = (u16*)p; p += ABF;
  u16* wt    = (u16*)p; p += 7 * WBF;
  u16* qbf   = (u16*)p; p += ABF;
  float* qf  = (float*)p; p += AF;
  u16* kbf   = (u16*)p; p += ABF;
  u16* vtb   = (u16*)p; p += ABF;
  u16* ctxb  = (u16*)p; p += ABF;
  float* tmpf = (float*)p; p += AF;
  u16* sobf  = decbf;  // reuse: decoder bf16 dead after layer-1 projections

  u16* WoT  = wt + 6 * 1048576;

  dim3 b256(256);
  convert_kernel<<<4096, b256, 0, stream>>>(dec, decbf);
  convert_kernel<<<4096, b256, 0, stream>>>(enc, encbf);
  WP wp;
  wp.w[0] = Wq; wp.w[1] = Wk; wp.w[2] = Wv; wp.w[3] = Wq2;
  wp.w[4] = Wk2; wp.w[5] = Wv2; wp.w[6] = Wo;
  transpose_kernel<<<dim3(16, 16, 7), b256, 0, stream>>>(wp, wt);

  // ---- layer 1 (self-attention on decoder inputs) ----
  qkv256_kernel<<<dim3(12, 16), 512, 0, stream>>>(
      decbf, decbf, decbf, wt, bq, bk, bv, qbf, qf, kbf, vtb);
  attn_kernel<<<1024, b256, 0, stream>>>(qbf, kbf, vtb, tgt_mask, ctxb);
  gemm_proj<<<dim3(8, 32), b256, 0, stream>>>(ctxb, WoT, bo, qf, tmpf);
  ln_kernel<0><<<4096, b256, 0, stream>>>(tmpf, gamma, beta, nullptr, sobf);
  // ---- layer 2 (cross-attention vs encoder states) ----
  qkv256_kernel<<<dim3(12, 16), 512, 0, stream>>>(
      sobf, encbf, encbf, wt + 3 * 1048576, bq2, bk2, bv2, qbf, qf, kbf, vtb);
  attn_kernel<<<1024, b256, 0, stream>>>(qbf, kbf, vtb, src_mask, ctxb);
  gemm_proj<<<dim3(8, 32), b256, 0, stream>>>(ctxb, WoT, bo, qf, tmpf);
  ln_kernel<1><<<4096, b256, 0, stream>>>(tmpf, gamma, beta, out, nullptr);
}

// Round 5
// 259.067 us; speedup vs baseline: 1.5211x; 1.0827x over previous
//
#include <hip/hip_runtime.h>
#include <stdint.h>

// ---------------------------------------------------------------------------
// AlbertDecoderAttention on MI355X (gfx950) — round 5
// Changes vs round 4:
//  * T4 counted-vmcnt pipeline in qkv256 / gemm_proj / attn: raw s_barrier
//    (no vmcnt(0) drain); next-tile global_load_lds stays in flight across
//    barriers, waited via s_waitcnt vmcnt(L) one iteration later.
//  * attn: mask prefetched one tile ahead into registers (avoids FIFO drain),
//    s_setprio(1) around MFMA clusters (T5, proven +4-7% on attn).
//  * converts fused into one launch.
// ---------------------------------------------------------------------------

typedef unsigned short u16;
typedef __bf16 bf16x8 __attribute__((ext_vector_type(8)));
typedef float f32x4 __attribute__((ext_vector_type(4)));

#define AS1 __attribute__((address_space(1)))
#define AS3 __attribute__((address_space(3)))

#define VMCNT(n) asm volatile("s_waitcnt vmcnt(" #n ")" ::: "memory")
#define SBARRIER() asm volatile("s_barrier" ::: "memory")

__device__ __forceinline__ u16 f2bf(float f) {
  union { float f; uint32_t u; } v; v.f = f;
  uint32_t u = v.u;
  return (u16)((u + 0x7fffu + ((u >> 16) & 1u)) >> 16);  // RNE
}

__device__ __forceinline__ uint32_t cvt_pk_bf16(float lo, float hi) {
  uint32_t r;
  asm("v_cvt_pk_bf16_f32 %0, %1, %2" : "=v"(r) : "v"(lo), "v"(hi));
  return r;  // lo -> bits[15:0], hi -> bits[31:16]
}

__device__ __forceinline__ void gl_lds16(const void* g, void* l) {
  __builtin_amdgcn_global_load_lds((AS1 void*)(g), (AS3 void*)(l), 16, 0, 0);
}

// swizzled byte address within a [rows][128B] LDS tile (involution on bits 4-6)
__device__ __forceinline__ int swz(int row, int byte) {
  return row * 128 + (byte ^ ((row & 7) << 4));
}

// ---------------------------------------------------------------------------
// f32 -> bf16 convert, two tensors in one launch (each 4096*1024 elems)
// ---------------------------------------------------------------------------
__global__ void __launch_bounds__(256)
convert2_kernel(const float* __restrict__ in0, u16* __restrict__ out0,
                const float* __restrict__ in1, u16* __restrict__ out1) {
  const int half = blockIdx.x >> 12;           // 0: dec, 1: enc
  const int i = (blockIdx.x & 4095) * 256 + threadIdx.x;
  const float* in = half ? in1 : in0;
  u16* out = half ? out1 : out0;
  float4 v = ((const float4*)in)[i];
  ushort4 o;
  o.x = f2bf(v.x); o.y = f2bf(v.y); o.z = f2bf(v.z); o.w = f2bf(v.w);
  ((ushort4*)out)[i] = o;
}

// ---------------------------------------------------------------------------
// Weight transpose + convert: W[k][n] f32 -> Wt[n][k] bf16 (7 matrices)
// ---------------------------------------------------------------------------
struct WP { const float* w[7]; };

__global__ void __launch_bounds__(256)
transpose_kernel(WP wp, u16* __restrict__ out) {
  __shared__ float tile[64][65];
  const float* W = wp.w[blockIdx.z];
  u16* Wt = out + (size_t)blockIdx.z * 1024 * 1024;
  const int k0 = blockIdx.y * 64, n0 = blockIdx.x * 64;
  const int t = threadIdx.x;
  const int r = t >> 4, c4 = (t & 15) * 4;
#pragma unroll
  for (int rr = 0; rr < 64; rr += 16) {
    float4 v = *(const float4*)&W[(size_t)(k0 + r + rr) * 1024 + n0 + c4];
    tile[r + rr][c4 + 0] = v.x; tile[r + rr][c4 + 1] = v.y;
    tile[r + rr][c4 + 2] = v.z; tile[r + rr][c4 + 3] = v.w;
  }
  __syncthreads();
  const int n = t >> 2, seg = (t & 3) * 16;
  union { u16 s[16]; uint4 q[2]; } u;
#pragma unroll
  for (int i = 0; i < 16; ++i) u.s[i] = f2bf(tile[seg + i][n]);
  uint4* dst = (uint4*)&Wt[(size_t)(n0 + n) * 1024 + k0 + seg];
  dst[0] = u.q[0]; dst[1] = u.q[1];
}

// ---------------------------------------------------------------------------
// qkv256: 3-segment projection GEMM, 256x256 tile, BK=32, 8 waves (2Mx4N),
// double-buffered 64KB LDS, counted-vmcnt pipeline (T4).
// ---------------------------------------------------------------------------
__global__ void __launch_bounds__(512, 2)
qkv256_kernel(const u16* __restrict__ A0, const u16* __restrict__ A1,
              const u16* __restrict__ A2, const u16* __restrict__ Bt,
              const float* __restrict__ b0, const float* __restrict__ b1,
              const float* __restrict__ b2,
              u16* __restrict__ qb, float* __restrict__ qf,
              u16* __restrict__ kb, u16* __restrict__ vt) {
  __shared__ u16 Alds[2][256 * 32];
  __shared__ u16 Blds[2][256 * 32];
  const int bm = blockIdx.y * 256, bn = blockIdx.x * 256;
  const int seg = bn >> 10;
  const u16* A = (seg == 0) ? A0 : (seg == 1) ? A1 : A2;
  const int t = threadIdx.x, wv = t >> 6, ln = t & 63;
  const int wm = (wv >> 2) * 128, wn = (wv & 3) * 64;
  const int lcol = ln & 15, lk8 = (ln >> 4) * 8, lr4 = (ln >> 4) * 4;

  f32x4 acc[8][4] = {};

  auto STAGE = [&](int buf, int k0) {
#pragma unroll
    for (int c = 0; c < 2; ++c) {
      const int o = c * 8192 + wv * 1024 + ln * 16;
      const int row = o >> 6, colb = o & 63;
      gl_lds16((const char*)A + ((size_t)(bm + row) * 1024 + k0) * 2 + colb,
               (char*)Alds[buf] + c * 8192 + wv * 1024);
      gl_lds16((const char*)Bt + ((size_t)(bn + row) * 1024 + k0) * 2 + colb,
               (char*)Blds[buf] + c * 8192 + wv * 1024);
    }
  };

  auto COMPUTE = [&](int buf) {
    const u16* Ab = Alds[buf];
    const u16* Bb = Blds[buf];
    bf16x8 a[8], b[4];
#pragma unroll
    for (int j = 0; j < 4; ++j)
      b[j] = *(const bf16x8*)&Bb[(wn + j * 16 + lcol) * 32 + lk8];
#pragma unroll
    for (int i = 0; i < 8; ++i)
      a[i] = *(const bf16x8*)&Ab[(wm + i * 16 + lcol) * 32 + lk8];
#pragma unroll
    for (int i = 0; i < 8; ++i)
#pragma unroll
      for (int j = 0; j < 4; ++j)
        acc[i][j] = __builtin_amdgcn_mfma_f32_16x16x32_bf16(a[i], b[j], acc[i][j], 0, 0, 0);
  };

  STAGE(0, 0);
  int cur = 0;
  for (int it = 0; it < 31; ++it) {
    STAGE(cur ^ 1, (it + 1) * 32);  // tile it+1 in flight across barriers
    VMCNT(4);                        // tile it's 4 loads landed
    SBARRIER();                      // all waves' tile-it writes visible
    COMPUTE(cur);
    SBARRIER();                      // all waves done reading cur
    cur ^= 1;
  }
  VMCNT(0);
  SBARRIER();
  COMPUTE(cur);

  const int cs = bn & 1023;
  const float* bias = (seg == 0) ? b0 : (seg == 1) ? b1 : b2;
#pragma unroll
  for (int j = 0; j < 4; ++j) {
    const int col = cs + wn + j * 16 + lcol;
    const float bc = bias[col];
#pragma unroll
    for (int i = 0; i < 8; ++i) {
      const int row0 = bm + wm + i * 16 + lr4;
      if (seg == 2) {
        ushort4 o;
        o.x = f2bf(acc[i][j][0] + bc); o.y = f2bf(acc[i][j][1] + bc);
        o.z = f2bf(acc[i][j][2] + bc); o.w = f2bf(acc[i][j][3] + bc);
        const int b_ = row0 >> 10, s = row0 & 1023;
        const int h = col >> 6, d = col & 63;
        *(ushort4*)&vt[(((size_t)(b_ * 16 + h) * 64 + d) << 10) + s] = o;
      } else if (seg == 0) {
#pragma unroll
        for (int r = 0; r < 4; ++r) {
          const size_t idx = (size_t)(row0 + r) * 1024 + col;
          const float v = acc[i][j][r] + bc;
          qb[idx] = f2bf(v); qf[idx] = v;
        }
      } else {
#pragma unroll
        for (int r = 0; r < 4; ++r) {
          const size_t idx = (size_t)(row0 + r) * 1024 + col;
          kb[idx] = f2bf(acc[i][j][r] + bc);
        }
      }
    }
  }
}

// ---------------------------------------------------------------------------
// Wo-projection GEMM: 128x128 tile, BK=64, 4 waves, counted-vmcnt pipeline.
// out f32 = acc + bias + resid (pre-layernorm sum).
// ---------------------------------------------------------------------------
__global__ void __launch_bounds__(256)
gemm_proj(const u16* __restrict__ A, const u16* __restrict__ Bt,
          const float* __restrict__ bias, const float* __restrict__ resid,
          float* __restrict__ outf) {
  __shared__ u16 Alds[2][8192];
  __shared__ u16 Blds[2][8192];
  const int bm = blockIdx.y * 128, bn = blockIdx.x * 128;
  const int t = threadIdx.x, wv = t >> 6, ln = t & 63;
  const int wm = (wv >> 1) * 64, wn = (wv & 1) * 64;
  const int lcol = ln & 15, lk8 = (ln >> 4) * 8, lr4 = (ln >> 4) * 4;

  f32x4 acc[4][4] = {};

  auto STAGE = [&](int buf, int k0) {
#pragma unroll
    for (int c = 0; c < 4; ++c) {
      const int o = c * 4096 + wv * 1024 + ln * 16;
      const int row = o >> 7, colb = o & 127;
      gl_lds16((const char*)A + ((size_t)(bm + row) * 1024 + k0) * 2 + colb,
               (char*)Alds[buf] + c * 4096 + wv * 1024);
      gl_lds16((const char*)Bt + ((size_t)(bn + row) * 1024 + k0) * 2 + colb,
               (char*)Blds[buf] + c * 4096 + wv * 1024);
    }
  };

  auto COMPUTE = [&](int buf) {
    const u16* Ab = Alds[buf];
    const u16* Bb = Blds[buf];
#pragma unroll
    for (int ks = 0; ks < 2; ++ks) {
      bf16x8 a[4], b[4];
#pragma unroll
      for (int i = 0; i < 4; ++i)
        a[i] = *(const bf16x8*)&Ab[(wm + i * 16 + lcol) * 64 + ks * 32 + lk8];
#pragma unroll
      for (int j = 0; j < 4; ++j)
        b[j] = *(const bf16x8*)&Bb[(wn + j * 16 + lcol) * 64 + ks * 32 + lk8];
#pragma unroll
      for (int i = 0; i < 4; ++i)
#pragma unroll
        for (int j = 0; j < 4; ++j)
          acc[i][j] = __builtin_amdgcn_mfma_f32_16x16x32_bf16(a[i], b[j], acc[i][j], 0, 0, 0);
    }
  };

  STAGE(0, 0);
  int cur = 0;
  for (int it = 0; it < 15; ++it) {
    STAGE(cur ^ 1, (it + 1) * 64);
    VMCNT(8);
    SBARRIER();
    COMPUTE(cur);
    SBARRIER();
    cur ^= 1;
  }
  VMCNT(0);
  SBARRIER();
  COMPUTE(cur);

#pragma unroll
  for (int j = 0; j < 4; ++j) {
    const int col = bn + wn + j * 16 + lcol;
    const float bc = bias[col];
#pragma unroll
    for (int i = 0; i < 4; ++i) {
      const int row0 = bm + wm + i * 16 + lr4;
#pragma unroll
      for (int r = 0; r < 4; ++r) {
        const size_t idx = (size_t)(row0 + r) * 1024 + col;
        outf[idx] = acc[i][j][r] + bc + resid[idx];
      }
    }
  }
}

// ---------------------------------------------------------------------------
// Flash attention, swapped-QK^T, counted-vmcnt pipeline, mask prefetch.
// grid 1024 blocks 1D (XCD-grouped), 4 waves x 16 q-rows, KV tile 64.
// Q,K bf16 [B,T,HID]; Vt bf16 [B,H,DH,S]; mask f32 [B,S]; ctx bf16 [B,T,HID].
// ---------------------------------------------------------------------------
__global__ void __launch_bounds__(256)
attn_kernel(const u16* __restrict__ Q, const u16* __restrict__ Kb,
            const u16* __restrict__ Vt, const float* __restrict__ mask,
            u16* __restrict__ ctx) {
  __shared__ u16 Klds[2][64 * 64];   // [s][d], swizzled
  __shared__ u16 Vlds[2][64 * 64];   // [d][s], swizzled
  __shared__ u16 Plds[4][16 * 64];   // per-wave [q][s], swizzled

  const int fid = blockIdx.x;
  const int xcd = fid & 7, idx = fid >> 3;
  const int bh = xcd * 8 + (idx >> 4);
  const int b = bh >> 4, h = bh & 15;
  const int q0 = (idx & 15) * 64;

  const int t = threadIdx.x, wv = t >> 6, ln = t & 63;
  const int lcol = ln & 15, g = ln >> 4;
  const int lk8 = g * 8, c0 = g * 16;

  const int qrow = q0 + wv * 16 + lcol;
  const u16* qptr = Q + ((size_t)(b * 1024 + qrow) * 1024 + h * 64);
  bf16x8 qa[2];
  qa[0] = *(const bf16x8*)(qptr + lk8);
  qa[1] = *(const bf16x8*)(qptr + 32 + lk8);

  const float* mrow = mask + b * 1024;
  char* pbase = (char*)&Plds[wv][0];

  f32x4 accO[4] = {};
  float m_r = -1e30f, l_r = 0.f;

  auto STAGE = [&](int buf, int s0) {
#pragma unroll
    for (int c = 0; c < 2; ++c) {
      const int o = c * 4096 + wv * 1024 + ln * 16;
      const int row = o >> 7;
      const int src_cb = (o & 127) ^ ((row & 7) << 4);  // inverse-swizzle src
      gl_lds16((const char*)Kb + ((size_t)((b * 1024 + s0 + row) * 1024 + h * 64)) * 2 + src_cb,
               (char*)Klds[buf] + c * 4096 + wv * 1024);
      gl_lds16((const char*)Vt + ((size_t)(((b * 16 + h) * 64 + row) * 1024 + s0)) * 2 + src_cb,
               (char*)Vlds[buf] + c * 4096 + wv * 1024);
    }
  };

  auto TILE = [&](int buf, const float4* mk) {
    // S^T = (K Q^T): accST[sb] = mfma(K-rows, Q-rows)
    f32x4 accST[4] = {};
    __builtin_amdgcn_s_setprio(1);
#pragma unroll
    for (int ks = 0; ks < 2; ++ks)
#pragma unroll
      for (int sb = 0; sb < 4; ++sb) {
        bf16x8 kb = *(const bf16x8*)((const char*)Klds[buf] + swz(sb * 16 + lcol, ks * 64 + c0));
        accST[sb] = __builtin_amdgcn_mfma_f32_16x16x32_bf16(kb, qa[ks], accST[sb], 0, 0, 0);
      }
    __builtin_amdgcn_s_setprio(0);

    // lane-local softmax over 16 s-values (q = lcol fixed per lane)
    float sv[4][4];
#pragma unroll
    for (int sb = 0; sb < 4; ++sb) {
      sv[sb][0] = accST[sb][0] * 0.125f + mk[sb].x;
      sv[sb][1] = accST[sb][1] * 0.125f + mk[sb].y;
      sv[sb][2] = accST[sb][2] * 0.125f + mk[sb].z;
      sv[sb][3] = accST[sb][3] * 0.125f + mk[sb].w;
    }
    float mt = sv[0][0];
#pragma unroll
    for (int sb = 0; sb < 4; ++sb)
#pragma unroll
      for (int r = 0; r < 4; ++r) mt = fmaxf(mt, sv[sb][r]);
    mt = fmaxf(mt, __shfl_xor(mt, 16));
    mt = fmaxf(mt, __shfl_xor(mt, 32));

    const float mn = fmaxf(m_r, mt);
    const float alpha = __expf(m_r - mn);
    m_r = mn;
    float rs = 0.f;
#pragma unroll
    for (int sb = 0; sb < 4; ++sb)
#pragma unroll
      for (int r = 0; r < 4; ++r) {
        const float pp = __expf(sv[sb][r] - mn);
        sv[sb][r] = pp;
        rs += pp;
      }
    rs += __shfl_xor(rs, 16);
    rs += __shfl_xor(rs, 32);
    l_r = l_r * alpha + rs;

    // P^T pack -> Plds[q=lcol][s_local], 4x ds_write_b64
#pragma unroll
    for (int sb = 0; sb < 4; ++sb) {
      uint2 dd;
      dd.x = cvt_pk_bf16(sv[sb][0], sv[sb][1]);
      dd.y = cvt_pk_bf16(sv[sb][2], sv[sb][3]);
      *(uint2*)(pbase + swz(lcol, sb * 32 + g * 8)) = dd;
    }

    // rescale O (col q = lcol is lane-local) then PV
#pragma unroll
    for (int df = 0; df < 4; ++df)
#pragma unroll
      for (int r = 0; r < 4; ++r) accO[df][r] *= alpha;
    __builtin_amdgcn_s_setprio(1);
#pragma unroll
    for (int ks = 0; ks < 2; ++ks) {
      bf16x8 pb = *(const bf16x8*)(pbase + swz(lcol, ks * 64 + c0));
#pragma unroll
      for (int df = 0; df < 4; ++df) {
        bf16x8 va = *(const bf16x8*)((const char*)Vlds[buf] + swz(df * 16 + lcol, ks * 64 + c0));
        accO[df] = __builtin_amdgcn_mfma_f32_16x16x32_bf16(va, pb, accO[df], 0, 0, 0);
      }
    }
    __builtin_amdgcn_s_setprio(0);
  };

  // prologue: tile 0 stage + mask
  STAGE(0, 0);
  float4 mk_cur[4];
#pragma unroll
  for (int sb = 0; sb < 4; ++sb)
    mk_cur[sb] = *(const float4*)&mrow[sb * 16 + g * 4];

  int cur = 0;
  for (int ti = 0; ti < 15; ++ti) {
    const int s1 = ti * 64 + 64;
    STAGE(cur ^ 1, s1);              // 4 loads for tile ti+1
    float4 mk_nxt[4];
#pragma unroll
    for (int sb = 0; sb < 4; ++sb)
      mk_nxt[sb] = *(const float4*)&mrow[s1 + sb * 16 + g * 4];
    VMCNT(12);                       // tile ti's 4 stage loads landed
    SBARRIER();
    TILE(cur, mk_cur);
    SBARRIER();                      // all waves done reading cur
#pragma unroll
    for (int sb = 0; sb < 4; ++sb) mk_cur[sb] = mk_nxt[sb];
    cur ^= 1;
  }
  VMCNT(4);                          // last tile's stage landed (masks may fly)
  SBARRIER();
  TILE(cur, mk_cur);

  const float inv = 1.0f / l_r;
  u16* cp = ctx + ((size_t)(b * 1024 + qrow) * 1024 + h * 64);
#pragma unroll
  for (int df = 0; df < 4; ++df) {
    ushort4 o;
    o.x = f2bf(accO[df][0] * inv); o.y = f2bf(accO[df][1] * inv);
    o.z = f2bf(accO[df][2] * inv); o.w = f2bf(accO[df][3] * inv);
    *(ushort4*)(cp + df * 16 + g * 4) = o;
  }
}

// ---------------------------------------------------------------------------
// LayerNorm over rows of x[4096][1024]; OUTF=1 -> f32 out, else bf16 out
// ---------------------------------------------------------------------------
template <int OUTF>
__global__ void __launch_bounds__(256)
ln_kernel(const float* __restrict__ x, const float* __restrict__ gamma,
          const float* __restrict__ beta, float* __restrict__ outf,
          u16* __restrict__ outb) {
  const int row = blockIdx.x, t = threadIdx.x;
  const float* xr = x + (size_t)row * 1024;
  float4 v = *(const float4*)&xr[t * 4];
  float s = v.x + v.y + v.z + v.w;
  float q = v.x * v.x + v.y * v.y + v.z * v.z + v.w * v.w;
#pragma unroll
  for (int off = 1; off < 64; off <<= 1) {
    s += __shfl_xor(s, off);
    q += __shfl_xor(q, off);
  }
  __shared__ float ws[4], wq[4];
  if ((t & 63) == 0) { ws[t >> 6] = s; wq[t >> 6] = q; }
  __syncthreads();
  s = ws[0] + ws[1] + ws[2] + ws[3];
  q = wq[0] + wq[1] + wq[2] + wq[3];
  const float mu = s * (1.0f / 1024.0f);
  float var = q * (1.0f / 1024.0f) - mu * mu;
  var = fmaxf(var, 0.0f);
  const float rstd = rsqrtf(var + 1e-12f);
  float4 g = *(const float4*)&gamma[t * 4];
  float4 be = *(const float4*)&beta[t * 4];
  float y0 = (v.x - mu) * rstd * g.x + be.x;
  float y1 = (v.y - mu) * rstd * g.y + be.y;
  float y2 = (v.z - mu) * rstd * g.z + be.z;
  float y3 = (v.w - mu) * rstd * g.w + be.w;
  if constexpr (OUTF) {
    float4 o; o.x = y0; o.y = y1; o.z = y2; o.w = y3;
    *(float4*)&outf[(size_t)row * 1024 + t * 4] = o;
  } else {
    ushort4 o; o.x = f2bf(y0); o.y = f2bf(y1); o.z = f2bf(y2); o.w = f2bf(y3);
    *(ushort4*)&outb[(size_t)row * 1024 + t * 4] = o;
  }
}

// ---------------------------------------------------------------------------
extern "C" void kernel_launch(void* const* d_in, const int* in_sizes, int n_in,
                              void* d_out, int out_size, void* d_ws, size_t ws_size,
                              hipStream_t stream) {
  const float* enc = (const float*)d_in[0];
  const float* dec = (const float*)d_in[1];
  const float* src_mask = (const float*)d_in[2];
  const float* tgt_mask = (const float*)d_in[3];
  const float* Wq  = (const float*)d_in[4];  const float* bq  = (const float*)d_in[5];
  const float* Wk  = (const float*)d_in[6];  const float* bk  = (const float*)d_in[7];
  const float* Wv  = (const float*)d_in[8];  const float* bv  = (const float*)d_in[9];
  const float* Wq2 = (const float*)d_in[10]; const float* bq2 = (const float*)d_in[11];
  const float* Wk2 = (const float*)d_in[12]; const float* bk2 = (const float*)d_in[13];
  const float* Wv2 = (const float*)d_in[14]; const float* bv2 = (const float*)d_in[15];
  const float* Wo  = (const float*)d_in[16]; const float* bo  = (const float*)d_in[17];
  const float* gamma = (const float*)d_in[18]; const float* beta = (const float*)d_in[19];
  float* out = (float*)d_out;

  char* p = (char*)d_ws;
  const size_t ABF = (size_t)4096 * 1024 * 2;  // bf16 activation
  const size_t AF  = (size_t)4096 * 1024 * 4;  // f32 activation
  const size_t WBF = (size_t)1024 * 1024 * 2;  // bf16 weight
  u16* decbf = (u16*)p; p += ABF;
  u16* encbf = (u16*)p; p += ABF;
  u16* wt    = (u16*)p; p += 7 * WBF;
  u16* qbf   = (u16*)p; p += ABF;
  float* qf  = (float*)p; p += AF;
  u16* kbf   = (u16*)p; p += ABF;
  u16* vtb   = (u16*)p; p += ABF;
  u16* ctxb  = (u16*)p; p += ABF;
  float* tmpf = (float*)p; p += AF;
  u16* sobf  = decbf;  // reuse: decoder bf16 dead after layer-1 projections

  u16* WoT  = wt + 6 * 1048576;

  dim3 b256(256);
  convert2_kernel<<<8192, b256, 0, stream>>>(dec, decbf, enc, encbf);
  WP wp;
  wp.w[0] = Wq; wp.w[1] = Wk; wp.w[2] = Wv; wp.w[3] = Wq2;
  wp.w[4] = Wk2; wp.w[5] = Wv2; wp.w[6] = Wo;
  transpose_kernel<<<dim3(16, 16, 7), b256, 0, stream>>>(wp, wt);

  // ---- layer 1 (self-attention on decoder inputs) ----
  qkv256_kernel<<<dim3(12, 16), 512, 0, stream>>>(
      decbf, decbf, decbf, wt, bq, bk, bv, qbf, qf, kbf, vtb);
  attn_kernel<<<1024, b256, 0, stream>>>(qbf, kbf, vtb, tgt_mask, ctxb);
  gemm_proj<<<dim3(8, 32), b256, 0, stream>>>(ctxb, WoT, bo, qf, tmpf);
  ln_kernel<0><<<4096, b256, 0, stream>>>(tmpf, gamma, beta, nullptr, sobf);
  // ---- layer 2 (cross-attention vs encoder states) ----
  qkv256_kernel<<<dim3(12, 16), 512, 0, stream>>>(
      sobf, encbf, encbf, wt + 3 * 1048576, bq2, bk2, bv2, qbf, qf, kbf, vtb);
  attn_kernel<<<1024, b256, 0, stream>>>(qbf, kbf, vtb, src_mask, ctxb);
  gemm_proj<<<dim3(8, 32), b256, 0, stream>>>(ctxb, WoT, bo, qf, tmpf);
  ln_kernel<1><<<4096, b256, 0, stream>>>(tmpf, gamma, beta, out, nullptr);
}

// Round 6
// 242.106 us; speedup vs baseline: 1.6277x; 1.0701x over previous
//
#include <hip/hip_runtime.h>
#include <stdint.h>

// ---------------------------------------------------------------------------
// AlbertDecoderAttention on MI355X (gfx950) — round 6
// Changes vs round 5:
//  * qkv projections rebuilt on the 8-phase template (m201 stack): 256x256,
//    BK=64, 8 waves, 128KB LDS double-buffer, swizzled 128B-row LDS (T2),
//    inline-asm ds_read_b128 (defeats compiler vmcnt(0) insertion),
//    counted vmcnt(2) never-0 in loop (T4), setprio MFMA clusters (T5).
//    4 phases/K-tile: {dsr frags; stage 1 unit; bar; lgkm; 16 MFMA; bar}.
//  * attn / gemm_proj / ln / converts unchanged from round 5.
// ---------------------------------------------------------------------------

typedef unsigned short u16;
typedef __bf16 bf16x8 __attribute__((ext_vector_type(8)));
typedef float f32x4 __attribute__((ext_vector_type(4)));

#define AS1 __attribute__((address_space(1)))
#define AS3 __attribute__((address_space(3)))
typedef AS3 char lds_char;
typedef AS3 unsigned short lds_u16;

#define VMCNT(n) asm volatile("s_waitcnt vmcnt(" #n ")" ::: "memory")
#define LGKM0() asm volatile("s_waitcnt lgkmcnt(0)" ::: "memory")
#define SBARRIER() asm volatile("s_barrier" ::: "memory")

__device__ __forceinline__ u16 f2bf(float f) {
  union { float f; uint32_t u; } v; v.f = f;
  uint32_t u = v.u;
  return (u16)((u + 0x7fffu + ((u >> 16) & 1u)) >> 16);  // RNE
}

__device__ __forceinline__ uint32_t cvt_pk_bf16(float lo, float hi) {
  uint32_t r;
  asm("v_cvt_pk_bf16_f32 %0, %1, %2" : "=v"(r) : "v"(lo), "v"(hi));
  return r;
}

__device__ __forceinline__ void gl_lds16(const void* g, void* l) {
  __builtin_amdgcn_global_load_lds((AS1 void*)(g), (AS3 void*)(l), 16, 0, 0);
}

__device__ __forceinline__ bf16x8 dsr128(const lds_u16* p) {
  bf16x8 r;
  asm volatile("ds_read_b128 %0, %1" : "=v"(r) : "v"(p));
  return r;
}

// swizzled byte address within a [rows][128B] LDS tile (involution on bits 4-6)
__device__ __forceinline__ int swz(int row, int byte) {
  return row * 128 + (byte ^ ((row & 7) << 4));
}

// ---------------------------------------------------------------------------
// f32 -> bf16 convert, two tensors in one launch (each 4096*1024 elems)
// ---------------------------------------------------------------------------
__global__ void __launch_bounds__(256)
convert2_kernel(const float* __restrict__ in0, u16* __restrict__ out0,
                const float* __restrict__ in1, u16* __restrict__ out1) {
  const int half = blockIdx.x >> 12;
  const int i = (blockIdx.x & 4095) * 256 + threadIdx.x;
  const float* in = half ? in1 : in0;
  u16* out = half ? out1 : out0;
  float4 v = ((const float4*)in)[i];
  ushort4 o;
  o.x = f2bf(v.x); o.y = f2bf(v.y); o.z = f2bf(v.z); o.w = f2bf(v.w);
  ((ushort4*)out)[i] = o;
}

// ---------------------------------------------------------------------------
// Weight transpose + convert: W[k][n] f32 -> Wt[n][k] bf16 (7 matrices)
// ---------------------------------------------------------------------------
struct WP { const float* w[7]; };

__global__ void __launch_bounds__(256)
transpose_kernel(WP wp, u16* __restrict__ out) {
  __shared__ float tile[64][65];
  const float* W = wp.w[blockIdx.z];
  u16* Wt = out + (size_t)blockIdx.z * 1024 * 1024;
  const int k0 = blockIdx.y * 64, n0 = blockIdx.x * 64;
  const int t = threadIdx.x;
  const int r = t >> 4, c4 = (t & 15) * 4;
#pragma unroll
  for (int rr = 0; rr < 64; rr += 16) {
    float4 v = *(const float4*)&W[(size_t)(k0 + r + rr) * 1024 + n0 + c4];
    tile[r + rr][c4 + 0] = v.x; tile[r + rr][c4 + 1] = v.y;
    tile[r + rr][c4 + 2] = v.z; tile[r + rr][c4 + 3] = v.w;
  }
  __syncthreads();
  const int n = t >> 2, seg = (t & 3) * 16;
  union { u16 s[16]; uint4 q[2]; } u;
#pragma unroll
  for (int i = 0; i < 16; ++i) u.s[i] = f2bf(tile[seg + i][n]);
  uint4* dst = (uint4*)&Wt[(size_t)(n0 + n) * 1024 + k0 + seg];
  dst[0] = u.q[0]; dst[1] = u.q[1];
}

// ---------------------------------------------------------------------------
// qkv8p: 3-segment projection GEMM on the 8-phase template.
// 256x256 tile, BK=64, 8 waves (2Mx4N), 128KB LDS dbuf, swizzled 128B rows.
// Per K-tile: 4 phases, each {asm ds_read frags; stage 1 unit (2 gl_lds);
// bar; lgkmcnt0; 16 MFMA w/ setprio; bar}; vmcnt(2) at phase0/3 end.
// Stage units ordered by first-read: Bh0, Bh1, A(q0,q2), A(q1,q3).
// ---------------------------------------------------------------------------
__global__ void __launch_bounds__(512, 2)
qkv8p_kernel(const u16* __restrict__ A0, const u16* __restrict__ A1,
             const u16* __restrict__ A2, const u16* __restrict__ Bt,
             const float* __restrict__ b0, const float* __restrict__ b1,
             const float* __restrict__ b2,
             u16* __restrict__ qb, float* __restrict__ qf,
             u16* __restrict__ kb, u16* __restrict__ vt) {
  __shared__ u16 Alds[2][256 * 64];   // 64KB: [buf][row][64 bf16], swizzled
  __shared__ u16 Blds[2][256 * 64];   // 64KB
  const int bm = blockIdx.y * 256, bn = blockIdx.x * 256;
  const int seg = bn >> 10;
  const u16* A = (seg == 0) ? A0 : (seg == 1) ? A1 : A2;
  const int t = threadIdx.x, wv = t >> 6, ln = t & 63;
  const int wm = (wv >> 2) * 128, wn = (wv & 3) * 64;
  const int lcol = ln & 15, g = ln >> 4, lr4 = g * 4;
  // frag byte offsets: row&7 == lcol&7 (wm,wn,i*16 all mult of 8)
  const int xr = (lcol & 7) << 4;
  const int aoff0 = (g * 16) ^ xr;          // ks=0
  const int aoff1 = (64 + g * 16) ^ xr;     // ks=1
  lds_char* ABase = (lds_char*)&Alds[0][0];
  lds_char* BBase = (lds_char*)&Blds[0][0];

  f32x4 acc[8][4] = {};

  // stage B half h (n-rows h*128..+127, full BK=64) of buffer buf: 2 gl_lds
  auto stageB = [&](int buf, int h, int k0) {
#pragma unroll
    for (int rd = 0; rd < 2; ++rd) {
      const int row = h * 128 + rd * 64 + (t >> 3);
      const int src = ((t & 7) * 16) ^ (((t >> 3) & 7) << 4);
      gl_lds16((const char*)Bt + ((size_t)(bn + row) * 1024 + k0) * 2 + src,
               (char*)&Blds[0][0] + buf * 32768 + h * 16384 + rd * 8192 + wv * 1024);
    }
  };
  // stage A quarter-pair p (quarters p and p+2): 2 gl_lds
  auto stageA = [&](int buf, int p, int k0) {
#pragma unroll
    for (int qq = 0; qq < 2; ++qq) {
      const int q = p + qq * 2;
      const int row = q * 64 + (t >> 3);
      const int src = ((t & 7) * 16) ^ (((t >> 3) & 7) << 4);
      gl_lds16((const char*)A + ((size_t)(bm + row) * 1024 + k0) * 2 + src,
               (char*)&Alds[0][0] + buf * 32768 + q * 8192 + wv * 1024);
    }
  };

  auto run_tile = [&](int cur, int nxt, int knxt, bool do_stage, bool fin) {
    lds_char* Ac = ABase + cur * 32768;
    lds_char* Bc = BBase + cur * 32768;
    bf16x8 bfr[4], afr[4];
    // ---- phase 0: frags B ks0 + A m0-3 ks0; stage Bh0'; MFMA m0-3 ks0
#pragma unroll
    for (int j = 0; j < 4; ++j)
      bfr[j] = dsr128((const lds_u16*)(Bc + (wn + j * 16 + lcol) * 128 + aoff0));
#pragma unroll
    for (int i = 0; i < 4; ++i)
      afr[i] = dsr128((const lds_u16*)(Ac + (wm + i * 16 + lcol) * 128 + aoff0));
    if (do_stage) stageB(nxt, 0, knxt);
    if (fin) VMCNT(0);
    __builtin_amdgcn_s_barrier();
    LGKM0();
    __builtin_amdgcn_sched_barrier(0);
    __builtin_amdgcn_s_setprio(1);
#pragma unroll
    for (int i = 0; i < 4; ++i)
#pragma unroll
      for (int j = 0; j < 4; ++j)
        acc[i][j] = __builtin_amdgcn_mfma_f32_16x16x32_bf16(afr[i], bfr[j], acc[i][j], 0, 0, 0);
    __builtin_amdgcn_s_setprio(0);
    if (!fin) VMCNT(2);          // waits prev tile's A(q1,q3); leaves Bh0'
    __builtin_amdgcn_s_barrier();
    // ---- phase 1: frags A m4-7 ks0 (B reused); stage Bh1'; MFMA m4-7 ks0
#pragma unroll
    for (int i = 0; i < 4; ++i)
      afr[i] = dsr128((const lds_u16*)(Ac + (wm + 64 + i * 16 + lcol) * 128 + aoff0));
    if (do_stage) stageB(nxt, 1, knxt);
    __builtin_amdgcn_s_barrier();
    LGKM0();
    __builtin_amdgcn_sched_barrier(0);
    __builtin_amdgcn_s_setprio(1);
#pragma unroll
    for (int i = 0; i < 4; ++i)
#pragma unroll
      for (int j = 0; j < 4; ++j)
        acc[4 + i][j] = __builtin_amdgcn_mfma_f32_16x16x32_bf16(afr[i], bfr[j], acc[4 + i][j], 0, 0, 0);
    __builtin_amdgcn_s_setprio(0);
    __builtin_amdgcn_s_barrier();
    // ---- phase 2: frags B ks1 + A m0-3 ks1; stage A(q0,q2)'; MFMA m0-3 ks1
#pragma unroll
    for (int j = 0; j < 4; ++j)
      bfr[j] = dsr128((const lds_u16*)(Bc + (wn + j * 16 + lcol) * 128 + aoff1));
#pragma unroll
    for (int i = 0; i < 4; ++i)
      afr[i] = dsr128((const lds_u16*)(Ac + (wm + i * 16 + lcol) * 128 + aoff1));
    if (do_stage) stageA(nxt, 0, knxt);
    __builtin_amdgcn_s_barrier();
    LGKM0();
    __builtin_amdgcn_sched_barrier(0);
    __builtin_amdgcn_s_setprio(1);
#pragma unroll
    for (int i = 0; i < 4; ++i)
#pragma unroll
      for (int j = 0; j < 4; ++j)
        acc[i][j] = __builtin_amdgcn_mfma_f32_16x16x32_bf16(afr[i], bfr[j], acc[i][j], 0, 0, 0);
    __builtin_amdgcn_s_setprio(0);
    __builtin_amdgcn_s_barrier();
    // ---- phase 3: frags A m4-7 ks1; stage A(q1,q3)'; MFMA m4-7 ks1
#pragma unroll
    for (int i = 0; i < 4; ++i)
      afr[i] = dsr128((const lds_u16*)(Ac + (wm + 64 + i * 16 + lcol) * 128 + aoff1));
    if (do_stage) stageA(nxt, 1, knxt);
    __builtin_amdgcn_s_barrier();
    LGKM0();
    __builtin_amdgcn_sched_barrier(0);
    __builtin_amdgcn_s_setprio(1);
#pragma unroll
    for (int i = 0; i < 4; ++i)
#pragma unroll
      for (int j = 0; j < 4; ++j)
        acc[4 + i][j] = __builtin_amdgcn_mfma_f32_16x16x32_bf16(afr[i], bfr[j], acc[4 + i][j], 0, 0, 0);
    __builtin_amdgcn_s_setprio(0);
    if (do_stage) VMCNT(2);      // waits Bh0',Bh1',A(q0,q2)'; leaves A(q1,q3)'
    __builtin_amdgcn_s_barrier();
  };

  // prologue: stage buffer 0 fully (k=0); wait all but A(q1,q3)
  stageB(0, 0, 0); stageB(0, 1, 0); stageA(0, 0, 0); stageA(0, 1, 0);
  VMCNT(2);
  __builtin_amdgcn_s_barrier();

  for (int kt = 0; kt < 14; kt += 2) {
    run_tile(0, 1, (kt + 1) * 64, true, false);
    run_tile(1, 0, (kt + 2) * 64, true, false);
  }
  run_tile(0, 1, 960, true, false);   // kt = 14
  run_tile(1, 0, 0, false, true);     // kt = 15

  // epilogue
  const int cs = bn & 1023;
  const float* bias = (seg == 0) ? b0 : (seg == 1) ? b1 : b2;
#pragma unroll
  for (int j = 0; j < 4; ++j) {
    const int col = cs + wn + j * 16 + lcol;
    const float bc = bias[col];
#pragma unroll
    for (int i = 0; i < 8; ++i) {
      const int row0 = bm + wm + i * 16 + lr4;
      if (seg == 2) {
        ushort4 o;
        o.x = f2bf(acc[i][j][0] + bc); o.y = f2bf(acc[i][j][1] + bc);
        o.z = f2bf(acc[i][j][2] + bc); o.w = f2bf(acc[i][j][3] + bc);
        const int b_ = row0 >> 10, s = row0 & 1023;
        const int h = col >> 6, d = col & 63;
        *(ushort4*)&vt[(((size_t)(b_ * 16 + h) * 64 + d) << 10) + s] = o;
      } else if (seg == 0) {
#pragma unroll
        for (int r = 0; r < 4; ++r) {
          const size_t idx = (size_t)(row0 + r) * 1024 + col;
          const float v = acc[i][j][r] + bc;
          qb[idx] = f2bf(v); qf[idx] = v;
        }
      } else {
#pragma unroll
        for (int r = 0; r < 4; ++r) {
          const size_t idx = (size_t)(row0 + r) * 1024 + col;
          kb[idx] = f2bf(acc[i][j][r] + bc);
        }
      }
    }
  }
}

// ---------------------------------------------------------------------------
// Wo-projection GEMM: 128x128 tile, BK=64, 4 waves, counted-vmcnt pipeline.
// ---------------------------------------------------------------------------
__global__ void __launch_bounds__(256)
gemm_proj(const u16* __restrict__ A, const u16* __restrict__ Bt,
          const float* __restrict__ bias, const float* __restrict__ resid,
          float* __restrict__ outf) {
  __shared__ u16 Alds[2][8192];
  __shared__ u16 Blds[2][8192];
  const int bm = blockIdx.y * 128, bn = blockIdx.x * 128;
  const int t = threadIdx.x, wv = t >> 6, ln = t & 63;
  const int wm = (wv >> 1) * 64, wn = (wv & 1) * 64;
  const int lcol = ln & 15, lk8 = (ln >> 4) * 8, lr4 = (ln >> 4) * 4;

  f32x4 acc[4][4] = {};

  auto STAGE = [&](int buf, int k0) {
#pragma unroll
    for (int c = 0; c < 4; ++c) {
      const int o = c * 4096 + wv * 1024 + ln * 16;
      const int row = o >> 7, colb = o & 127;
      gl_lds16((const char*)A + ((size_t)(bm + row) * 1024 + k0) * 2 + colb,
               (char*)Alds[buf] + c * 4096 + wv * 1024);
      gl_lds16((const char*)Bt + ((size_t)(bn + row) * 1024 + k0) * 2 + colb,
               (char*)Blds[buf] + c * 4096 + wv * 1024);
    }
  };

  auto COMPUTE = [&](int buf) {
    const u16* Ab = Alds[buf];
    const u16* Bb = Blds[buf];
#pragma unroll
    for (int ks = 0; ks < 2; ++ks) {
      bf16x8 a[4], b[4];
#pragma unroll
      for (int i = 0; i < 4; ++i)
        a[i] = *(const bf16x8*)&Ab[(wm + i * 16 + lcol) * 64 + ks * 32 + lk8];
#pragma unroll
      for (int j = 0; j < 4; ++j)
        b[j] = *(const bf16x8*)&Bb[(wn + j * 16 + lcol) * 64 + ks * 32 + lk8];
#pragma unroll
      for (int i = 0; i < 4; ++i)
#pragma unroll
        for (int j = 0; j < 4; ++j)
          acc[i][j] = __builtin_amdgcn_mfma_f32_16x16x32_bf16(a[i], b[j], acc[i][j], 0, 0, 0);
    }
  };

  STAGE(0, 0);
  int cur = 0;
  for (int it = 0; it < 15; ++it) {
    STAGE(cur ^ 1, (it + 1) * 64);
    VMCNT(8);
    SBARRIER();
    COMPUTE(cur);
    SBARRIER();
    cur ^= 1;
  }
  VMCNT(0);
  SBARRIER();
  COMPUTE(cur);

#pragma unroll
  for (int j = 0; j < 4; ++j) {
    const int col = bn + wn + j * 16 + lcol;
    const float bc = bias[col];
#pragma unroll
    for (int i = 0; i < 4; ++i) {
      const int row0 = bm + wm + i * 16 + lr4;
#pragma unroll
      for (int r = 0; r < 4; ++r) {
        const size_t idx = (size_t)(row0 + r) * 1024 + col;
        outf[idx] = acc[i][j][r] + bc + resid[idx];
      }
    }
  }
}

// ---------------------------------------------------------------------------
// Flash attention, swapped-QK^T, counted-vmcnt pipeline, mask prefetch.
// ---------------------------------------------------------------------------
__global__ void __launch_bounds__(256)
attn_kernel(const u16* __restrict__ Q, const u16* __restrict__ Kb,
            const u16* __restrict__ Vt, const float* __restrict__ mask,
            u16* __restrict__ ctx) {
  __shared__ u16 Klds[2][64 * 64];
  __shared__ u16 Vlds[2][64 * 64];
  __shared__ u16 Plds[4][16 * 64];

  const int fid = blockIdx.x;
  const int xcd = fid & 7, idx = fid >> 3;
  const int bh = xcd * 8 + (idx >> 4);
  const int b = bh >> 4, h = bh & 15;
  const int q0 = (idx & 15) * 64;

  const int t = threadIdx.x, wv = t >> 6, ln = t & 63;
  const int lcol = ln & 15, g = ln >> 4;
  const int lk8 = g * 8, c0 = g * 16;

  const int qrow = q0 + wv * 16 + lcol;
  const u16* qptr = Q + ((size_t)(b * 1024 + qrow) * 1024 + h * 64);
  bf16x8 qa[2];
  qa[0] = *(const bf16x8*)(qptr + lk8);
  qa[1] = *(const bf16x8*)(qptr + 32 + lk8);

  const float* mrow = mask + b * 1024;
  char* pbase = (char*)&Plds[wv][0];

  f32x4 accO[4] = {};
  float m_r = -1e30f, l_r = 0.f;

  auto STAGE = [&](int buf, int s0) {
#pragma unroll
    for (int c = 0; c < 2; ++c) {
      const int o = c * 4096 + wv * 1024 + ln * 16;
      const int row = o >> 7;
      const int src_cb = (o & 127) ^ ((row & 7) << 4);
      gl_lds16((const char*)Kb + ((size_t)((b * 1024 + s0 + row) * 1024 + h * 64)) * 2 + src_cb,
               (char*)Klds[buf] + c * 4096 + wv * 1024);
      gl_lds16((const char*)Vt + ((size_t)(((b * 16 + h) * 64 + row) * 1024 + s0)) * 2 + src_cb,
               (char*)Vlds[buf] + c * 4096 + wv * 1024);
    }
  };

  auto TILE = [&](int buf, const float4* mk) {
    f32x4 accST[4] = {};
    __builtin_amdgcn_s_setprio(1);
#pragma unroll
    for (int ks = 0; ks < 2; ++ks)
#pragma unroll
      for (int sb = 0; sb < 4; ++sb) {
        bf16x8 kb = *(const bf16x8*)((const char*)Klds[buf] + swz(sb * 16 + lcol, ks * 64 + c0));
        accST[sb] = __builtin_amdgcn_mfma_f32_16x16x32_bf16(kb, qa[ks], accST[sb], 0, 0, 0);
      }
    __builtin_amdgcn_s_setprio(0);

    float sv[4][4];
#pragma unroll
    for (int sb = 0; sb < 4; ++sb) {
      sv[sb][0] = accST[sb][0] * 0.125f + mk[sb].x;
      sv[sb][1] = accST[sb][1] * 0.125f + mk[sb].y;
      sv[sb][2] = accST[sb][2] * 0.125f + mk[sb].z;
      sv[sb][3] = accST[sb][3] * 0.125f + mk[sb].w;
    }
    float mt = sv[0][0];
#pragma unroll
    for (int sb = 0; sb < 4; ++sb)
#pragma unroll
      for (int r = 0; r < 4; ++r) mt = fmaxf(mt, sv[sb][r]);
    mt = fmaxf(mt, __shfl_xor(mt, 16));
    mt = fmaxf(mt, __shfl_xor(mt, 32));

    const float mn = fmaxf(m_r, mt);
    const float alpha = __expf(m_r - mn);
    m_r = mn;
    float rs = 0.f;
#pragma unroll
    for (int sb = 0; sb < 4; ++sb)
#pragma unroll
      for (int r = 0; r < 4; ++r) {
        const float pp = __expf(sv[sb][r] - mn);
        sv[sb][r] = pp;
        rs += pp;
      }
    rs += __shfl_xor(rs, 16);
    rs += __shfl_xor(rs, 32);
    l_r = l_r * alpha + rs;

#pragma unroll
    for (int sb = 0; sb < 4; ++sb) {
      uint2 dd;
      dd.x = cvt_pk_bf16(sv[sb][0], sv[sb][1]);
      dd.y = cvt_pk_bf16(sv[sb][2], sv[sb][3]);
      *(uint2*)(pbase + swz(lcol, sb * 32 + g * 8)) = dd;
    }

#pragma unroll
    for (int df = 0; df < 4; ++df)
#pragma unroll
      for (int r = 0; r < 4; ++r) accO[df][r] *= alpha;
    __builtin_amdgcn_s_setprio(1);
#pragma unroll
    for (int ks = 0; ks < 2; ++ks) {
      bf16x8 pb = *(const bf16x8*)(pbase + swz(lcol, ks * 64 + c0));
#pragma unroll
      for (int df = 0; df < 4; ++df) {
        bf16x8 va = *(const bf16x8*)((const char*)Vlds[buf] + swz(df * 16 + lcol, ks * 64 + c0));
        accO[df] = __builtin_amdgcn_mfma_f32_16x16x32_bf16(va, pb, accO[df], 0, 0, 0);
      }
    }
    __builtin_amdgcn_s_setprio(0);
  };

  STAGE(0, 0);
  float4 mk_cur[4];
#pragma unroll
  for (int sb = 0; sb < 4; ++sb)
    mk_cur[sb] = *(const float4*)&mrow[sb * 16 + g * 4];

  int cur = 0;
  for (int ti = 0; ti < 15; ++ti) {
    const int s1 = ti * 64 + 64;
    STAGE(cur ^ 1, s1);
    float4 mk_nxt[4];
#pragma unroll
    for (int sb = 0; sb < 4; ++sb)
      mk_nxt[sb] = *(const float4*)&mrow[s1 + sb * 16 + g * 4];
    VMCNT(12);
    SBARRIER();
    TILE(cur, mk_cur);
    SBARRIER();
#pragma unroll
    for (int sb = 0; sb < 4; ++sb) mk_cur[sb] = mk_nxt[sb];
    cur ^= 1;
  }
  VMCNT(4);
  SBARRIER();
  TILE(cur, mk_cur);

  const float inv = 1.0f / l_r;
  u16* cp = ctx + ((size_t)(b * 1024 + qrow) * 1024 + h * 64);
#pragma unroll
  for (int df = 0; df < 4; ++df) {
    ushort4 o;
    o.x = f2bf(accO[df][0] * inv); o.y = f2bf(accO[df][1] * inv);
    o.z = f2bf(accO[df][2] * inv); o.w = f2bf(accO[df][3] * inv);
    *(ushort4*)(cp + df * 16 + g * 4) = o;
  }
}

// ---------------------------------------------------------------------------
// LayerNorm over rows of x[4096][1024]; OUTF=1 -> f32 out, else bf16 out
// ---------------------------------------------------------------------------
template <int OUTF>
__global__ void __launch_bounds__(256)
ln_kernel(const float* __restrict__ x, const float* __restrict__ gamma,
          const float* __restrict__ beta, float* __restrict__ outf,
          u16* __restrict__ outb) {
  const int row = blockIdx.x, t = threadIdx.x;
  const float* xr = x + (size_t)row * 1024;
  float4 v = *(const float4*)&xr[t * 4];
  float s = v.x + v.y + v.z + v.w;
  float q = v.x * v.x + v.y * v.y + v.z * v.z + v.w * v.w;
#pragma unroll
  for (int off = 1; off < 64; off <<= 1) {
    s += __shfl_xor(s, off);
    q += __shfl_xor(q, off);
  }
  __shared__ float ws[4], wq[4];
  if ((t & 63) == 0) { ws[t >> 6] = s; wq[t >> 6] = q; }
  __syncthreads();
  s = ws[0] + ws[1] + ws[2] + ws[3];
  q = wq[0] + wq[1] + wq[2] + wq[3];
  const float mu = s * (1.0f / 1024.0f);
  float var = q * (1.0f / 1024.0f) - mu * mu;
  var = fmaxf(var, 0.0f);
  const float rstd = rsqrtf(var + 1e-12f);
  float4 g = *(const float4*)&gamma[t * 4];
  float4 be = *(const float4*)&beta[t * 4];
  float y0 = (v.x - mu) * rstd * g.x + be.x;
  float y1 = (v.y - mu) * rstd * g.y + be.y;
  float y2 = (v.z - mu) * rstd * g.z + be.z;
  float y3 = (v.w - mu) * rstd * g.w + be.w;
  if constexpr (OUTF) {
    float4 o; o.x = y0; o.y = y1; o.z = y2; o.w = y3;
    *(float4*)&outf[(size_t)row * 1024 + t * 4] = o;
  } else {
    ushort4 o; o.x = f2bf(y0); o.y = f2bf(y1); o.z = f2bf(y2); o.w = f2bf(y3);
    *(ushort4*)&outb[(size_t)row * 1024 + t * 4] = o;
  }
}

// ---------------------------------------------------------------------------
extern "C" void kernel_launch(void* const* d_in, const int* in_sizes, int n_in,
                              void* d_out, int out_size, void* d_ws, size_t ws_size,
                              hipStream_t stream) {
  const float* enc = (const float*)d_in[0];
  const float* dec = (const float*)d_in[1];
  const float* src_mask = (const float*)d_in[2];
  const float* tgt_mask = (const float*)d_in[3];
  const float* Wq  = (const float*)d_in[4];  const float* bq  = (const float*)d_in[5];
  const float* Wk  = (const float*)d_in[6];  const float* bk  = (const float*)d_in[7];
  const float* Wv  = (const float*)d_in[8];  const float* bv  = (const float*)d_in[9];
  const float* Wq2 = (const float*)d_in[10]; const float* bq2 = (const float*)d_in[11];
  const float* Wk2 = (const float*)d_in[12]; const float* bk2 = (const float*)d_in[13];
  const float* Wv2 = (const float*)d_in[14]; const float* bv2 = (const float*)d_in[15];
  const float* Wo  = (const float*)d_in[16]; const float* bo  = (const float*)d_in[17];
  const float* gamma = (const float*)d_in[18]; const float* beta = (const float*)d_in[19];
  float* out = (float*)d_out;

  char* p = (char*)d_ws;
  const size_t ABF = (size_t)4096 * 1024 * 2;
  const size_t AF  = (size_t)4096 * 1024 * 4;
  const size_t WBF = (size_t)1024 * 1024 * 2;
  u16* decbf = (u16*)p; p += ABF;
  u16* encbf = (u16*)p; p += ABF;
  u16* wt    = (u16*)p; p += 7 * WBF;
  u16* qbf   = (u16*)p; p += ABF;
  float* qf  = (float*)p; p += AF;
  u16* kbf   = (u16*)p; p += ABF;
  u16* vtb   = (u16*)p; p += ABF;
  u16* ctxb  = (u16*)p; p += ABF;
  float* tmpf = (float*)p; p += AF;
  u16* sobf  = decbf;  // reuse: decoder bf16 dead after layer-1 projections

  u16* WoT  = wt + 6 * 1048576;

  dim3 b256(256);
  convert2_kernel<<<8192, b256, 0, stream>>>(dec, decbf, enc, encbf);
  WP wp;
  wp.w[0] = Wq; wp.w[1] = Wk; wp.w[2] = Wv; wp.w[3] = Wq2;
  wp.w[4] = Wk2; wp.w[5] = Wv2; wp.w[6] = Wo;
  transpose_kernel<<<dim3(16, 16, 7), b256, 0, stream>>>(wp, wt);

  // ---- layer 1 (self-attention on decoder inputs) ----
  qkv8p_kernel<<<dim3(12, 16), 512, 0, stream>>>(
      decbf, decbf, decbf, wt, bq, bk, bv, qbf, qf, kbf, vtb);
  attn_kernel<<<1024, b256, 0, stream>>>(qbf, kbf, vtb, tgt_mask, ctxb);
  gemm_proj<<<dim3(8, 32), b256, 0, stream>>>(ctxb, WoT, bo, qf, tmpf);
  ln_kernel<0><<<4096, b256, 0, stream>>>(tmpf, gamma, beta, nullptr, sobf);
  // ---- layer 2 (cross-attention vs encoder states) ----
  qkv8p_kernel<<<dim3(12, 16), 512, 0, stream>>>(
      sobf, encbf, encbf, wt + 3 * 1048576, bq2, bk2, bv2, qbf, qf, kbf, vtb);
  attn_kernel<<<1024, b256, 0, stream>>>(qbf, kbf, vtb, src_mask, ctxb);
  gemm_proj<<<dim3(8, 32), b256, 0, stream>>>(ctxb, WoT, bo, qf, tmpf);
  ln_kernel<1><<<4096, b256, 0, stream>>>(tmpf, gamma, beta, out, nullptr);
}

// Round 7
// 234.189 us; speedup vs baseline: 1.6827x; 1.0338x over previous
//
#include <hip/hip_runtime.h>
#include <stdint.h>

// ---------------------------------------------------------------------------
// AlbertDecoderAttention on MI355X (gfx950) — round 7
// Changes vs round 6:
//  * qkv: BK=32 with FOUR LDS buffers (128KB) — stage tile t+2 during tile t,
//    so global_load_lds lead time (~2 tiles ≈ 1100+cyc) > HBM latency;
//    counted vmcnt(4) at tile end; 2 phases/tile; T2 swizzle (2-bit XOR on
//    64B rows); asm ds_read_b128; setprio. 2D XCD-chunked tile mapping.
//  * dropped f32 residual buffer (qf): residual flows as bf16 (saves 32MB/layer).
//  * gemm_proj: bf16 resid + XCD-chunked mapping.
//  * attn: T13 defer-max (skip O-rescale when tile max within +8 of running).
// ---------------------------------------------------------------------------

typedef unsigned short u16;
typedef __bf16 bf16x8 __attribute__((ext_vector_type(8)));
typedef float f32x4 __attribute__((ext_vector_type(4)));

#define AS1 __attribute__((address_space(1)))
#define AS3 __attribute__((address_space(3)))
typedef AS3 char lds_char;
typedef AS3 unsigned short lds_u16;

#define VMCNT(n) asm volatile("s_waitcnt vmcnt(" #n ")" ::: "memory")
#define LGKM0() asm volatile("s_waitcnt lgkmcnt(0)" ::: "memory")
#define SBARRIER() asm volatile("s_barrier" ::: "memory")

__device__ __forceinline__ u16 f2bf(float f) {
  union { float f; uint32_t u; } v; v.f = f;
  uint32_t u = v.u;
  return (u16)((u + 0x7fffu + ((u >> 16) & 1u)) >> 16);  // RNE
}

__device__ __forceinline__ float bf2f(u16 b) {
  union { uint32_t u; float f; } v; v.u = ((uint32_t)b) << 16;
  return v.f;
}

__device__ __forceinline__ uint32_t cvt_pk_bf16(float lo, float hi) {
  uint32_t r;
  asm("v_cvt_pk_bf16_f32 %0, %1, %2" : "=v"(r) : "v"(lo), "v"(hi));
  return r;
}

__device__ __forceinline__ void gl_lds16(const void* g, void* l) {
  __builtin_amdgcn_global_load_lds((AS1 void*)(g), (AS3 void*)(l), 16, 0, 0);
}

__device__ __forceinline__ bf16x8 dsr128(const lds_u16* p) {
  bf16x8 r;
  asm volatile("ds_read_b128 %0, %1" : "=v"(r) : "v"(p));
  return r;
}

// swizzled byte address within a [rows][128B] LDS tile (attn tiles)
__device__ __forceinline__ int swz(int row, int byte) {
  return row * 128 + (byte ^ ((row & 7) << 4));
}

// ---------------------------------------------------------------------------
// f32 -> bf16 convert, two tensors in one launch (each 4096*1024 elems)
// ---------------------------------------------------------------------------
__global__ void __launch_bounds__(256)
convert2_kernel(const float* __restrict__ in0, u16* __restrict__ out0,
                const float* __restrict__ in1, u16* __restrict__ out1) {
  const int half = blockIdx.x >> 12;
  const int i = (blockIdx.x & 4095) * 256 + threadIdx.x;
  const float* in = half ? in1 : in0;
  u16* out = half ? out1 : out0;
  float4 v = ((const float4*)in)[i];
  ushort4 o;
  o.x = f2bf(v.x); o.y = f2bf(v.y); o.z = f2bf(v.z); o.w = f2bf(v.w);
  ((ushort4*)out)[i] = o;
}

// ---------------------------------------------------------------------------
// Weight transpose + convert: W[k][n] f32 -> Wt[n][k] bf16 (7 matrices)
// ---------------------------------------------------------------------------
struct WP { const float* w[7]; };

__global__ void __launch_bounds__(256)
transpose_kernel(WP wp, u16* __restrict__ out) {
  __shared__ float tile[64][65];
  const float* W = wp.w[blockIdx.z];
  u16* Wt = out + (size_t)blockIdx.z * 1024 * 1024;
  const int k0 = blockIdx.y * 64, n0 = blockIdx.x * 64;
  const int t = threadIdx.x;
  const int r = t >> 4, c4 = (t & 15) * 4;
#pragma unroll
  for (int rr = 0; rr < 64; rr += 16) {
    float4 v = *(const float4*)&W[(size_t)(k0 + r + rr) * 1024 + n0 + c4];
    tile[r + rr][c4 + 0] = v.x; tile[r + rr][c4 + 1] = v.y;
    tile[r + rr][c4 + 2] = v.z; tile[r + rr][c4 + 3] = v.w;
  }
  __syncthreads();
  const int n = t >> 2, seg = (t & 3) * 16;
  union { u16 s[16]; uint4 q[2]; } u;
#pragma unroll
  for (int i = 0; i < 16; ++i) u.s[i] = f2bf(tile[seg + i][n]);
  uint4* dst = (uint4*)&Wt[(size_t)(n0 + n) * 1024 + k0 + seg];
  dst[0] = u.q[0]; dst[1] = u.q[1];
}

// ---------------------------------------------------------------------------
// qkv4b: 3-segment projection GEMM. 256x256 tile, BK=32, 8 waves (2Mx4N),
// FOUR-buffer LDS (stage t+2 during t), counted vmcnt(4), 2 phases/tile.
// LDS rows are 64B (32 bf16), swizzled: byte ^= (row&3)<<4.
// Bt = [W0|W1|W2] as [3072][1024] bf16. seg0->qb, seg1->kb, seg2->Vt.
// ---------------------------------------------------------------------------
__global__ void __launch_bounds__(512, 2)
qkv4b_kernel(const u16* __restrict__ A0, const u16* __restrict__ A1,
             const u16* __restrict__ A2, const u16* __restrict__ Bt,
             const float* __restrict__ b0, const float* __restrict__ b1,
             const float* __restrict__ b2,
             u16* __restrict__ qb, u16* __restrict__ kb, u16* __restrict__ vt) {
  __shared__ u16 Alds[4][256 * 32];   // 16KB per buffer
  __shared__ u16 Blds[4][256 * 32];

  // 2D XCD-chunked tile mapping: dispatch d -> XCD chunk 4m x 6n
  const int d = blockIdx.y * 12 + blockIdx.x;
  const int c = d & 7, ci = d >> 3;            // 192 = 8 * 24
  const int mt = (c & 3) * 4 + (ci & 3);       // 0..15
  const int nt = (c >> 2) * 6 + (ci >> 2);     // 0..11
  const int bm = mt * 256, bn = nt * 256;
  const int seg = nt >> 2;
  const u16* A = (seg == 0) ? A0 : (seg == 1) ? A1 : A2;

  const int t = threadIdx.x, wv = t >> 6, ln = t & 63;
  const int wm = (wv >> 2) * 128, wn = (wv & 3) * 64;
  const int lcol = ln & 15, g = ln >> 4, lr4 = g * 4;
  const int aoff = (g * 16) ^ ((lcol & 3) << 4);  // frag byte off in 64B row

  lds_char* ABase = (lds_char*)&Alds[0][0];
  lds_char* BBase = (lds_char*)&Blds[0][0];

  // staging: per wave 2 gl_lds per matrix per tile (row halves 0-127,128-255)
  const int st_row = wv * 16 + (ln >> 2);                  // within half
  const int st_srcb = (((ln & 3) ^ ((ln >> 2) & 3)) * 16); // inv-swizzle src
  auto stageA = [&](int buf, int k0) {
#pragma unroll
    for (int hf = 0; hf < 2; ++hf) {
      const int row = hf * 128 + st_row;
      gl_lds16((const char*)A + ((size_t)(bm + row) * 1024 + k0) * 2 + st_srcb,
               (char*)ABase + buf * 16384 + hf * 8192 + wv * 1024);
    }
  };
  auto stageB = [&](int buf, int k0) {
#pragma unroll
    for (int hf = 0; hf < 2; ++hf) {
      const int row = hf * 128 + st_row;
      gl_lds16((const char*)Bt + ((size_t)(bn + row) * 1024 + k0) * 2 + st_srcb,
               (char*)BBase + buf * 16384 + hf * 8192 + wv * 1024);
    }
  };

  f32x4 acc[8][4] = {};

  // prologue: stage tiles 0 and 1; wait tile 0 (leave tile 1 in flight)
  stageA(0, 0); stageB(0, 0);
  stageA(1, 32); stageB(1, 32);
  VMCNT(4);
  __builtin_amdgcn_s_barrier();

  for (int kt = 0; kt < 32; ++kt) {
    const int buf = kt & 3;
    lds_char* Ab = ABase + buf * 16384;
    lds_char* Bb = BBase + buf * 16384;
    const int sbuf = (kt + 2) & 3;
    const int sk = (kt + 2) * 32;
    const bool do_st = kt < 30;
    bf16x8 afr[4], bfr[4];

    // ---- phase 0: frags B j0-3 + A i0-3; stage A(t+2); MFMA i0-3
#pragma unroll
    for (int j = 0; j < 4; ++j)
      bfr[j] = dsr128((const lds_u16*)(Bb + (wn + j * 16 + lcol) * 64 + aoff));
#pragma unroll
    for (int i = 0; i < 4; ++i)
      afr[i] = dsr128((const lds_u16*)(Ab + (wm + i * 16 + lcol) * 64 + aoff));
    if (do_st) stageA(sbuf, sk);
    __builtin_amdgcn_s_barrier();
    LGKM0();
    __builtin_amdgcn_sched_barrier(0);
    __builtin_amdgcn_s_setprio(1);
#pragma unroll
    for (int i = 0; i < 4; ++i)
#pragma unroll
      for (int j = 0; j < 4; ++j)
        acc[i][j] = __builtin_amdgcn_mfma_f32_16x16x32_bf16(afr[i], bfr[j], acc[i][j], 0, 0, 0);
    __builtin_amdgcn_s_setprio(0);
    __builtin_amdgcn_s_barrier();

    // ---- phase 1: frags A i4-7 (B reused); stage B(t+2); MFMA i4-7
#pragma unroll
    for (int i = 0; i < 4; ++i)
      afr[i] = dsr128((const lds_u16*)(Ab + (wm + 64 + i * 16 + lcol) * 64 + aoff));
    if (do_st) stageB(sbuf, sk);
    __builtin_amdgcn_s_barrier();
    LGKM0();
    __builtin_amdgcn_sched_barrier(0);
    __builtin_amdgcn_s_setprio(1);
#pragma unroll
    for (int i = 0; i < 4; ++i)
#pragma unroll
      for (int j = 0; j < 4; ++j)
        acc[4 + i][j] = __builtin_amdgcn_mfma_f32_16x16x32_bf16(afr[i], bfr[j], acc[4 + i][j], 0, 0, 0);
    __builtin_amdgcn_s_setprio(0);
    if (kt < 30) { VMCNT(4); }       // tile kt+1 landed; t+2 stays in flight
    else if (kt == 30) { VMCNT(0); } // last tile's stages
    __builtin_amdgcn_s_barrier();
  }

  // epilogue (bf16 outputs only)
  const int cs = bn & 1023;
  const float* bias = (seg == 0) ? b0 : (seg == 1) ? b1 : b2;
  u16* outp = (seg == 0) ? qb : kb;
#pragma unroll
  for (int j = 0; j < 4; ++j) {
    const int col = cs + wn + j * 16 + lcol;
    const float bc = bias[col];
#pragma unroll
    for (int i = 0; i < 8; ++i) {
      const int row0 = bm + wm + i * 16 + lr4;
      if (seg == 2) {
        ushort4 o;
        o.x = f2bf(acc[i][j][0] + bc); o.y = f2bf(acc[i][j][1] + bc);
        o.z = f2bf(acc[i][j][2] + bc); o.w = f2bf(acc[i][j][3] + bc);
        const int b_ = row0 >> 10, s = row0 & 1023;
        const int h = col >> 6, dd = col & 63;
        *(ushort4*)&vt[(((size_t)(b_ * 16 + h) * 64 + dd) << 10) + s] = o;
      } else {
#pragma unroll
        for (int r = 0; r < 4; ++r)
          outp[(size_t)(row0 + r) * 1024 + col] = f2bf(acc[i][j][r] + bc);
      }
    }
  }
}

// ---------------------------------------------------------------------------
// Wo-projection GEMM: 128x128 tile, BK=64, 4 waves, counted-vmcnt pipeline.
// out f32 = acc + bias + bf2f(resid). XCD-chunked tile mapping (8m x 4n).
// ---------------------------------------------------------------------------
__global__ void __launch_bounds__(256)
gemm_proj(const u16* __restrict__ A, const u16* __restrict__ Bt,
          const float* __restrict__ bias, const u16* __restrict__ resid,
          float* __restrict__ outf) {
  __shared__ u16 Alds[2][8192];
  __shared__ u16 Blds[2][8192];
  const int d = blockIdx.y * 8 + blockIdx.x;   // 256 blocks
  const int c = d & 7, ci = d >> 3;            // 256 = 8 * 32
  const int mt = (c & 3) * 8 + (ci & 7);       // 0..31
  const int nt = (c >> 2) * 4 + (ci >> 3);     // 0..7
  const int bm = mt * 128, bn = nt * 128;
  const int t = threadIdx.x, wv = t >> 6, ln = t & 63;
  const int wm = (wv >> 1) * 64, wn = (wv & 1) * 64;
  const int lcol = ln & 15, lk8 = (ln >> 4) * 8, lr4 = (ln >> 4) * 4;

  f32x4 acc[4][4] = {};

  auto STAGE = [&](int buf, int k0) {
#pragma unroll
    for (int cc = 0; cc < 4; ++cc) {
      const int o = cc * 4096 + wv * 1024 + ln * 16;
      const int row = o >> 7, colb = o & 127;
      gl_lds16((const char*)A + ((size_t)(bm + row) * 1024 + k0) * 2 + colb,
               (char*)Alds[buf] + cc * 4096 + wv * 1024);
      gl_lds16((const char*)Bt + ((size_t)(bn + row) * 1024 + k0) * 2 + colb,
               (char*)Blds[buf] + cc * 4096 + wv * 1024);
    }
  };

  auto COMPUTE = [&](int buf) {
    const u16* Ab = Alds[buf];
    const u16* Bb = Blds[buf];
#pragma unroll
    for (int ks = 0; ks < 2; ++ks) {
      bf16x8 a[4], b[4];
#pragma unroll
      for (int i = 0; i < 4; ++i)
        a[i] = *(const bf16x8*)&Ab[(wm + i * 16 + lcol) * 64 + ks * 32 + lk8];
#pragma unroll
      for (int j = 0; j < 4; ++j)
        b[j] = *(const bf16x8*)&Bb[(wn + j * 16 + lcol) * 64 + ks * 32 + lk8];
#pragma unroll
      for (int i = 0; i < 4; ++i)
#pragma unroll
        for (int j = 0; j < 4; ++j)
          acc[i][j] = __builtin_amdgcn_mfma_f32_16x16x32_bf16(a[i], b[j], acc[i][j], 0, 0, 0);
    }
  };

  STAGE(0, 0);
  int cur = 0;
  for (int it = 0; it < 15; ++it) {
    STAGE(cur ^ 1, (it + 1) * 64);
    VMCNT(8);
    SBARRIER();
    COMPUTE(cur);
    SBARRIER();
    cur ^= 1;
  }
  VMCNT(0);
  SBARRIER();
  COMPUTE(cur);

#pragma unroll
  for (int j = 0; j < 4; ++j) {
    const int col = bn + wn + j * 16 + lcol;
    const float bc = bias[col];
#pragma unroll
    for (int i = 0; i < 4; ++i) {
      const int row0 = bm + wm + i * 16 + lr4;
#pragma unroll
      for (int r = 0; r < 4; ++r) {
        const size_t idx = (size_t)(row0 + r) * 1024 + col;
        outf[idx] = acc[i][j][r] + bc + bf2f(resid[idx]);
      }
    }
  }
}

// ---------------------------------------------------------------------------
// Flash attention, swapped-QK^T, counted-vmcnt pipeline, mask prefetch,
// defer-max (T13). grid 1024 blocks 1D (XCD-grouped), 4 waves x 16 q-rows.
// ---------------------------------------------------------------------------
__global__ void __launch_bounds__(256)
attn_kernel(const u16* __restrict__ Q, const u16* __restrict__ Kb,
            const u16* __restrict__ Vt, const float* __restrict__ mask,
            u16* __restrict__ ctx) {
  __shared__ u16 Klds[2][64 * 64];
  __shared__ u16 Vlds[2][64 * 64];
  __shared__ u16 Plds[4][16 * 64];

  const int fid = blockIdx.x;
  const int xcd = fid & 7, idx = fid >> 3;
  const int bh = xcd * 8 + (idx >> 4);
  const int b = bh >> 4, h = bh & 15;
  const int q0 = (idx & 15) * 64;

  const int t = threadIdx.x, wv = t >> 6, ln = t & 63;
  const int lcol = ln & 15, g = ln >> 4;
  const int lk8 = g * 8, c0 = g * 16;

  const int qrow = q0 + wv * 16 + lcol;
  const u16* qptr = Q + ((size_t)(b * 1024 + qrow) * 1024 + h * 64);
  bf16x8 qa[2];
  qa[0] = *(const bf16x8*)(qptr + lk8);
  qa[1] = *(const bf16x8*)(qptr + 32 + lk8);

  const float* mrow = mask + b * 1024;
  char* pbase = (char*)&Plds[wv][0];

  f32x4 accO[4] = {};
  float m_r = -1e30f, l_r = 0.f;

  auto STAGE = [&](int buf, int s0) {
#pragma unroll
    for (int c = 0; c < 2; ++c) {
      const int o = c * 4096 + wv * 1024 + ln * 16;
      const int row = o >> 7;
      const int src_cb = (o & 127) ^ ((row & 7) << 4);
      gl_lds16((const char*)Kb + ((size_t)((b * 1024 + s0 + row) * 1024 + h * 64)) * 2 + src_cb,
               (char*)Klds[buf] + c * 4096 + wv * 1024);
      gl_lds16((const char*)Vt + ((size_t)(((b * 16 + h) * 64 + row) * 1024 + s0)) * 2 + src_cb,
               (char*)Vlds[buf] + c * 4096 + wv * 1024);
    }
  };

  auto TILE = [&](int buf, const float4* mk) {
    f32x4 accST[4] = {};
    __builtin_amdgcn_s_setprio(1);
#pragma unroll
    for (int ks = 0; ks < 2; ++ks)
#pragma unroll
      for (int sb = 0; sb < 4; ++sb) {
        bf16x8 kb = *(const bf16x8*)((const char*)Klds[buf] + swz(sb * 16 + lcol, ks * 64 + c0));
        accST[sb] = __builtin_amdgcn_mfma_f32_16x16x32_bf16(kb, qa[ks], accST[sb], 0, 0, 0);
      }
    __builtin_amdgcn_s_setprio(0);

    float sv[4][4];
#pragma unroll
    for (int sb = 0; sb < 4; ++sb) {
      sv[sb][0] = accST[sb][0] * 0.125f + mk[sb].x;
      sv[sb][1] = accST[sb][1] * 0.125f + mk[sb].y;
      sv[sb][2] = accST[sb][2] * 0.125f + mk[sb].z;
      sv[sb][3] = accST[sb][3] * 0.125f + mk[sb].w;
    }
    float mt = sv[0][0];
#pragma unroll
    for (int sb = 0; sb < 4; ++sb)
#pragma unroll
      for (int r = 0; r < 4; ++r) mt = fmaxf(mt, sv[sb][r]);
    mt = fmaxf(mt, __shfl_xor(mt, 16));
    mt = fmaxf(mt, __shfl_xor(mt, 32));

    // defer-max: skip rescale when tile max within +8 of running max
    const bool nr = __all(mt <= m_r + 8.0f) != 0;
    float alpha = 1.0f;
    if (!nr) {
      const float mn2 = fmaxf(m_r, mt);
      alpha = __expf(m_r - mn2);
      m_r = mn2;
    }
    float rs = 0.f;
#pragma unroll
    for (int sb = 0; sb < 4; ++sb)
#pragma unroll
      for (int r = 0; r < 4; ++r) {
        const float pp = __expf(sv[sb][r] - m_r);
        sv[sb][r] = pp;
        rs += pp;
      }
    rs += __shfl_xor(rs, 16);
    rs += __shfl_xor(rs, 32);
    l_r = nr ? (l_r + rs) : (l_r * alpha + rs);

#pragma unroll
    for (int sb = 0; sb < 4; ++sb) {
      uint2 dd;
      dd.x = cvt_pk_bf16(sv[sb][0], sv[sb][1]);
      dd.y = cvt_pk_bf16(sv[sb][2], sv[sb][3]);
      *(uint2*)(pbase + swz(lcol, sb * 32 + g * 8)) = dd;
    }

    if (!nr) {
#pragma unroll
      for (int df = 0; df < 4; ++df)
#pragma unroll
        for (int r = 0; r < 4; ++r) accO[df][r] *= alpha;
    }
    __builtin_amdgcn_s_setprio(1);
#pragma unroll
    for (int ks = 0; ks < 2; ++ks) {
      bf16x8 pb = *(const bf16x8*)(pbase + swz(lcol, ks * 64 + c0));
#pragma unroll
      for (int df = 0; df < 4; ++df) {
        bf16x8 va = *(const bf16x8*)((const char*)Vlds[buf] + swz(df * 16 + lcol, ks * 64 + c0));
        accO[df] = __builtin_amdgcn_mfma_f32_16x16x32_bf16(va, pb, accO[df], 0, 0, 0);
      }
    }
    __builtin_amdgcn_s_setprio(0);
  };

  STAGE(0, 0);
  float4 mk_cur[4];
#pragma unroll
  for (int sb = 0; sb < 4; ++sb)
    mk_cur[sb] = *(const float4*)&mrow[sb * 16 + g * 4];

  int cur = 0;
  for (int ti = 0; ti < 15; ++ti) {
    const int s1 = ti * 64 + 64;
    STAGE(cur ^ 1, s1);
    float4 mk_nxt[4];
#pragma unroll
    for (int sb = 0; sb < 4; ++sb)
      mk_nxt[sb] = *(const float4*)&mrow[s1 + sb * 16 + g * 4];
    VMCNT(12);
    SBARRIER();
    TILE(cur, mk_cur);
    SBARRIER();
#pragma unroll
    for (int sb = 0; sb < 4; ++sb) mk_cur[sb] = mk_nxt[sb];
    cur ^= 1;
  }
  VMCNT(4);
  SBARRIER();
  TILE(cur, mk_cur);

  const float inv = 1.0f / l_r;
  u16* cp = ctx + ((size_t)(b * 1024 + qrow) * 1024 + h * 64);
#pragma unroll
  for (int df = 0; df < 4; ++df) {
    ushort4 o;
    o.x = f2bf(accO[df][0] * inv); o.y = f2bf(accO[df][1] * inv);
    o.z = f2bf(accO[df][2] * inv); o.w = f2bf(accO[df][3] * inv);
    *(ushort4*)(cp + df * 16 + g * 4) = o;
  }
}

// ---------------------------------------------------------------------------
// LayerNorm over rows of x[4096][1024]; OUTF=1 -> f32 out, else bf16 out
// ---------------------------------------------------------------------------
template <int OUTF>
__global__ void __launch_bounds__(256)
ln_kernel(const float* __restrict__ x, const float* __restrict__ gamma,
          const float* __restrict__ beta, float* __restrict__ outf,
          u16* __restrict__ outb) {
  const int row = blockIdx.x, t = threadIdx.x;
  const float* xr = x + (size_t)row * 1024;
  float4 v = *(const float4*)&xr[t * 4];
  float s = v.x + v.y + v.z + v.w;
  float q = v.x * v.x + v.y * v.y + v.z * v.z + v.w * v.w;
#pragma unroll
  for (int off = 1; off < 64; off <<= 1) {
    s += __shfl_xor(s, off);
    q += __shfl_xor(q, off);
  }
  __shared__ float ws[4], wq[4];
  if ((t & 63) == 0) { ws[t >> 6] = s; wq[t >> 6] = q; }
  __syncthreads();
  s = ws[0] + ws[1] + ws[2] + ws[3];
  q = wq[0] + wq[1] + wq[2] + wq[3];
  const float mu = s * (1.0f / 1024.0f);
  float var = q * (1.0f / 1024.0f) - mu * mu;
  var = fmaxf(var, 0.0f);
  const float rstd = rsqrtf(var + 1e-12f);
  float4 g = *(const float4*)&gamma[t * 4];
  float4 be = *(const float4*)&beta[t * 4];
  float y0 = (v.x - mu) * rstd * g.x + be.x;
  float y1 = (v.y - mu) * rstd * g.y + be.y;
  float y2 = (v.z - mu) * rstd * g.z + be.z;
  float y3 = (v.w - mu) * rstd * g.w + be.w;
  if constexpr (OUTF) {
    float4 o; o.x = y0; o.y = y1; o.z = y2; o.w = y3;
    *(float4*)&outf[(size_t)row * 1024 + t * 4] = o;
  } else {
    ushort4 o; o.x = f2bf(y0); o.y = f2bf(y1); o.z = f2bf(y2); o.w = f2bf(y3);
    *(ushort4*)&outb[(size_t)row * 1024 + t * 4] = o;
  }
}

// ---------------------------------------------------------------------------
extern "C" void kernel_launch(void* const* d_in, const int* in_sizes, int n_in,
                              void* d_out, int out_size, void* d_ws, size_t ws_size,
                              hipStream_t stream) {
  const float* enc = (const float*)d_in[0];
  const float* dec = (const float*)d_in[1];
  const float* src_mask = (const float*)d_in[2];
  const float* tgt_mask = (const float*)d_in[3];
  const float* Wq  = (const float*)d_in[4];  const float* bq  = (const float*)d_in[5];
  const float* Wk  = (const float*)d_in[6];  const float* bk  = (const float*)d_in[7];
  const float* Wv  = (const float*)d_in[8];  const float* bv  = (const float*)d_in[9];
  const float* Wq2 = (const float*)d_in[10]; const float* bq2 = (const float*)d_in[11];
  const float* Wk2 = (const float*)d_in[12]; const float* bk2 = (const float*)d_in[13];
  const float* Wv2 = (const float*)d_in[14]; const float* bv2 = (const float*)d_in[15];
  const float* Wo  = (const float*)d_in[16]; const float* bo  = (const float*)d_in[17];
  const float* gamma = (const float*)d_in[18]; const float* beta = (const float*)d_in[19];
  float* out = (float*)d_out;

  char* p = (char*)d_ws;
  const size_t ABF = (size_t)4096 * 1024 * 2;
  const size_t AF  = (size_t)4096 * 1024 * 4;
  const size_t WBF = (size_t)1024 * 1024 * 2;
  u16* decbf = (u16*)p; p += ABF;
  u16* encbf = (u16*)p; p += ABF;
  u16* wt    = (u16*)p; p += 7 * WBF;
  u16* qbf   = (u16*)p; p += ABF;
  u16* kbf   = (u16*)p; p += ABF;
  u16* vtb   = (u16*)p; p += ABF;
  u16* ctxb  = (u16*)p; p += ABF;
  float* tmpf = (float*)p; p += AF;
  u16* sobf  = decbf;  // reuse: decoder bf16 dead after layer-1 projections

  u16* WoT  = wt + 6 * 1048576;

  dim3 b256(256);
  convert2_kernel<<<8192, b256, 0, stream>>>(dec, decbf, enc, encbf);
  WP wp;
  wp.w[0] = Wq; wp.w[1] = Wk; wp.w[2] = Wv; wp.w[3] = Wq2;
  wp.w[4] = Wk2; wp.w[5] = Wv2; wp.w[6] = Wo;
  transpose_kernel<<<dim3(16, 16, 7), b256, 0, stream>>>(wp, wt);

  // ---- layer 1 (self-attention on decoder inputs) ----
  qkv4b_kernel<<<dim3(12, 16), 512, 0, stream>>>(
      decbf, decbf, decbf, wt, bq, bk, bv, qbf, kbf, vtb);
  attn_kernel<<<1024, b256, 0, stream>>>(qbf, kbf, vtb, tgt_mask, ctxb);
  gemm_proj<<<dim3(8, 32), b256, 0, stream>>>(ctxb, WoT, bo, qbf, tmpf);
  ln_kernel<0><<<4096, b256, 0, stream>>>(tmpf, gamma, beta, nullptr, sobf);
  // ---- layer 2 (cross-attention vs encoder states) ----
  qkv4b_kernel<<<dim3(12, 16), 512, 0, stream>>>(
      sobf, encbf, encbf, wt + 3 * 1048576, bq2, bk2, bv2, qbf, kbf, vtb);
  attn_kernel<<<1024, b256, 0, stream>>>(qbf, kbf, vtb, src_mask, ctxb);
  gemm_proj<<<dim3(8, 32), b256, 0, stream>>>(ctxb, WoT, bo, qbf, tmpf);
  ln_kernel<1><<<4096, b256, 0, stream>>>(tmpf, gamma, beta, out, nullptr);
}

// Round 8
// 233.859 us; speedup vs baseline: 1.6851x; 1.0014x over previous
//
#include <hip/hip_runtime.h>
#include <stdint.h>

// ---------------------------------------------------------------------------
// AlbertDecoderAttention on MI355X (gfx950) — round 8
// Changes vs round 7 (qkv only; rest unchanged):
//  * swizzle FIX: XOR row bits 1-2 (not 0-1) into byte bits 4-5 -> each
//    8-lane HW group hits 8 distinct 4-bank windows (round-6-style zero
//    conflicts, adapted to 64B rows).
//  * 3-deep prefetch: stage tile t+3 across 4 LDS buffers; steady VMCNT(8).
//  * LDS-bounce epilogue: acc -> swizzled [256][256] LDS tile (Vt transposed
//    in-LDS) -> 256B-contiguous global stores (full-line writes, 16 stores
//    per thread instead of 128 scalar ones).
// ---------------------------------------------------------------------------

typedef unsigned short u16;
typedef __bf16 bf16x8 __attribute__((ext_vector_type(8)));
typedef float f32x4 __attribute__((ext_vector_type(4)));

#define AS1 __attribute__((address_space(1)))
#define AS3 __attribute__((address_space(3)))
typedef AS3 char lds_char;
typedef AS3 unsigned short lds_u16;

#define VMCNT(n) asm volatile("s_waitcnt vmcnt(" #n ")" ::: "memory")
#define LGKM0() asm volatile("s_waitcnt lgkmcnt(0)" ::: "memory")
#define SBARRIER() asm volatile("s_barrier" ::: "memory")

__device__ __forceinline__ u16 f2bf(float f) {
  union { float f; uint32_t u; } v; v.f = f;
  uint32_t u = v.u;
  return (u16)((u + 0x7fffu + ((u >> 16) & 1u)) >> 16);  // RNE
}

__device__ __forceinline__ float bf2f(u16 b) {
  union { uint32_t u; float f; } v; v.u = ((uint32_t)b) << 16;
  return v.f;
}

__device__ __forceinline__ uint32_t cvt_pk_bf16(float lo, float hi) {
  uint32_t r;
  asm("v_cvt_pk_bf16_f32 %0, %1, %2" : "=v"(r) : "v"(lo), "v"(hi));
  return r;
}

__device__ __forceinline__ void gl_lds16(const void* g, void* l) {
  __builtin_amdgcn_global_load_lds((AS1 void*)(g), (AS3 void*)(l), 16, 0, 0);
}

__device__ __forceinline__ bf16x8 dsr128(const lds_u16* p) {
  bf16x8 r;
  asm volatile("ds_read_b128 %0, %1" : "=v"(r) : "v"(p));
  return r;
}

// swizzled byte address within a [rows][128B] LDS tile (attn tiles)
__device__ __forceinline__ int swz(int row, int byte) {
  return row * 128 + (byte ^ ((row & 7) << 4));
}

// ---------------------------------------------------------------------------
// f32 -> bf16 convert, two tensors in one launch (each 4096*1024 elems)
// ---------------------------------------------------------------------------
__global__ void __launch_bounds__(256)
convert2_kernel(const float* __restrict__ in0, u16* __restrict__ out0,
                const float* __restrict__ in1, u16* __restrict__ out1) {
  const int half = blockIdx.x >> 12;
  const int i = (blockIdx.x & 4095) * 256 + threadIdx.x;
  const float* in = half ? in1 : in0;
  u16* out = half ? out1 : out0;
  float4 v = ((const float4*)in)[i];
  ushort4 o;
  o.x = f2bf(v.x); o.y = f2bf(v.y); o.z = f2bf(v.z); o.w = f2bf(v.w);
  ((ushort4*)out)[i] = o;
}

// ---------------------------------------------------------------------------
// Weight transpose + convert: W[k][n] f32 -> Wt[n][k] bf16 (7 matrices)
// ---------------------------------------------------------------------------
struct WP { const float* w[7]; };

__global__ void __launch_bounds__(256)
transpose_kernel(WP wp, u16* __restrict__ out) {
  __shared__ float tile[64][65];
  const float* W = wp.w[blockIdx.z];
  u16* Wt = out + (size_t)blockIdx.z * 1024 * 1024;
  const int k0 = blockIdx.y * 64, n0 = blockIdx.x * 64;
  const int t = threadIdx.x;
  const int r = t >> 4, c4 = (t & 15) * 4;
#pragma unroll
  for (int rr = 0; rr < 64; rr += 16) {
    float4 v = *(const float4*)&W[(size_t)(k0 + r + rr) * 1024 + n0 + c4];
    tile[r + rr][c4 + 0] = v.x; tile[r + rr][c4 + 1] = v.y;
    tile[r + rr][c4 + 2] = v.z; tile[r + rr][c4 + 3] = v.w;
  }
  __syncthreads();
  const int n = t >> 2, seg = (t & 3) * 16;
  union { u16 s[16]; uint4 q[2]; } u;
#pragma unroll
  for (int i = 0; i < 16; ++i) u.s[i] = f2bf(tile[seg + i][n]);
  uint4* dst = (uint4*)&Wt[(size_t)(n0 + n) * 1024 + k0 + seg];
  dst[0] = u.q[0]; dst[1] = u.q[1];
}

// ---------------------------------------------------------------------------
// qkv4c: 3-segment projection GEMM. 256x256 tile, BK=32, 8 waves (2Mx4N),
// 4-buffer LDS (stage t+3 during t, VMCNT(8) steady), 2 phases/tile.
// LDS rows 64B; swizzle: byte ^= ((row>>1)&3)<<4 (bank-verified per 8-lane
// group). LDS-bounce epilogue for full-line global writes.
// ---------------------------------------------------------------------------
__global__ void __launch_bounds__(512, 2)
qkv4c_kernel(const u16* __restrict__ A0, const u16* __restrict__ A1,
             const u16* __restrict__ A2, const u16* __restrict__ Bt,
             const float* __restrict__ b0, const float* __restrict__ b1,
             const float* __restrict__ b2,
             u16* __restrict__ qb, u16* __restrict__ kb, u16* __restrict__ vt) {
  __shared__ u16 SH[65536];   // 128KB: staging (4xA 16KB | 4xB 16KB), then epilogue tile

  // 2D XCD-chunked tile mapping: dispatch d -> XCD chunk 4m x 6n
  const int d = blockIdx.y * 12 + blockIdx.x;
  const int c = d & 7, ci = d >> 3;            // 192 = 8 * 24
  const int mt = (c & 3) * 4 + (ci & 3);       // 0..15
  const int nt = (c >> 2) * 6 + (ci >> 2);     // 0..11
  const int bm = mt * 256, bn = nt * 256;
  const int seg = nt >> 2;
  const u16* A = (seg == 0) ? A0 : (seg == 1) ? A1 : A2;

  const int t = threadIdx.x, wv = t >> 6, ln = t & 63;
  const int wm = (wv >> 2) * 128, wn = (wv & 3) * 64;
  const int lcol = ln & 15, g = ln >> 4;
  // frag byte off in 64B row: row bits 1-2 (== lcol bits 1-2) XOR into bits 4-5
  const int aoff = (g * 16) ^ (((lcol >> 1) & 3) << 4);

  lds_char* ABase = (lds_char*)&SH[0];
  lds_char* BBase = (lds_char*)&SH[32768];

  // staging: linear LDS dest; inverse-swizzled global source.
  // dest row = hf*128 + wv*16 + (ln>>2); (row>>1)&3 == (ln>>3)&3
  const int st_row = wv * 16 + (ln >> 2);
  const int st_srcb = (((ln & 3) ^ ((ln >> 3) & 3)) * 16);
  auto stageA = [&](int buf, int k0) {
#pragma unroll
    for (int hf = 0; hf < 2; ++hf) {
      const int row = hf * 128 + st_row;
      gl_lds16((const char*)A + ((size_t)(bm + row) * 1024 + k0) * 2 + st_srcb,
               (char*)&SH[0] + buf * 16384 + hf * 8192 + wv * 1024);
    }
  };
  auto stageB = [&](int buf, int k0) {
#pragma unroll
    for (int hf = 0; hf < 2; ++hf) {
      const int row = hf * 128 + st_row;
      gl_lds16((const char*)Bt + ((size_t)(bn + row) * 1024 + k0) * 2 + st_srcb,
               (char*)&SH[32768] + buf * 16384 + hf * 8192 + wv * 1024);
    }
  };

  f32x4 acc[8][4] = {};

  // prologue: stage tiles 0,1,2; wait tile 0 (8 loads stay in flight)
  stageA(0, 0); stageB(0, 0);
  stageA(1, 32); stageB(1, 32);
  stageA(2, 64); stageB(2, 64);
  VMCNT(8);
  __builtin_amdgcn_s_barrier();

  for (int kt = 0; kt < 32; ++kt) {
    const int buf = kt & 3;
    lds_char* Ab = ABase + buf * 16384;
    lds_char* Bb = BBase + buf * 16384;
    const int sbuf = (kt + 3) & 3;
    const int sk = (kt + 3) * 32;
    const bool do_st = kt < 29;
    bf16x8 afr[4], bfr[4];

    // ---- phase 0: frags B j0-3 + A i0-3; stage A(t+3); MFMA i0-3
#pragma unroll
    for (int j = 0; j < 4; ++j)
      bfr[j] = dsr128((const lds_u16*)(Bb + (wn + j * 16 + lcol) * 64 + aoff));
#pragma unroll
    for (int i = 0; i < 4; ++i)
      afr[i] = dsr128((const lds_u16*)(Ab + (wm + i * 16 + lcol) * 64 + aoff));
    if (do_st) stageA(sbuf, sk);
    __builtin_amdgcn_s_barrier();
    LGKM0();
    __builtin_amdgcn_sched_barrier(0);
    __builtin_amdgcn_s_setprio(1);
#pragma unroll
    for (int i = 0; i < 4; ++i)
#pragma unroll
      for (int j = 0; j < 4; ++j)
        acc[i][j] = __builtin_amdgcn_mfma_f32_16x16x32_bf16(afr[i], bfr[j], acc[i][j], 0, 0, 0);
    __builtin_amdgcn_s_setprio(0);
    __builtin_amdgcn_s_barrier();

    // ---- phase 1: frags A i4-7 (B reused); stage B(t+3); MFMA i4-7
#pragma unroll
    for (int i = 0; i < 4; ++i)
      afr[i] = dsr128((const lds_u16*)(Ab + (wm + 64 + i * 16 + lcol) * 64 + aoff));
    if (do_st) stageB(sbuf, sk);
    __builtin_amdgcn_s_barrier();
    LGKM0();
    __builtin_amdgcn_sched_barrier(0);
    __builtin_amdgcn_s_setprio(1);
#pragma unroll
    for (int i = 0; i < 4; ++i)
#pragma unroll
      for (int j = 0; j < 4; ++j)
        acc[4 + i][j] = __builtin_amdgcn_mfma_f32_16x16x32_bf16(afr[i], bfr[j], acc[4 + i][j], 0, 0, 0);
    __builtin_amdgcn_s_setprio(0);
    if (kt < 29)       { VMCNT(8); }   // tile kt+1 landed; t+2,t+3 in flight
    else if (kt == 29) { VMCNT(4); }   // tile 30 landed; t31 in flight
    else if (kt == 30) { VMCNT(0); }   // tile 31 landed
    __builtin_amdgcn_s_barrier();
  }

  // ---- epilogue: bounce through SH as swizzled [256][256] bf16 tile ----
  const int cs = bn & 1023;
  const float* bias = (seg == 0) ? b0 : (seg == 1) ? b1 : b2;

  if (seg == 2) {
    // transposed-in-LDS: SH[col][m], ushort4-packed (r 0..3 contiguous in m)
#pragma unroll
    for (int j = 0; j < 4; ++j) {
      const int col_l = wn + j * 16 + lcol;
      const float bc = bias[cs + col_l];
#pragma unroll
      for (int i = 0; i < 8; ++i) {
        const int m4 = wm + i * 16 + g * 4;
        ushort4 o;
        o.x = f2bf(acc[i][j][0] + bc); o.y = f2bf(acc[i][j][1] + bc);
        o.z = f2bf(acc[i][j][2] + bc); o.w = f2bf(acc[i][j][3] + bc);
        *(ushort4*)((char*)SH + col_l * 512 + ((m4 * 2) ^ ((col_l & 7) << 4))) = o;
      }
    }
  } else {
    // row-major: SH[m][col], scalar u16 (index-level swizzle: col ^ ((m&7)<<3))
#pragma unroll
    for (int j = 0; j < 4; ++j) {
      const int col_l = wn + j * 16 + lcol;
      const float bc = bias[cs + col_l];
#pragma unroll
      for (int i = 0; i < 8; ++i) {
        const int m0 = wm + i * 16 + g * 4;
#pragma unroll
        for (int r = 0; r < 4; ++r)
          SH[(m0 + r) * 256 + (col_l ^ (((m0 + r) & 7) << 3))] = f2bf(acc[i][j][r] + bc);
      }
    }
  }
  __builtin_amdgcn_s_barrier();

  // read-out: thread t handles LDS row t>>1, half t&1 -> 256B contiguous store
  {
    const int R = t >> 1, hb = t & 1;
    u16* gp;
    if (seg == 2) {
      const int col = cs + R;
      const int h = col >> 6, dd = col & 63;
      gp = vt + ((size_t)((bm >> 10) * 16 + h) * 64 + dd) * 1024 + (bm & 1023) + hb * 128;
    } else {
      u16* outp = (seg == 0) ? qb : kb;
      gp = outp + (size_t)(bm + R) * 1024 + cs + hb * 128;
    }
#pragma unroll
    for (int cix = 0; cix < 16; ++cix) {
      uint4 v = *(uint4*)((char*)SH + R * 512 + ((hb * 256 + cix * 16) ^ ((R & 7) << 4)));
      *(uint4*)(gp + cix * 8) = v;
    }
  }
}

// ---------------------------------------------------------------------------
// Wo-projection GEMM: 128x128 tile, BK=64, 4 waves, counted-vmcnt pipeline.
// out f32 = acc + bias + bf2f(resid). XCD-chunked tile mapping (8m x 4n).
// ---------------------------------------------------------------------------
__global__ void __launch_bounds__(256)
gemm_proj(const u16* __restrict__ A, const u16* __restrict__ Bt,
          const float* __restrict__ bias, const u16* __restrict__ resid,
          float* __restrict__ outf) {
  __shared__ u16 Alds[2][8192];
  __shared__ u16 Blds[2][8192];
  const int d = blockIdx.y * 8 + blockIdx.x;   // 256 blocks
  const int c = d & 7, ci = d >> 3;            // 256 = 8 * 32
  const int mt = (c & 3) * 8 + (ci & 7);       // 0..31
  const int nt = (c >> 2) * 4 + (ci >> 3);     // 0..7
  const int bm = mt * 128, bn = nt * 128;
  const int t = threadIdx.x, wv = t >> 6, ln = t & 63;
  const int wm = (wv >> 1) * 64, wn = (wv & 1) * 64;
  const int lcol = ln & 15, lk8 = (ln >> 4) * 8, lr4 = (ln >> 4) * 4;

  f32x4 acc[4][4] = {};

  auto STAGE = [&](int buf, int k0) {
#pragma unroll
    for (int cc = 0; cc < 4; ++cc) {
      const int o = cc * 4096 + wv * 1024 + ln * 16;
      const int row = o >> 7, colb = o & 127;
      gl_lds16((const char*)A + ((size_t)(bm + row) * 1024 + k0) * 2 + colb,
               (char*)Alds[buf] + cc * 4096 + wv * 1024);
      gl_lds16((const char*)Bt + ((size_t)(bn + row) * 1024 + k0) * 2 + colb,
               (char*)Blds[buf] + cc * 4096 + wv * 1024);
    }
  };

  auto COMPUTE = [&](int buf) {
    const u16* Ab = Alds[buf];
    const u16* Bb = Blds[buf];
#pragma unroll
    for (int ks = 0; ks < 2; ++ks) {
      bf16x8 a[4], b[4];
#pragma unroll
      for (int i = 0; i < 4; ++i)
        a[i] = *(const bf16x8*)&Ab[(wm + i * 16 + lcol) * 64 + ks * 32 + lk8];
#pragma unroll
      for (int j = 0; j < 4; ++j)
        b[j] = *(const bf16x8*)&Bb[(wn + j * 16 + lcol) * 64 + ks * 32 + lk8];
#pragma unroll
      for (int i = 0; i < 4; ++i)
#pragma unroll
        for (int j = 0; j < 4; ++j)
          acc[i][j] = __builtin_amdgcn_mfma_f32_16x16x32_bf16(a[i], b[j], acc[i][j], 0, 0, 0);
    }
  };

  STAGE(0, 0);
  int cur = 0;
  for (int it = 0; it < 15; ++it) {
    STAGE(cur ^ 1, (it + 1) * 64);
    VMCNT(8);
    SBARRIER();
    COMPUTE(cur);
    SBARRIER();
    cur ^= 1;
  }
  VMCNT(0);
  SBARRIER();
  COMPUTE(cur);

#pragma unroll
  for (int j = 0; j < 4; ++j) {
    const int col = bn + wn + j * 16 + lcol;
    const float bc = bias[col];
#pragma unroll
    for (int i = 0; i < 4; ++i) {
      const int row0 = bm + wm + i * 16 + lr4;
#pragma unroll
      for (int r = 0; r < 4; ++r) {
        const size_t idx = (size_t)(row0 + r) * 1024 + col;
        outf[idx] = acc[i][j][r] + bc + bf2f(resid[idx]);
      }
    }
  }
}

// ---------------------------------------------------------------------------
// Flash attention, swapped-QK^T, counted-vmcnt pipeline, mask prefetch,
// defer-max (T13). grid 1024 blocks 1D (XCD-grouped), 4 waves x 16 q-rows.
// ---------------------------------------------------------------------------
__global__ void __launch_bounds__(256)
attn_kernel(const u16* __restrict__ Q, const u16* __restrict__ Kb,
            const u16* __restrict__ Vt, const float* __restrict__ mask,
            u16* __restrict__ ctx) {
  __shared__ u16 Klds[2][64 * 64];
  __shared__ u16 Vlds[2][64 * 64];
  __shared__ u16 Plds[4][16 * 64];

  const int fid = blockIdx.x;
  const int xcd = fid & 7, idx = fid >> 3;
  const int bh = xcd * 8 + (idx >> 4);
  const int b = bh >> 4, h = bh & 15;
  const int q0 = (idx & 15) * 64;

  const int t = threadIdx.x, wv = t >> 6, ln = t & 63;
  const int lcol = ln & 15, g = ln >> 4;
  const int lk8 = g * 8, c0 = g * 16;

  const int qrow = q0 + wv * 16 + lcol;
  const u16* qptr = Q + ((size_t)(b * 1024 + qrow) * 1024 + h * 64);
  bf16x8 qa[2];
  qa[0] = *(const bf16x8*)(qptr + lk8);
  qa[1] = *(const bf16x8*)(qptr + 32 + lk8);

  const float* mrow = mask + b * 1024;
  char* pbase = (char*)&Plds[wv][0];

  f32x4 accO[4] = {};
  float m_r = -1e30f, l_r = 0.f;

  auto STAGE = [&](int buf, int s0) {
#pragma unroll
    for (int c = 0; c < 2; ++c) {
      const int o = c * 4096 + wv * 1024 + ln * 16;
      const int row = o >> 7;
      const int src_cb = (o & 127) ^ ((row & 7) << 4);
      gl_lds16((const char*)Kb + ((size_t)((b * 1024 + s0 + row) * 1024 + h * 64)) * 2 + src_cb,
               (char*)Klds[buf] + c * 4096 + wv * 1024);
      gl_lds16((const char*)Vt + ((size_t)(((b * 16 + h) * 64 + row) * 1024 + s0)) * 2 + src_cb,
               (char*)Vlds[buf] + c * 4096 + wv * 1024);
    }
  };

  auto TILE = [&](int buf, const float4* mk) {
    f32x4 accST[4] = {};
    __builtin_amdgcn_s_setprio(1);
#pragma unroll
    for (int ks = 0; ks < 2; ++ks)
#pragma unroll
      for (int sb = 0; sb < 4; ++sb) {
        bf16x8 kb = *(const bf16x8*)((const char*)Klds[buf] + swz(sb * 16 + lcol, ks * 64 + c0));
        accST[sb] = __builtin_amdgcn_mfma_f32_16x16x32_bf16(kb, qa[ks], accST[sb], 0, 0, 0);
      }
    __builtin_amdgcn_s_setprio(0);

    float sv[4][4];
#pragma unroll
    for (int sb = 0; sb < 4; ++sb) {
      sv[sb][0] = accST[sb][0] * 0.125f + mk[sb].x;
      sv[sb][1] = accST[sb][1] * 0.125f + mk[sb].y;
      sv[sb][2] = accST[sb][2] * 0.125f + mk[sb].z;
      sv[sb][3] = accST[sb][3] * 0.125f + mk[sb].w;
    }
    float mt = sv[0][0];
#pragma unroll
    for (int sb = 0; sb < 4; ++sb)
#pragma unroll
      for (int r = 0; r < 4; ++r) mt = fmaxf(mt, sv[sb][r]);
    mt = fmaxf(mt, __shfl_xor(mt, 16));
    mt = fmaxf(mt, __shfl_xor(mt, 32));

    const bool nr = __all(mt <= m_r + 8.0f) != 0;
    float alpha = 1.0f;
    if (!nr) {
      const float mn2 = fmaxf(m_r, mt);
      alpha = __expf(m_r - mn2);
      m_r = mn2;
    }
    float rs = 0.f;
#pragma unroll
    for (int sb = 0; sb < 4; ++sb)
#pragma unroll
      for (int r = 0; r < 4; ++r) {
        const float pp = __expf(sv[sb][r] - m_r);
        sv[sb][r] = pp;
        rs += pp;
      }
    rs += __shfl_xor(rs, 16);
    rs += __shfl_xor(rs, 32);
    l_r = nr ? (l_r + rs) : (l_r * alpha + rs);

#pragma unroll
    for (int sb = 0; sb < 4; ++sb) {
      uint2 dd;
      dd.x = cvt_pk_bf16(sv[sb][0], sv[sb][1]);
      dd.y = cvt_pk_bf16(sv[sb][2], sv[sb][3]);
      *(uint2*)(pbase + swz(lcol, sb * 32 + g * 8)) = dd;
    }

    if (!nr) {
#pragma unroll
      for (int df = 0; df < 4; ++df)
#pragma unroll
        for (int r = 0; r < 4; ++r) accO[df][r] *= alpha;
    }
    __builtin_amdgcn_s_setprio(1);
#pragma unroll
    for (int ks = 0; ks < 2; ++ks) {
      bf16x8 pb = *(const bf16x8*)(pbase + swz(lcol, ks * 64 + c0));
#pragma unroll
      for (int df = 0; df < 4; ++df) {
        bf16x8 va = *(const bf16x8*)((const char*)Vlds[buf] + swz(df * 16 + lcol, ks * 64 + c0));
        accO[df] = __builtin_amdgcn_mfma_f32_16x16x32_bf16(va, pb, accO[df], 0, 0, 0);
      }
    }
    __builtin_amdgcn_s_setprio(0);
  };

  STAGE(0, 0);
  float4 mk_cur[4];
#pragma unroll
  for (int sb = 0; sb < 4; ++sb)
    mk_cur[sb] = *(const float4*)&mrow[sb * 16 + g * 4];

  int cur = 0;
  for (int ti = 0; ti < 15; ++ti) {
    const int s1 = ti * 64 + 64;
    STAGE(cur ^ 1, s1);
    float4 mk_nxt[4];
#pragma unroll
    for (int sb = 0; sb < 4; ++sb)
      mk_nxt[sb] = *(const float4*)&mrow[s1 + sb * 16 + g * 4];
    VMCNT(12);
    SBARRIER();
    TILE(cur, mk_cur);
    SBARRIER();
#pragma unroll
    for (int sb = 0; sb < 4; ++sb) mk_cur[sb] = mk_nxt[sb];
    cur ^= 1;
  }
  VMCNT(4);
  SBARRIER();
  TILE(cur, mk_cur);

  const float inv = 1.0f / l_r;
  u16* cp = ctx + ((size_t)(b * 1024 + qrow) * 1024 + h * 64);
#pragma unroll
  for (int df = 0; df < 4; ++df) {
    ushort4 o;
    o.x = f2bf(accO[df][0] * inv); o.y = f2bf(accO[df][1] * inv);
    o.z = f2bf(accO[df][2] * inv); o.w = f2bf(accO[df][3] * inv);
    *(ushort4*)(cp + df * 16 + g * 4) = o;
  }
}

// ---------------------------------------------------------------------------
// LayerNorm over rows of x[4096][1024]; OUTF=1 -> f32 out, else bf16 out
// ---------------------------------------------------------------------------
template <int OUTF>
__global__ void __launch_bounds__(256)
ln_kernel(const float* __restrict__ x, const float* __restrict__ gamma,
          const float* __restrict__ beta, float* __restrict__ outf,
          u16* __restrict__ outb) {
  const int row = blockIdx.x, t = threadIdx.x;
  const float* xr = x + (size_t)row * 1024;
  float4 v = *(const float4*)&xr[t * 4];
  float s = v.x + v.y + v.z + v.w;
  float q = v.x * v.x + v.y * v.y + v.z * v.z + v.w * v.w;
#pragma unroll
  for (int off = 1; off < 64; off <<= 1) {
    s += __shfl_xor(s, off);
    q += __shfl_xor(q, off);
  }
  __shared__ float ws[4], wq[4];
  if ((t & 63) == 0) { ws[t >> 6] = s; wq[t >> 6] = q; }
  __syncthreads();
  s = ws[0] + ws[1] + ws[2] + ws[3];
  q = wq[0] + wq[1] + wq[2] + wq[3];
  const float mu = s * (1.0f / 1024.0f);
  float var = q * (1.0f / 1024.0f) - mu * mu;
  var = fmaxf(var, 0.0f);
  const float rstd = rsqrtf(var + 1e-12f);
  float4 g = *(const float4*)&gamma[t * 4];
  float4 be = *(const float4*)&beta[t * 4];
  float y0 = (v.x - mu) * rstd * g.x + be.x;
  float y1 = (v.y - mu) * rstd * g.y + be.y;
  float y2 = (v.z - mu) * rstd * g.z + be.z;
  float y3 = (v.w - mu) * rstd * g.w + be.w;
  if constexpr (OUTF) {
    float4 o; o.x = y0; o.y = y1; o.z = y2; o.w = y3;
    *(float4*)&outf[(size_t)row * 1024 + t * 4] = o;
  } else {
    ushort4 o; o.x = f2bf(y0); o.y = f2bf(y1); o.z = f2bf(y2); o.w = f2bf(y3);
    *(ushort4*)&outb[(size_t)row * 1024 + t * 4] = o;
  }
}

// ---------------------------------------------------------------------------
extern "C" void kernel_launch(void* const* d_in, const int* in_sizes, int n_in,
                              void* d_out, int out_size, void* d_ws, size_t ws_size,
                              hipStream_t stream) {
  const float* enc = (const float*)d_in[0];
  const float* dec = (const float*)d_in[1];
  const float* src_mask = (const float*)d_in[2];
  const float* tgt_mask = (const float*)d_in[3];
  const float* Wq  = (const float*)d_in[4];  const float* bq  = (const float*)d_in[5];
  const float* Wk  = (const float*)d_in[6];  const float* bk  = (const float*)d_in[7];
  const float* Wv  = (const float*)d_in[8];  const float* bv  = (const float*)d_in[9];
  const float* Wq2 = (const float*)d_in[10]; const float* bq2 = (const float*)d_in[11];
  const float* Wk2 = (const float*)d_in[12]; const float* bk2 = (const float*)d_in[13];
  const float* Wv2 = (const float*)d_in[14]; const float* bv2 = (const float*)d_in[15];
  const float* Wo  = (const float*)d_in[16]; const float* bo  = (const float*)d_in[17];
  const float* gamma = (const float*)d_in[18]; const float* beta = (const float*)d_in[19];
  float* out = (float*)d_out;

  char* p = (char*)d_ws;
  const size_t ABF = (size_t)4096 * 1024 * 2;
  const size_t AF  = (size_t)4096 * 1024 * 4;
  const size_t WBF = (size_t)1024 * 1024 * 2;
  u16* decbf = (u16*)p; p += ABF;
  u16* encbf = (u16*)p; p += ABF;
  u16* wt    = (u16*)p; p += 7 * WBF;
  u16* qbf   = (u16*)p; p += ABF;
  u16* kbf   = (u16*)p; p += ABF;
  u16* vtb   = (u16*)p; p += ABF;
  u16* ctxb  = (u16*)p; p += ABF;
  float* tmpf = (float*)p; p += AF;
  u16* sobf  = decbf;  // reuse: decoder bf16 dead after layer-1 projections

  u16* WoT  = wt + 6 * 1048576;

  dim3 b256(256);
  convert2_kernel<<<8192, b256, 0, stream>>>(dec, decbf, enc, encbf);
  WP wp;
  wp.w[0] = Wq; wp.w[1] = Wk; wp.w[2] = Wv; wp.w[3] = Wq2;
  wp.w[4] = Wk2; wp.w[5] = Wv2; wp.w[6] = Wo;
  transpose_kernel<<<dim3(16, 16, 7), b256, 0, stream>>>(wp, wt);

  // ---- layer 1 (self-attention on decoder inputs) ----
  qkv4c_kernel<<<dim3(12, 16), 512, 0, stream>>>(
      decbf, decbf, decbf, wt, bq, bk, bv, qbf, kbf, vtb);
  attn_kernel<<<1024, b256, 0, stream>>>(qbf, kbf, vtb, tgt_mask, ctxb);
  gemm_proj<<<dim3(8, 32), b256, 0, stream>>>(ctxb, WoT, bo, qbf, tmpf);
  ln_kernel<0><<<4096, b256, 0, stream>>>(tmpf, gamma, beta, nullptr, sobf);
  // ---- layer 2 (cross-attention vs encoder states) ----
  qkv4c_kernel<<<dim3(12, 16), 512, 0, stream>>>(
      sobf, encbf, encbf, wt + 3 * 1048576, bq2, bk2, bv2, qbf, kbf, vtb);
  attn_kernel<<<1024, b256, 0, stream>>>(qbf, kbf, vtb, src_mask, ctxb);
  gemm_proj<<<dim3(8, 32), b256, 0, stream>>>(ctxb, WoT, bo, qbf, tmpf);
  ln_kernel<1><<<4096, b256, 0, stream>>>(tmpf, gamma, beta, out, nullptr);
}

// Round 9
// 218.763 us; speedup vs baseline: 1.8014x; 1.0690x over previous
//
#include <hip/hip_runtime.h>
#include <stdint.h>

// ---------------------------------------------------------------------------
// AlbertDecoderAttention on MI355X (gfx950) — round 9
// Changes vs round 8:
//  * qkv -> qkv3b: 256x128 tile, grid 384 (2 blocks/CU co-resident, 3-buf
//    72KB LDS) for cross-block TLP; BK=32 single-phase tiles {8 dsr, stage
//    t+2, bar, lgkm0, 16 MFMA, VMCNT(3), bar}; swizzle kept; LDS-bounce
//    epilogue; XCD n-chunking; __launch_bounds__(512,4).
//  * gemm_proj: 3-bit XOR LDS swizzle (was 16-way conflicted), 3-buf BK=64
//    stage t+2 / VMCNT(8), 32-MFMA barrier intervals.
//  * attn / converts / transpose / ln unchanged.
// ---------------------------------------------------------------------------

typedef unsigned short u16;
typedef __bf16 bf16x8 __attribute__((ext_vector_type(8)));
typedef float f32x4 __attribute__((ext_vector_type(4)));

#define AS1 __attribute__((address_space(1)))
#define AS3 __attribute__((address_space(3)))
typedef AS3 char lds_char;
typedef AS3 unsigned short lds_u16;

#define VMCNT(n) asm volatile("s_waitcnt vmcnt(" #n ")" ::: "memory")
#define LGKM0() asm volatile("s_waitcnt lgkmcnt(0)" ::: "memory")
#define SBARRIER() asm volatile("s_barrier" ::: "memory")

__device__ __forceinline__ u16 f2bf(float f) {
  union { float f; uint32_t u; } v; v.f = f;
  uint32_t u = v.u;
  return (u16)((u + 0x7fffu + ((u >> 16) & 1u)) >> 16);  // RNE
}

__device__ __forceinline__ float bf2f(u16 b) {
  union { uint32_t u; float f; } v; v.u = ((uint32_t)b) << 16;
  return v.f;
}

__device__ __forceinline__ uint32_t cvt_pk_bf16(float lo, float hi) {
  uint32_t r;
  asm("v_cvt_pk_bf16_f32 %0, %1, %2" : "=v"(r) : "v"(lo), "v"(hi));
  return r;
}

__device__ __forceinline__ void gl_lds16(const void* g, void* l) {
  __builtin_amdgcn_global_load_lds((AS1 void*)(g), (AS3 void*)(l), 16, 0, 0);
}

__device__ __forceinline__ bf16x8 dsr128(const lds_u16* p) {
  bf16x8 r;
  asm volatile("ds_read_b128 %0, %1" : "=v"(r) : "v"(p));
  return r;
}

// swizzled byte address within a [rows][128B] LDS tile (attn tiles)
__device__ __forceinline__ int swz(int row, int byte) {
  return row * 128 + (byte ^ ((row & 7) << 4));
}

// ---------------------------------------------------------------------------
// f32 -> bf16 convert, two tensors in one launch (each 4096*1024 elems)
// ---------------------------------------------------------------------------
__global__ void __launch_bounds__(256)
convert2_kernel(const float* __restrict__ in0, u16* __restrict__ out0,
                const float* __restrict__ in1, u16* __restrict__ out1) {
  const int half = blockIdx.x >> 12;
  const int i = (blockIdx.x & 4095) * 256 + threadIdx.x;
  const float* in = half ? in1 : in0;
  u16* out = half ? out1 : out0;
  float4 v = ((const float4*)in)[i];
  ushort4 o;
  o.x = f2bf(v.x); o.y = f2bf(v.y); o.z = f2bf(v.z); o.w = f2bf(v.w);
  ((ushort4*)out)[i] = o;
}

// ---------------------------------------------------------------------------
// Weight transpose + convert: W[k][n] f32 -> Wt[n][k] bf16 (7 matrices)
// ---------------------------------------------------------------------------
struct WP { const float* w[7]; };

__global__ void __launch_bounds__(256)
transpose_kernel(WP wp, u16* __restrict__ out) {
  __shared__ float tile[64][65];
  const float* W = wp.w[blockIdx.z];
  u16* Wt = out + (size_t)blockIdx.z * 1024 * 1024;
  const int k0 = blockIdx.y * 64, n0 = blockIdx.x * 64;
  const int t = threadIdx.x;
  const int r = t >> 4, c4 = (t & 15) * 4;
#pragma unroll
  for (int rr = 0; rr < 64; rr += 16) {
    float4 v = *(const float4*)&W[(size_t)(k0 + r + rr) * 1024 + n0 + c4];
    tile[r + rr][c4 + 0] = v.x; tile[r + rr][c4 + 1] = v.y;
    tile[r + rr][c4 + 2] = v.z; tile[r + rr][c4 + 3] = v.w;
  }
  __syncthreads();
  const int n = t >> 2, seg = (t & 3) * 16;
  union { u16 s[16]; uint4 q[2]; } u;
#pragma unroll
  for (int i = 0; i < 16; ++i) u.s[i] = f2bf(tile[seg + i][n]);
  uint4* dst = (uint4*)&Wt[(size_t)(n0 + n) * 1024 + k0 + seg];
  dst[0] = u.q[0]; dst[1] = u.q[1];
}

// ---------------------------------------------------------------------------
// qkv3b: 3-segment projection GEMM. 256x128 tile, BK=32, 8 waves (4Mx2N),
// 3-buffer LDS (72KB -> 2 blocks/CU), stage t+2, VMCNT(3), 1 phase/tile.
// LDS rows 64B; swizzle byte ^= ((row>>1)&3)<<4. LDS-bounce epilogue.
// Bt = [W0|W1|W2] as [3072][1024]. seg0->qb, seg1->kb, seg2->Vt.
// ---------------------------------------------------------------------------
__global__ void __launch_bounds__(512, 4)
qkv3b_kernel(const u16* __restrict__ A0, const u16* __restrict__ A1,
             const u16* __restrict__ A2, const u16* __restrict__ Bt,
             const float* __restrict__ b0, const float* __restrict__ b1,
             const float* __restrict__ b2,
             u16* __restrict__ qb, u16* __restrict__ kb, u16* __restrict__ vt) {
  __shared__ u16 SH[36864];   // 72KB: 3 x (A 16KB + B 8KB); epilogue tile 64KB

  // XCD-chunked mapping: 384 blocks = 8 XCD x (16m x 3n)
  const int d = blockIdx.y * 24 + blockIdx.x;
  const int c = d & 7, ci = d >> 3;          // ci 0..47
  const int mt = ci & 15, nt = c * 3 + (ci >> 4);
  const int bm = mt * 256, bn = nt * 128;
  const int seg = nt >> 3;                    // 8 n-tiles per 1024-col segment
  const int cs = (nt & 7) * 128;
  const u16* A = (seg == 0) ? A0 : (seg == 1) ? A1 : A2;

  const int t = threadIdx.x, wv = t >> 6, ln = t & 63;
  const int wm = (wv >> 1) * 64, wn = (wv & 1) * 64;
  const int lcol = ln & 15, g = ln >> 4;
  const int aoff = (g * 16) ^ (((lcol >> 1) & 3) << 4);

  lds_char* base = (lds_char*)&SH[0];
  // staging: linear dest t*16; inverse-swizzled source chunk
  const int st_srcb = (((t & 3) ^ ((t >> 3) & 3)) * 16);
  auto STAGE = [&](int buf, int k0) {
#pragma unroll
    for (int l = 0; l < 2; ++l) {             // A: 256 rows, 2 loads
      const int row = l * 128 + (t >> 2);
      gl_lds16((const char*)A + ((size_t)(bm + row) * 1024 + k0) * 2 + st_srcb,
               (char*)base + buf * 24576 + l * 8192 + (t >> 6) * 1024);
    }
    {                                          // B: 128 rows, 1 load
      const int row = t >> 2;
      gl_lds16((const char*)Bt + ((size_t)(bn + row) * 1024 + k0) * 2 + st_srcb,
               (char*)base + buf * 24576 + 16384 + (t >> 6) * 1024);
    }
  };

  f32x4 acc[4][4] = {};

  // prologue: stage tiles 0,1; wait tile 0 (tile 1's 3 loads stay in flight)
  STAGE(0, 0);
  STAGE(1, 32);
  VMCNT(3);
  __builtin_amdgcn_s_barrier();

  int cur = 0, st = 2;
  for (int kt = 0; kt < 32; ++kt) {
    lds_char* Ab = base + cur * 24576;
    lds_char* Bb = Ab + 16384;
    bf16x8 afr[4], bfr[4];
#pragma unroll
    for (int j = 0; j < 4; ++j)
      bfr[j] = dsr128((const lds_u16*)(Bb + (wn + j * 16 + lcol) * 64 + aoff));
#pragma unroll
    for (int i = 0; i < 4; ++i)
      afr[i] = dsr128((const lds_u16*)(Ab + (wm + i * 16 + lcol) * 64 + aoff));
    if (kt < 30) STAGE(st, (kt + 2) * 32);
    __builtin_amdgcn_s_barrier();
    LGKM0();
    __builtin_amdgcn_sched_barrier(0);
    __builtin_amdgcn_s_setprio(1);
#pragma unroll
    for (int i = 0; i < 4; ++i)
#pragma unroll
      for (int j = 0; j < 4; ++j)
        acc[i][j] = __builtin_amdgcn_mfma_f32_16x16x32_bf16(afr[i], bfr[j], acc[i][j], 0, 0, 0);
    __builtin_amdgcn_s_setprio(0);
    if (kt < 30)       { VMCNT(3); }   // tile kt+1 landed; kt+2 in flight
    else if (kt == 30) { VMCNT(0); }
    __builtin_amdgcn_s_barrier();
    cur = (cur == 2) ? 0 : cur + 1;
    st  = (st == 2)  ? 0 : st + 1;
  }

  // ---- epilogue: bounce through SH (64KB tile) for full-line writes ----
  const float* bias = (seg == 0) ? b0 : (seg == 1) ? b1 : b2;

  if (seg == 2) {
    // transposed: SH[col 128][m 256], 512B rows; byte m4*2 ^ ((col&7)<<4)
#pragma unroll
    for (int j = 0; j < 4; ++j) {
      const int col_l = wn + j * 16 + lcol;
      const float bc = bias[cs + col_l];
#pragma unroll
      for (int i = 0; i < 4; ++i) {
        const int m4 = wm + i * 16 + g * 4;
        ushort4 o;
        o.x = f2bf(acc[i][j][0] + bc); o.y = f2bf(acc[i][j][1] + bc);
        o.z = f2bf(acc[i][j][2] + bc); o.w = f2bf(acc[i][j][3] + bc);
        *(ushort4*)((char*)SH + col_l * 512 + ((m4 * 2) ^ ((col_l & 7) << 4))) = o;
      }
    }
  } else {
    // row-major: SH[m 256][col 128]; index swizzle col ^ ((m&7)<<3)
#pragma unroll
    for (int j = 0; j < 4; ++j) {
      const int col_l = wn + j * 16 + lcol;
      const float bc = bias[cs + col_l];
#pragma unroll
      for (int i = 0; i < 4; ++i) {
        const int m0 = wm + i * 16 + g * 4;
#pragma unroll
        for (int r = 0; r < 4; ++r)
          SH[(m0 + r) * 128 + (col_l ^ (((m0 + r) & 7) << 3))] = f2bf(acc[i][j][r] + bc);
      }
    }
  }
  __builtin_amdgcn_s_barrier();

  if (seg == 2) {
    // 128 cols x 512B; thread: col = t>>2, quarter q = t&3 (128B)
    const int C = t >> 2, q = t & 3;
    const int col = cs + C;
    const int h = col >> 6, dd = col & 63;
    u16* gp = vt + ((size_t)((bm >> 10) * 16 + h) * 64 + dd) * 1024 + (bm & 1023) + q * 64;
#pragma unroll
    for (int cix = 0; cix < 8; ++cix) {
      uint4 v = *(uint4*)((char*)SH + C * 512 + ((q * 128 + cix * 16) ^ ((C & 7) << 4)));
      *(uint4*)(gp + cix * 8) = v;
    }
  } else {
    // 256 rows x 256B; thread: row = t>>1, half hb = t&1 (128B)
    const int R = t >> 1, hb = t & 1;
    u16* outp = (seg == 0) ? qb : kb;
    u16* gp = outp + (size_t)(bm + R) * 1024 + cs + hb * 64;
#pragma unroll
    for (int cix = 0; cix < 8; ++cix) {
      uint4 v = *(uint4*)((char*)SH + R * 256 + ((hb * 128 + cix * 16) ^ ((R & 7) << 4)));
      *(uint4*)(gp + cix * 8) = v;
    }
  }
}

// ---------------------------------------------------------------------------
// Wo-projection GEMM: 128x128, BK=64, 4 waves, 3-buf stage t+2 / VMCNT(8),
// swizzled LDS (3-bit XOR), 32-MFMA barrier intervals.
// out f32 = acc + bias + bf2f(resid). XCD-chunked (8m x 4n).
// ---------------------------------------------------------------------------
__global__ void __launch_bounds__(256)
gemm_proj(const u16* __restrict__ A, const u16* __restrict__ Bt,
          const float* __restrict__ bias, const u16* __restrict__ resid,
          float* __restrict__ outf) {
  __shared__ u16 Alds[3][8192];   // 16KB each, 128B rows, swizzled
  __shared__ u16 Blds[3][8192];
  const int d = blockIdx.y * 8 + blockIdx.x;   // 256 blocks
  const int c = d & 7, ci = d >> 3;
  const int mt = (c & 3) * 8 + (ci & 7);
  const int nt = (c >> 2) * 4 + (ci >> 3);
  const int bm = mt * 128, bn = nt * 128;
  const int t = threadIdx.x, wv = t >> 6, ln = t & 63;
  const int wm = (wv >> 1) * 64, wn = (wv & 1) * 64;
  const int lcol = ln & 15, g = ln >> 4, lr4 = g * 4;
  const int xr = (lcol & 7) << 4;
  const int aoff0 = (g * 16) ^ xr;          // ks=0
  const int aoff1 = (64 + g * 16) ^ xr;     // ks=1

  f32x4 acc[4][4] = {};

  // stage: 128 rows x 128B per matrix; thread row = t>>3, chunk t&7
  const int st_srcb = (((t & 7) ^ ((t >> 3) & 7)) * 16);
  auto STAGE = [&](int buf, int k0) {
#pragma unroll
    for (int l = 0; l < 4; ++l) {
      const int row = l * 32 + (t >> 3);
      gl_lds16((const char*)A + ((size_t)(bm + row) * 1024 + k0) * 2 + st_srcb,
               (char*)&Alds[buf][0] + l * 4096 + (t >> 6) * 1024);
      gl_lds16((const char*)Bt + ((size_t)(bn + row) * 1024 + k0) * 2 + st_srcb,
               (char*)&Blds[buf][0] + l * 4096 + (t >> 6) * 1024);
    }
  };

  STAGE(0, 0);
  STAGE(1, 64);
  VMCNT(8);
  __builtin_amdgcn_s_barrier();

  int cur = 0, st = 2;
  for (int it = 0; it < 16; ++it) {
    lds_char* Ab = (lds_char*)&Alds[cur][0];
    lds_char* Bb = (lds_char*)&Blds[cur][0];
    bf16x8 a0[4], b0v[4], a1[4], b1v[4];
#pragma unroll
    for (int i = 0; i < 4; ++i) {
      a0[i]  = dsr128((const lds_u16*)(Ab + (wm + i * 16 + lcol) * 128 + aoff0));
      b0v[i] = dsr128((const lds_u16*)(Bb + (wn + i * 16 + lcol) * 128 + aoff0));
    }
#pragma unroll
    for (int i = 0; i < 4; ++i) {
      a1[i]  = dsr128((const lds_u16*)(Ab + (wm + i * 16 + lcol) * 128 + aoff1));
      b1v[i] = dsr128((const lds_u16*)(Bb + (wn + i * 16 + lcol) * 128 + aoff1));
    }
    if (it < 14) STAGE(st, (it + 2) * 64);
    __builtin_amdgcn_s_barrier();
    LGKM0();
    __builtin_amdgcn_sched_barrier(0);
    __builtin_amdgcn_s_setprio(1);
#pragma unroll
    for (int i = 0; i < 4; ++i)
#pragma unroll
      for (int j = 0; j < 4; ++j)
        acc[i][j] = __builtin_amdgcn_mfma_f32_16x16x32_bf16(a0[i], b0v[j], acc[i][j], 0, 0, 0);
#pragma unroll
    for (int i = 0; i < 4; ++i)
#pragma unroll
      for (int j = 0; j < 4; ++j)
        acc[i][j] = __builtin_amdgcn_mfma_f32_16x16x32_bf16(a1[i], b1v[j], acc[i][j], 0, 0, 0);
    __builtin_amdgcn_s_setprio(0);
    if (it < 14)       { VMCNT(8); }
    else if (it == 14) { VMCNT(0); }
    __builtin_amdgcn_s_barrier();
    cur = (cur == 2) ? 0 : cur + 1;
    st  = (st == 2)  ? 0 : st + 1;
  }

#pragma unroll
  for (int j = 0; j < 4; ++j) {
    const int col = bn + wn + j * 16 + lcol;
    const float bc = bias[col];
#pragma unroll
    for (int i = 0; i < 4; ++i) {
      const int row0 = bm + wm + i * 16 + lr4;
#pragma unroll
      for (int r = 0; r < 4; ++r) {
        const size_t idx = (size_t)(row0 + r) * 1024 + col;
        outf[idx] = acc[i][j][r] + bc + bf2f(resid[idx]);
      }
    }
  }
}

// ---------------------------------------------------------------------------
// Flash attention, swapped-QK^T, counted-vmcnt pipeline, mask prefetch,
// defer-max (T13). grid 1024 blocks 1D (XCD-grouped), 4 waves x 16 q-rows.
// ---------------------------------------------------------------------------
__global__ void __launch_bounds__(256)
attn_kernel(const u16* __restrict__ Q, const u16* __restrict__ Kb,
            const u16* __restrict__ Vt, const float* __restrict__ mask,
            u16* __restrict__ ctx) {
  __shared__ u16 Klds[2][64 * 64];
  __shared__ u16 Vlds[2][64 * 64];
  __shared__ u16 Plds[4][16 * 64];

  const int fid = blockIdx.x;
  const int xcd = fid & 7, idx = fid >> 3;
  const int bh = xcd * 8 + (idx >> 4);
  const int b = bh >> 4, h = bh & 15;
  const int q0 = (idx & 15) * 64;

  const int t = threadIdx.x, wv = t >> 6, ln = t & 63;
  const int lcol = ln & 15, g = ln >> 4;
  const int lk8 = g * 8, c0 = g * 16;

  const int qrow = q0 + wv * 16 + lcol;
  const u16* qptr = Q + ((size_t)(b * 1024 + qrow) * 1024 + h * 64);
  bf16x8 qa[2];
  qa[0] = *(const bf16x8*)(qptr + lk8);
  qa[1] = *(const bf16x8*)(qptr + 32 + lk8);

  const float* mrow = mask + b * 1024;
  char* pbase = (char*)&Plds[wv][0];

  f32x4 accO[4] = {};
  float m_r = -1e30f, l_r = 0.f;

  auto STAGE = [&](int buf, int s0) {
#pragma unroll
    for (int c = 0; c < 2; ++c) {
      const int o = c * 4096 + wv * 1024 + ln * 16;
      const int row = o >> 7;
      const int src_cb = (o & 127) ^ ((row & 7) << 4);
      gl_lds16((const char*)Kb + ((size_t)((b * 1024 + s0 + row) * 1024 + h * 64)) * 2 + src_cb,
               (char*)Klds[buf] + c * 4096 + wv * 1024);
      gl_lds16((const char*)Vt + ((size_t)(((b * 16 + h) * 64 + row) * 1024 + s0)) * 2 + src_cb,
               (char*)Vlds[buf] + c * 4096 + wv * 1024);
    }
  };

  auto TILE = [&](int buf, const float4* mk) {
    f32x4 accST[4] = {};
    __builtin_amdgcn_s_setprio(1);
#pragma unroll
    for (int ks = 0; ks < 2; ++ks)
#pragma unroll
      for (int sb = 0; sb < 4; ++sb) {
        bf16x8 kb = *(const bf16x8*)((const char*)Klds[buf] + swz(sb * 16 + lcol, ks * 64 + c0));
        accST[sb] = __builtin_amdgcn_mfma_f32_16x16x32_bf16(kb, qa[ks], accST[sb], 0, 0, 0);
      }
    __builtin_amdgcn_s_setprio(0);

    float sv[4][4];
#pragma unroll
    for (int sb = 0; sb < 4; ++sb) {
      sv[sb][0] = accST[sb][0] * 0.125f + mk[sb].x;
      sv[sb][1] = accST[sb][1] * 0.125f + mk[sb].y;
      sv[sb][2] = accST[sb][2] * 0.125f + mk[sb].z;
      sv[sb][3] = accST[sb][3] * 0.125f + mk[sb].w;
    }
    float mt = sv[0][0];
#pragma unroll
    for (int sb = 0; sb < 4; ++sb)
#pragma unroll
      for (int r = 0; r < 4; ++r) mt = fmaxf(mt, sv[sb][r]);
    mt = fmaxf(mt, __shfl_xor(mt, 16));
    mt = fmaxf(mt, __shfl_xor(mt, 32));

    const bool nr = __all(mt <= m_r + 8.0f) != 0;
    float alpha = 1.0f;
    if (!nr) {
      const float mn2 = fmaxf(m_r, mt);
      alpha = __expf(m_r - mn2);
      m_r = mn2;
    }
    float rs = 0.f;
#pragma unroll
    for (int sb = 0; sb < 4; ++sb)
#pragma unroll
      for (int r = 0; r < 4; ++r) {
        const float pp = __expf(sv[sb][r] - m_r);
        sv[sb][r] = pp;
        rs += pp;
      }
    rs += __shfl_xor(rs, 16);
    rs += __shfl_xor(rs, 32);
    l_r = nr ? (l_r + rs) : (l_r * alpha + rs);

#pragma unroll
    for (int sb = 0; sb < 4; ++sb) {
      uint2 dd;
      dd.x = cvt_pk_bf16(sv[sb][0], sv[sb][1]);
      dd.y = cvt_pk_bf16(sv[sb][2], sv[sb][3]);
      *(uint2*)(pbase + swz(lcol, sb * 32 + g * 8)) = dd;
    }

    if (!nr) {
#pragma unroll
      for (int df = 0; df < 4; ++df)
#pragma unroll
        for (int r = 0; r < 4; ++r) accO[df][r] *= alpha;
    }
    __builtin_amdgcn_s_setprio(1);
#pragma unroll
    for (int ks = 0; ks < 2; ++ks) {
      bf16x8 pb = *(const bf16x8*)(pbase + swz(lcol, ks * 64 + c0));
#pragma unroll
      for (int df = 0; df < 4; ++df) {
        bf16x8 va = *(const bf16x8*)((const char*)Vlds[buf] + swz(df * 16 + lcol, ks * 64 + c0));
        accO[df] = __builtin_amdgcn_mfma_f32_16x16x32_bf16(va, pb, accO[df], 0, 0, 0);
      }
    }
    __builtin_amdgcn_s_setprio(0);
  };

  STAGE(0, 0);
  float4 mk_cur[4];
#pragma unroll
  for (int sb = 0; sb < 4; ++sb)
    mk_cur[sb] = *(const float4*)&mrow[sb * 16 + g * 4];

  int cur = 0;
  for (int ti = 0; ti < 15; ++ti) {
    const int s1 = ti * 64 + 64;
    STAGE(cur ^ 1, s1);
    float4 mk_nxt[4];
#pragma unroll
    for (int sb = 0; sb < 4; ++sb)
      mk_nxt[sb] = *(const float4*)&mrow[s1 + sb * 16 + g * 4];
    VMCNT(12);
    SBARRIER();
    TILE(cur, mk_cur);
    SBARRIER();
#pragma unroll
    for (int sb = 0; sb < 4; ++sb) mk_cur[sb] = mk_nxt[sb];
    cur ^= 1;
  }
  VMCNT(4);
  SBARRIER();
  TILE(cur, mk_cur);

  const float inv = 1.0f / l_r;
  u16* cp = ctx + ((size_t)(b * 1024 + qrow) * 1024 + h * 64);
#pragma unroll
  for (int df = 0; df < 4; ++df) {
    ushort4 o;
    o.x = f2bf(accO[df][0] * inv); o.y = f2bf(accO[df][1] * inv);
    o.z = f2bf(accO[df][2] * inv); o.w = f2bf(accO[df][3] * inv);
    *(ushort4*)(cp + df * 16 + g * 4) = o;
  }
}

// ---------------------------------------------------------------------------
// LayerNorm over rows of x[4096][1024]; OUTF=1 -> f32 out, else bf16 out
// ---------------------------------------------------------------------------
template <int OUTF>
__global__ void __launch_bounds__(256)
ln_kernel(const float* __restrict__ x, const float* __restrict__ gamma,
          const float* __restrict__ beta, float* __restrict__ outf,
          u16* __restrict__ outb) {
  const int row = blockIdx.x, t = threadIdx.x;
  const float* xr = x + (size_t)row * 1024;
  float4 v = *(const float4*)&xr[t * 4];
  float s = v.x + v.y + v.z + v.w;
  float q = v.x * v.x + v.y * v.y + v.z * v.z + v.w * v.w;
#pragma unroll
  for (int off = 1; off < 64; off <<= 1) {
    s += __shfl_xor(s, off);
    q += __shfl_xor(q, off);
  }
  __shared__ float ws[4], wq[4];
  if ((t & 63) == 0) { ws[t >> 6] = s; wq[t >> 6] = q; }
  __syncthreads();
  s = ws[0] + ws[1] + ws[2] + ws[3];
  q = wq[0] + wq[1] + wq[2] + wq[3];
  const float mu = s * (1.0f / 1024.0f);
  float var = q * (1.0f / 1024.0f) - mu * mu;
  var = fmaxf(var, 0.0f);
  const float rstd = rsqrtf(var + 1e-12f);
  float4 g = *(const float4*)&gamma[t * 4];
  float4 be = *(const float4*)&beta[t * 4];
  float y0 = (v.x - mu) * rstd * g.x + be.x;
  float y1 = (v.y - mu) * rstd * g.y + be.y;
  float y2 = (v.z - mu) * rstd * g.z + be.z;
  float y3 = (v.w - mu) * rstd * g.w + be.w;
  if constexpr (OUTF) {
    float4 o; o.x = y0; o.y = y1; o.z = y2; o.w = y3;
    *(float4*)&outf[(size_t)row * 1024 + t * 4] = o;
  } else {
    ushort4 o; o.x = f2bf(y0); o.y = f2bf(y1); o.z = f2bf(y2); o.w = f2bf(y3);
    *(ushort4*)&outb[(size_t)row * 1024 + t * 4] = o;
  }
}

// ---------------------------------------------------------------------------
extern "C" void kernel_launch(void* const* d_in, const int* in_sizes, int n_in,
                              void* d_out, int out_size, void* d_ws, size_t ws_size,
                              hipStream_t stream) {
  const float* enc = (const float*)d_in[0];
  const float* dec = (const float*)d_in[1];
  const float* src_mask = (const float*)d_in[2];
  const float* tgt_mask = (const float*)d_in[3];
  const float* Wq  = (const float*)d_in[4];  const float* bq  = (const float*)d_in[5];
  const float* Wk  = (const float*)d_in[6];  const float* bk  = (const float*)d_in[7];
  const float* Wv  = (const float*)d_in[8];  const float* bv  = (const float*)d_in[9];
  const float* Wq2 = (const float*)d_in[10]; const float* bq2 = (const float*)d_in[11];
  const float* Wk2 = (const float*)d_in[12]; const float* bk2 = (const float*)d_in[13];
  const float* Wv2 = (const float*)d_in[14]; const float* bv2 = (const float*)d_in[15];
  const float* Wo  = (const float*)d_in[16]; const float* bo  = (const float*)d_in[17];
  const float* gamma = (const float*)d_in[18]; const float* beta = (const float*)d_in[19];
  float* out = (float*)d_out;

  char* p = (char*)d_ws;
  const size_t ABF = (size_t)4096 * 1024 * 2;
  const size_t AF  = (size_t)4096 * 1024 * 4;
  const size_t WBF = (size_t)1024 * 1024 * 2;
  u16* decbf = (u16*)p; p += ABF;
  u16* encbf = (u16*)p; p += ABF;
  u16* wt    = (u16*)p; p += 7 * WBF;
  u16* qbf   = (u16*)p; p += ABF;
  u16* kbf   = (u16*)p; p += ABF;
  u16* vtb   = (u16*)p; p += ABF;
  u16* ctxb  = (u16*)p; p += ABF;
  float* tmpf = (float*)p; p += AF;
  u16* sobf  = decbf;  // reuse: decoder bf16 dead after layer-1 projections

  u16* WoT  = wt + 6 * 1048576;

  dim3 b256(256);
  convert2_kernel<<<8192, b256, 0, stream>>>(dec, decbf, enc, encbf);
  WP wp;
  wp.w[0] = Wq; wp.w[1] = Wk; wp.w[2] = Wv; wp.w[3] = Wq2;
  wp.w[4] = Wk2; wp.w[5] = Wv2; wp.w[6] = Wo;
  transpose_kernel<<<dim3(16, 16, 7), b256, 0, stream>>>(wp, wt);

  // ---- layer 1 (self-attention on decoder inputs) ----
  qkv3b_kernel<<<dim3(24, 16), 512, 0, stream>>>(
      decbf, decbf, decbf, wt, bq, bk, bv, qbf, kbf, vtb);
  attn_kernel<<<1024, b256, 0, stream>>>(qbf, kbf, vtb, tgt_mask, ctxb);
  gemm_proj<<<dim3(8, 32), b256, 0, stream>>>(ctxb, WoT, bo, qbf, tmpf);
  ln_kernel<0><<<4096, b256, 0, stream>>>(tmpf, gamma, beta, nullptr, sobf);
  // ---- layer 2 (cross-attention vs encoder states) ----
  qkv3b_kernel<<<dim3(24, 16), 512, 0, stream>>>(
      sobf, encbf, encbf, wt + 3 * 1048576, bq2, bk2, bv2, qbf, kbf, vtb);
  attn_kernel<<<1024, b256, 0, stream>>>(qbf, kbf, vtb, src_mask, ctxb);
  gemm_proj<<<dim3(8, 32), b256, 0, stream>>>(ctxb, WoT, bo, qbf, tmpf);
  ln_kernel<1><<<4096, b256, 0, stream>>>(tmpf, gamma, beta, out, nullptr);
}